// Round 1
// baseline (784.835 us; speedup 1.0000x reference)
//
#include <hip/hip_runtime.h>
#include <hip/hip_bf16.h>

#define INV_SQRT2f 0.70710678118654752440f
#define BETAf 0.3f
#define OMBf  0.7f
#define LN_EPSf 1e-5f

#define B 128
#define S 1024
#define P 336
#define PPAD 384
#define C 128
#define H1 32
#define H2 16

// workspace layout (float offsets)
#define WS_MEAN   0                         // 16384
#define WS_STD    16384                     // 16384
#define WS_SUMWHP 32768                     // 384
#define WS_ROWWTP 33152                     // 384
#define WS_BCP    33536                     // 384
#define WS_WHP2T  33920                     // 1024*384 = 393216
#define WS_H2     427136                    // 128*1024*16 = 2097152
#define WS_WCPT   2524288                   // 3072*336 = 1032192
#define WS_M      3556480                   // 128*336*16 = 688128
#define WS_EVP    4244608                   // 128*4*128 = 65536
#define WS_SQP    4310144                   // 65536
// total 4375680 floats = 17.5 MB

// ---------------------------------------------------------------------------
// k_prep: Whp2T[u][p] (Haar-folded Whp, transposed, padded to PPAD),
//         sumWhp[p], rowWtp[p], bcP[p]
__global__ void k_prep(const float* __restrict__ Whp, const float* __restrict__ Wtp,
                       const float* __restrict__ bc, float* __restrict__ ws)
{
    const int p = blockIdx.x;     // 0..383
    const int t = threadIdx.x;    // 256
    float* whp2t = ws + WS_WHP2T;
    __shared__ float red[768];
    float sw = 0.f, rw = 0.f, bp = 0.f;
    if (p < P) {
        for (int sp = t; sp < 512; sp += 256) {
            float a = Whp[p * 1024 + sp];
            float d = Whp[p * 1024 + 512 + sp];
            whp2t[(size_t)(2 * sp) * PPAD + p]     = (a + d) * INV_SQRT2f;
            whp2t[(size_t)(2 * sp + 1) * PPAD + p] = (a - d) * INV_SQRT2f;
            sw += a + d;
        }
        for (int s = t; s < S; s += 256) {
            float w = Wtp[p * 1024 + s];
            rw += w;
            bp += w * bc[s];
        }
    } else {
        for (int sp = t; sp < 512; sp += 256) {
            whp2t[(size_t)(2 * sp) * PPAD + p]     = 0.f;
            whp2t[(size_t)(2 * sp + 1) * PPAD + p] = 0.f;
        }
    }
    red[t] = sw; red[256 + t] = rw; red[512 + t] = bp;
    __syncthreads();
    for (int off = 128; off > 0; off >>= 1) {
        if (t < off) {
            red[t]       += red[t + off];
            red[256 + t] += red[256 + t + off];
            red[512 + t] += red[512 + t + off];
        }
        __syncthreads();
    }
    if (t == 0) {
        ws[WS_SUMWHP + p] = (p < P) ? red[0]   : 0.f;
        ws[WS_ROWWTP + p] = (p < P) ? red[256] : 0.f;
        ws[WS_BCP + p]    = (p < P) ? red[512] : 0.f;
    }
}

// ---------------------------------------------------------------------------
// stats pass 1: per (b, u-quarter): partial even-sum and sum-of-squares
__global__ void k_stats1(const float* __restrict__ x, float* __restrict__ ws)
{
    const int b = blockIdx.x;
    const int j = blockIdx.y;       // 0..3
    const int t = threadIdx.x;      // 256
    const int c = t & 127;
    const int half = t >> 7;
    const float* xb = x + (size_t)b * S * C;
    const int ub = j * 256 + half * 128;
    float ev = 0.f, sq = 0.f;
    #pragma unroll 4
    for (int it = 0; it < 128; it += 2) {
        float v0 = xb[(size_t)(ub + it) * C + c];       // even u
        float v1 = xb[(size_t)(ub + it + 1) * C + c];   // odd u
        ev += v0;
        sq += v0 * v0 + v1 * v1;
    }
    __shared__ float evb[256], sqb[256];
    evb[t] = ev; sqb[t] = sq;
    __syncthreads();
    if (t < 128) {
        ws[WS_EVP + ((size_t)b * 4 + j) * 128 + c] = evb[c] + evb[128 + c];
        ws[WS_SQP + ((size_t)b * 4 + j) * 128 + c] = sqb[c] + sqb[128 + c];
    }
}

// stats pass 2: mean/stdev per (b,c).  mean = 2c/S * evensum; sum(xw^2) = sum(x^2)
__global__ void k_stats2(float* __restrict__ ws)
{
    const int idx = blockIdx.x * 256 + threadIdx.x;   // b*128+c, grid 64
    const int b = idx >> 7, c = idx & 127;
    float ev = 0.f, sq = 0.f;
    #pragma unroll
    for (int j = 0; j < 4; j++) {
        ev += ws[WS_EVP + ((size_t)b * 4 + j) * 128 + c];
        sq += ws[WS_SQP + ((size_t)b * 4 + j) * 128 + c];
    }
    float mean = ev * (INV_SQRT2f / 512.f);
    float var  = (sq - 1024.f * mean * mean) * (1.f / 1023.f);  // ddof=1
    ws[WS_MEAN + idx] = mean;
    ws[WS_STD + idx]  = sqrtf(var + LN_EPSf);
}

// ---------------------------------------------------------------------------
// MLP: one thread per (b,s) row. h2[b][s][g] to workspace.
__global__ void k_mlp(const float* __restrict__ xme,
                      const float* __restrict__ W1, const float* __restrict__ b1,
                      const float* __restrict__ g1, const float* __restrict__ be1,
                      const float* __restrict__ W2, const float* __restrict__ b2,
                      const float* __restrict__ g2, const float* __restrict__ be2,
                      float* __restrict__ ws)
{
    __shared__ float w1s[128], b1s[32], g1s[32], be1s[32];
    __shared__ float w2s[512], b2s[16], g2s[16], be2s[16];
    const int t = threadIdx.x;
    if (t < 128) w1s[t] = W1[t];
    if (t < 32) { b1s[t] = b1[t]; g1s[t] = g1[t]; be1s[t] = be1[t]; }
    for (int i = t; i < 512; i += 256) w2s[i] = W2[i];
    if (t < 16) { b2s[t] = b2[t]; g2s[t] = g2[t]; be2s[t] = be2[t]; }
    __syncthreads();

    const int row = blockIdx.x * 256 + t;      // b*1024+s
    float4 v = *(const float4*)(xme + (size_t)row * 4);

    float h1v[32];
    float m = 0.f;
    #pragma unroll
    for (int i = 0; i < 32; i++) {
        float a = w1s[i*4+0]*v.x + w1s[i*4+1]*v.y + w1s[i*4+2]*v.z + w1s[i*4+3]*v.w + b1s[i];
        h1v[i] = a; m += a;
    }
    m *= (1.f / 32.f);
    float var = 0.f;
    #pragma unroll
    for (int i = 0; i < 32; i++) { float d = h1v[i] - m; var += d * d; }
    var *= (1.f / 32.f);
    float rs = rsqrtf(var + LN_EPSf);
    #pragma unroll
    for (int i = 0; i < 32; i++)
        h1v[i] = fmaxf((h1v[i] - m) * rs * g1s[i] + be1s[i], 0.f);

    float h2v[16];
    float m2 = 0.f;
    #pragma unroll
    for (int g = 0; g < 16; g++) {
        float a = b2s[g];
        #pragma unroll
        for (int i = 0; i < 32; i++) a = fmaf(w2s[g * 32 + i], h1v[i], a);
        h2v[g] = a; m2 += a;
    }
    m2 *= (1.f / 16.f);
    float v2 = 0.f;
    #pragma unroll
    for (int g = 0; g < 16; g++) { float d = h2v[g] - m2; v2 += d * d; }
    v2 *= (1.f / 16.f);
    float rs2 = rsqrtf(v2 + LN_EPSf);
    float* h2o = ws + WS_H2 + (size_t)row * 16;
    #pragma unroll
    for (int g = 0; g < 16; g++)
        h2o[g] = fmaxf((h2v[g] - m2) * rs2 * g2s[g] + be2s[g], 0.f);
}

// ---------------------------------------------------------------------------
// WcPT[m][p] = sum_o Wtp[p,o] * Wc[o, m]   (m = i*3+k, 3072; p = 336)
// grid (12 m-blocks, 28 p-groups of 12), block 256
__global__ __launch_bounds__(256) void k_wcp(const float* __restrict__ Wc,
                                             const float* __restrict__ Wtp,
                                             float* __restrict__ ws)
{
    __shared__ float wtpT[1024 * 12];     // [s][q], 48 KB
    const int t = threadIdx.x;
    const int p0 = blockIdx.y * 12;
    for (int q = 0; q < 12; q++)
        for (int s = t; s < 1024; s += 256)
            wtpT[s * 12 + q] = Wtp[(size_t)(p0 + q) * 1024 + s];
    __syncthreads();

    const int m = blockIdx.x * 256 + t;
    float acc[12];
    #pragma unroll
    for (int q = 0; q < 12; q++) acc[q] = 0.f;

    for (int s = 0; s < 1024; s++) {
        float wv = Wc[(size_t)s * 3072 + m];
        const float4* w4 = (const float4*)(wtpT + s * 12);
        float4 a0 = w4[0], a1 = w4[1], a2 = w4[2];
        acc[0] = fmaf(a0.x, wv, acc[0]); acc[1]  = fmaf(a0.y, wv, acc[1]);
        acc[2] = fmaf(a0.z, wv, acc[2]); acc[3]  = fmaf(a0.w, wv, acc[3]);
        acc[4] = fmaf(a1.x, wv, acc[4]); acc[5]  = fmaf(a1.y, wv, acc[5]);
        acc[6] = fmaf(a1.z, wv, acc[6]); acc[7]  = fmaf(a1.w, wv, acc[7]);
        acc[8] = fmaf(a2.x, wv, acc[8]); acc[9]  = fmaf(a2.y, wv, acc[9]);
        acc[10] = fmaf(a2.z, wv, acc[10]); acc[11] = fmaf(a2.w, wv, acc[11]);
    }
    float* o = ws + WS_WCPT + (size_t)m * 336 + p0;
    *(float4*)(o)     = make_float4(acc[0], acc[1], acc[2],  acc[3]);
    *(float4*)(o + 4) = make_float4(acc[4], acc[5], acc[6],  acc[7]);
    *(float4*)(o + 8) = make_float4(acc[8], acc[9], acc[10], acc[11]);
}

// ---------------------------------------------------------------------------
// M[b][p][g] = bcP[p] + sum_{i,k} h_pad[b,i,g+k-1] * WcPT[i*3+k][p]
// grid (b=128, ptile=6 of 64), block 256 = 64 p-lanes x 4 i-quarters
__global__ __launch_bounds__(256) void k_mconv(float* __restrict__ ws)
{
    __shared__ float hl[16384];   // h2[b], 64 KB; reused as reduction buffer
    const int b = blockIdx.x;
    const int pt = blockIdx.y;
    const int t = threadIdx.x;
    const float* h2 = ws + WS_H2 + (size_t)b * 16384;
    for (int i = t * 4; i < 16384; i += 1024)
        *(float4*)(hl + i) = *(const float4*)(h2 + i);
    __syncthreads();

    const int pl = t & 63;
    const int q  = t >> 6;
    const int p  = pt * 64 + pl;
    const int pc = p < P ? p : P - 1;
    const float* wcpt = ws + WS_WCPT;

    float acc[16];
    #pragma unroll
    for (int g = 0; g < 16; g++) acc[g] = 0.f;

    for (int i = q * 256; i < q * 256 + 256; i++) {
        const float4* h4 = (const float4*)(hl + i * 16);
        float4 ha = h4[0], hb = h4[1], hc = h4[2], hd = h4[3];
        float hr[16] = {ha.x,ha.y,ha.z,ha.w, hb.x,hb.y,hb.z,hb.w,
                        hc.x,hc.y,hc.z,hc.w, hd.x,hd.y,hd.z,hd.w};
        float w0 = wcpt[(size_t)(i * 3 + 0) * 336 + pc];
        float w1 = wcpt[(size_t)(i * 3 + 1) * 336 + pc];
        float w2 = wcpt[(size_t)(i * 3 + 2) * 336 + pc];
        #pragma unroll
        for (int g = 0; g < 16; g++) acc[g] = fmaf(hr[g], w1, acc[g]);
        #pragma unroll
        for (int g = 1; g < 16; g++) acc[g] = fmaf(hr[g - 1], w0, acc[g]);
        #pragma unroll
        for (int g = 0; g < 15; g++) acc[g] = fmaf(hr[g + 1], w2, acc[g]);
    }
    __syncthreads();   // done reading h
    #pragma unroll
    for (int g = 0; g < 16; g++) hl[t * 16 + g] = acc[g];
    __syncthreads();

    float* Mo = ws + WS_M;
    for (int jj = t; jj < 1024; jj += 256) {
        int pl2 = jj >> 4, g = jj & 15;
        float s = hl[(0 * 64 + pl2) * 16 + g] + hl[(1 * 64 + pl2) * 16 + g]
                + hl[(2 * 64 + pl2) * 16 + g] + hl[(3 * 64 + pl2) * 16 + g];
        int pg = pt * 64 + pl2;
        if (pg < P)
            Mo[((size_t)b * P + pg) * 16 + g] = s + ws[WS_BCP + pg];
    }
}

// ---------------------------------------------------------------------------
// pred GEMM + fused epilogue.
// S1[b,p,c] = sum_u Whp2T[u][p] * x[b,u,c]
// out = BETA*S1 + (BETA*bhp[p] + OMB*TO)*std[b,c] + (1-BETA*sumWhp[p])*mean[b,c]
// TO = sum_g M[b,p,g]*W3[c,g] + rowWtp[p]*b3[c] + btp[p]
// grid (ptile=6 of 64, b=128), block 128 = 8 p-threads x 16 c-threads, 8x8 tile
__global__ __launch_bounds__(128) void k_pred(
    const float* __restrict__ x,
    const float* __restrict__ W3, const float* __restrict__ b3,
    const float* __restrict__ btp, const float* __restrict__ bhp,
    const float* __restrict__ ws, float* __restrict__ out)
{
    const int b = blockIdx.y;
    const int pt0 = blockIdx.x * 64;
    const int t = threadIdx.x;
    const int ct = t & 15;
    const int pt = t >> 4;
    const int c0 = ct * 8;
    const int p0 = pt0 + pt * 8;

    const float* xb = x + (size_t)b * S * C + c0;
    const float* wt = ws + WS_WHP2T + p0;

    float acc[8][8];
    #pragma unroll
    for (int i = 0; i < 8; i++)
        #pragma unroll
        for (int j = 0; j < 8; j++) acc[i][j] = 0.f;

    for (int u = 0; u < S; u++) {
        float4 xa = *(const float4*)(xb + (size_t)u * C);
        float4 xc = *(const float4*)(xb + (size_t)u * C + 4);
        float4 wa = *(const float4*)(wt + (size_t)u * PPAD);
        float4 wb = *(const float4*)(wt + (size_t)u * PPAD + 4);
        float xv[8] = {xa.x, xa.y, xa.z, xa.w, xc.x, xc.y, xc.z, xc.w};
        float wv[8] = {wa.x, wa.y, wa.z, wa.w, wb.x, wb.y, wb.z, wb.w};
        #pragma unroll
        for (int i = 0; i < 8; i++)
            #pragma unroll
            for (int j = 0; j < 8; j++)
                acc[i][j] = fmaf(wv[i], xv[j], acc[i][j]);
    }

    // epilogue
    #pragma unroll
    for (int i = 0; i < 8; i++)
        #pragma unroll
        for (int j = 0; j < 8; j++) acc[i][j] *= BETAf;

    float sd[8], mn[8], b3v[8];
    #pragma unroll
    for (int j = 0; j < 8; j++) {
        sd[j]  = ws[WS_STD + b * C + c0 + j];
        mn[j]  = ws[WS_MEAN + b * C + c0 + j];
        b3v[j] = b3[c0 + j];
    }
    int pcl[8];
    #pragma unroll
    for (int i = 0; i < 8; i++) pcl[i] = (p0 + i < P) ? (p0 + i) : (P - 1);

    const float* Mb = ws + WS_M + (size_t)b * P * 16;
    #pragma unroll
    for (int g = 0; g < 16; g++) {
        float mcol[8], wj[8];
        #pragma unroll
        for (int i = 0; i < 8; i++) mcol[i] = Mb[pcl[i] * 16 + g];
        #pragma unroll
        for (int j = 0; j < 8; j++) wj[j] = OMBf * sd[j] * W3[(c0 + j) * 16 + g];
        #pragma unroll
        for (int i = 0; i < 8; i++)
            #pragma unroll
            for (int j = 0; j < 8; j++)
                acc[i][j] = fmaf(mcol[i], wj[j], acc[i][j]);
    }

    #pragma unroll
    for (int i = 0; i < 8; i++) {
        int p = p0 + i;
        float bhpv = bhp[pcl[i]], btpv = btp[pcl[i]];
        float sumw = ws[WS_SUMWHP + pcl[i]], roww = ws[WS_ROWWTP + pcl[i]];
        float res[8];
        #pragma unroll
        for (int j = 0; j < 8; j++) {
            res[j] = acc[i][j] + BETAf * bhpv * sd[j]
                   + (1.f - BETAf * sumw) * mn[j]
                   + OMBf * sd[j] * (btpv + roww * b3v[j]);
        }
        if (p < P) {
            float* op = out + ((size_t)b * P + p) * C + c0;
            *(float4*)(op)     = make_float4(res[0], res[1], res[2], res[3]);
            *(float4*)(op + 4) = make_float4(res[4], res[5], res[6], res[7]);
        }
    }
}

// ---------------------------------------------------------------------------
extern "C" void kernel_launch(void* const* d_in, const int* in_sizes, int n_in,
                              void* d_out, int out_size, void* d_ws, size_t ws_size,
                              hipStream_t stream)
{
    const float* x    = (const float*)d_in[0];
    const float* xme  = (const float*)d_in[1];
    const float* W1   = (const float*)d_in[4];
    const float* b1   = (const float*)d_in[5];
    const float* g1   = (const float*)d_in[6];
    const float* be1  = (const float*)d_in[7];
    const float* W2   = (const float*)d_in[8];
    const float* b2   = (const float*)d_in[9];
    const float* g2   = (const float*)d_in[10];
    const float* be2  = (const float*)d_in[11];
    const float* Wc   = (const float*)d_in[12];
    const float* bc   = (const float*)d_in[13];
    const float* W3   = (const float*)d_in[14];
    const float* b3   = (const float*)d_in[15];
    const float* Wtp  = (const float*)d_in[16];
    const float* btp  = (const float*)d_in[17];
    const float* Whp  = (const float*)d_in[18];
    const float* bhp  = (const float*)d_in[19];
    float* ws  = (float*)d_ws;
    float* out = (float*)d_out;

    k_prep  <<<dim3(PPAD),      dim3(256), 0, stream>>>(Whp, Wtp, bc, ws);
    k_stats1<<<dim3(B, 4),      dim3(256), 0, stream>>>(x, ws);
    k_stats2<<<dim3(64),        dim3(256), 0, stream>>>(ws);
    k_mlp   <<<dim3(512),       dim3(256), 0, stream>>>(xme, W1, b1, g1, be1,
                                                        W2, b2, g2, be2, ws);
    k_wcp   <<<dim3(12, 28),    dim3(256), 0, stream>>>(Wc, Wtp, ws);
    k_mconv <<<dim3(B, 6),      dim3(256), 0, stream>>>(ws);
    k_pred  <<<dim3(6, B),      dim3(128), 0, stream>>>(x, W3, b3, btp, bhp, ws, out);
}

// Round 4
// 375.888 us; speedup vs baseline: 2.0880x; 2.0880x over previous
//
#include <hip/hip_runtime.h>
#include <hip/hip_bf16.h>

#define INV_SQRT2f 0.70710678118654752440f
#define BETAf 0.3f
#define OMBf  0.7f
#define LN_EPSf 1e-5f

#define B 128
#define S 1024
#define P 336
#define C 128
#define H1 32
#define H2 16

// ---------------- workspace layout (float offsets) ----------------
#define WS_WHP2G  0               // bf16 A-image, 64 tiles * 12288 B = 786432 B
#define WS_EPI    262144          // float4[384]: {A13, A4, A2, -}
#define WS_MEAN   263680          // 16384
#define WS_STD    280064          // 16384
#define WS_BCP    296448          // 384
#define WS_H2     296832          // 128*1024*16 = 2097152
#define WS_WCPT   2393984         // 3072*336  = 1032192
#define WS_M      3426176         // 128*336*16 = 688128
#define WS_EVP    4114304         // 65536
#define WS_SQP    4179840         // 65536
// total 4245376 floats = 16.98 MB

typedef short  s16x8 __attribute__((ext_vector_type(8)));
typedef float  f32x4 __attribute__((ext_vector_type(4)));

// exact RNE float->bf16
__device__ __forceinline__ unsigned f2bf(float f) {
    unsigned u = __float_as_uint(f);
    return (u + 0x7fffu + ((u >> 16) & 1u)) >> 16;
}

// A-image u32 index for the pair (u=2sp, u=2sp+1) of projection row p.
// Tile (kt*2+ptile): 12 subtiles [sub][kg][m][8] of bf16 (1024 B each).
__device__ __forceinline__ int whp2l_u32(int p, int sp) {
    int kt   = sp >> 4;                  // K-chunk of 32 (u = 32kt + k)
    int tile = kt * 2 + p / 192;
    int sub  = (p % 192) >> 4;
    int kg   = (sp & 15) >> 2;           // k = 2*(sp&15); kgroup = k>>3
    int m    = p & 15;
    int byte = tile * 12288 + sub * 1024 + kg * 256 + m * 16 + 4 * (sp & 3);
    return byte >> 2;
}

// ---------------------------------------------------------------------------
// k_prep: bf16 A-image (Haar-folded, BETA-scaled Whp2) + EPI + bcP
__global__ void k_prep(const float* __restrict__ Whp, const float* __restrict__ Wtp,
                       const float* __restrict__ bc,  const float* __restrict__ bhp,
                       const float* __restrict__ btp, float* __restrict__ ws)
{
    const int p = blockIdx.x;     // 0..335
    const int t = threadIdx.x;    // 256
    unsigned* img = (unsigned*)ws;
    __shared__ float red[768];
    float sw = 0.f, rw = 0.f, bp = 0.f;
    for (int sp = t; sp < 512; sp += 256) {
        float a = Whp[p * 1024 + sp];
        float d = Whp[p * 1024 + 512 + sp];
        float va = BETAf * (a + d) * INV_SQRT2f;   // u = 2sp
        float vb = BETAf * (a - d) * INV_SQRT2f;   // u = 2sp+1
        img[whp2l_u32(p, sp)] = f2bf(va) | (f2bf(vb) << 16);
        sw += a + d;
    }
    for (int s = t; s < S; s += 256) {
        float w = Wtp[p * 1024 + s];
        rw += w;
        bp += w * bc[s];
    }
    red[t] = sw; red[256 + t] = rw; red[512 + t] = bp;
    __syncthreads();
    for (int off = 128; off > 0; off >>= 1) {
        if (t < off) {
            red[t]       += red[t + off];
            red[256 + t] += red[256 + t + off];
            red[512 + t] += red[512 + t + off];
        }
        __syncthreads();
    }
    if (t == 0) {
        ws[WS_BCP + p] = red[512];
        float* e = ws + WS_EPI + p * 4;
        e[0] = BETAf * bhp[p] + OMBf * btp[p];   // A13
        e[1] = OMBf * red[256];                  // A4 = OMB*rowWtp
        e[2] = 1.f - BETAf * red[0];             // A2 = 1-BETA*sumWhp
        e[3] = 0.f;
    }
}

// ---------------------------------------------------------------------------
// stats pass 1
__global__ void k_stats1(const float* __restrict__ x, float* __restrict__ ws)
{
    const int b = blockIdx.x;
    const int j = blockIdx.y;       // 0..3
    const int t = threadIdx.x;      // 256
    const int c = t & 127;
    const int half = t >> 7;
    const float* xb = x + (size_t)b * S * C;
    const int ub = j * 256 + half * 128;
    float ev = 0.f, sq = 0.f;
    #pragma unroll 4
    for (int it = 0; it < 128; it += 2) {
        float v0 = xb[(size_t)(ub + it) * C + c];
        float v1 = xb[(size_t)(ub + it + 1) * C + c];
        ev += v0;
        sq += v0 * v0 + v1 * v1;
    }
    __shared__ float evb[256], sqb[256];
    evb[t] = ev; sqb[t] = sq;
    __syncthreads();
    if (t < 128) {
        ws[WS_EVP + ((size_t)b * 4 + j) * 128 + c] = evb[c] + evb[128 + c];
        ws[WS_SQP + ((size_t)b * 4 + j) * 128 + c] = sqb[c] + sqb[128 + c];
    }
}

__global__ void k_stats2(float* __restrict__ ws)
{
    const int idx = blockIdx.x * 256 + threadIdx.x;
    const int b = idx >> 7, c = idx & 127;
    float ev = 0.f, sq = 0.f;
    #pragma unroll
    for (int j = 0; j < 4; j++) {
        ev += ws[WS_EVP + ((size_t)b * 4 + j) * 128 + c];
        sq += ws[WS_SQP + ((size_t)b * 4 + j) * 128 + c];
    }
    float mean = ev * (INV_SQRT2f / 512.f);
    float var  = (sq - 1024.f * mean * mean) * (1.f / 1023.f);
    ws[WS_MEAN + idx] = mean;
    ws[WS_STD + idx]  = sqrtf(var + LN_EPSf);
}

// ---------------------------------------------------------------------------
// MLP
__global__ void k_mlp(const float* __restrict__ xme,
                      const float* __restrict__ W1, const float* __restrict__ b1,
                      const float* __restrict__ g1, const float* __restrict__ be1,
                      const float* __restrict__ W2, const float* __restrict__ b2,
                      const float* __restrict__ g2, const float* __restrict__ be2,
                      float* __restrict__ ws)
{
    __shared__ float w1s[128], b1s[32], g1s[32], be1s[32];
    __shared__ float w2s[512], b2s[16], g2s[16], be2s[16];
    const int t = threadIdx.x;
    if (t < 128) w1s[t] = W1[t];
    if (t < 32) { b1s[t] = b1[t]; g1s[t] = g1[t]; be1s[t] = be1[t]; }
    for (int i = t; i < 512; i += 256) w2s[i] = W2[i];
    if (t < 16) { b2s[t] = b2[t]; g2s[t] = g2[t]; be2s[t] = be2[t]; }
    __syncthreads();

    const int row = blockIdx.x * 256 + t;
    float4 v = *(const float4*)(xme + (size_t)row * 4);

    float h1v[32];
    float m = 0.f;
    #pragma unroll
    for (int i = 0; i < 32; i++) {
        float a = w1s[i*4+0]*v.x + w1s[i*4+1]*v.y + w1s[i*4+2]*v.z + w1s[i*4+3]*v.w + b1s[i];
        h1v[i] = a; m += a;
    }
    m *= (1.f / 32.f);
    float var = 0.f;
    #pragma unroll
    for (int i = 0; i < 32; i++) { float d = h1v[i] - m; var += d * d; }
    var *= (1.f / 32.f);
    float rs = rsqrtf(var + LN_EPSf);
    #pragma unroll
    for (int i = 0; i < 32; i++)
        h1v[i] = fmaxf((h1v[i] - m) * rs * g1s[i] + be1s[i], 0.f);

    float h2v[16];
    float m2 = 0.f;
    #pragma unroll
    for (int g = 0; g < 16; g++) {
        float a = b2s[g];
        #pragma unroll
        for (int i = 0; i < 32; i++) a = fmaf(w2s[g * 32 + i], h1v[i], a);
        h2v[g] = a; m2 += a;
    }
    m2 *= (1.f / 16.f);
    float v2 = 0.f;
    #pragma unroll
    for (int g = 0; g < 16; g++) { float d = h2v[g] - m2; v2 += d * d; }
    v2 *= (1.f / 16.f);
    float rs2 = rsqrtf(v2 + LN_EPSf);
    float* h2o = ws + WS_H2 + (size_t)row * 16;
    #pragma unroll
    for (int g = 0; g < 16; g++)
        h2o[g] = fmaxf((h2v[g] - m2) * rs2 * g2s[g] + be2s[g], 0.f);
}

// ---------------------------------------------------------------------------
// WcPT[m][p] = sum_o Wtp[p,o] * Wc[o, m]
__global__ __launch_bounds__(256) void k_wcp(const float* __restrict__ Wc,
                                             const float* __restrict__ Wtp,
                                             float* __restrict__ ws)
{
    __shared__ float wtpT[1024 * 12];
    const int t = threadIdx.x;
    const int p0 = blockIdx.y * 12;
    for (int q = 0; q < 12; q++)
        for (int s = t; s < 1024; s += 256)
            wtpT[s * 12 + q] = Wtp[(size_t)(p0 + q) * 1024 + s];
    __syncthreads();

    const int m = blockIdx.x * 256 + t;
    float acc[12];
    #pragma unroll
    for (int q = 0; q < 12; q++) acc[q] = 0.f;

    for (int s = 0; s < 1024; s++) {
        float wv = Wc[(size_t)s * 3072 + m];
        const float4* w4 = (const float4*)(wtpT + s * 12);
        float4 a0 = w4[0], a1 = w4[1], a2 = w4[2];
        acc[0] = fmaf(a0.x, wv, acc[0]); acc[1]  = fmaf(a0.y, wv, acc[1]);
        acc[2] = fmaf(a0.z, wv, acc[2]); acc[3]  = fmaf(a0.w, wv, acc[3]);
        acc[4] = fmaf(a1.x, wv, acc[4]); acc[5]  = fmaf(a1.y, wv, acc[5]);
        acc[6] = fmaf(a1.z, wv, acc[6]); acc[7]  = fmaf(a1.w, wv, acc[7]);
        acc[8] = fmaf(a2.x, wv, acc[8]); acc[9]  = fmaf(a2.y, wv, acc[9]);
        acc[10] = fmaf(a2.z, wv, acc[10]); acc[11] = fmaf(a2.w, wv, acc[11]);
    }
    float* o = ws + WS_WCPT + (size_t)m * 336 + p0;
    *(float4*)(o)     = make_float4(acc[0], acc[1], acc[2],  acc[3]);
    *(float4*)(o + 4) = make_float4(acc[4], acc[5], acc[6],  acc[7]);
    *(float4*)(o + 8) = make_float4(acc[8], acc[9], acc[10], acc[11]);
}

// ---------------------------------------------------------------------------
// k_mconv
__global__ __launch_bounds__(256) void k_mconv(float* __restrict__ ws)
{
    __shared__ float hl[16384];
    const int b = blockIdx.x;
    const int pt = blockIdx.y;
    const int t = threadIdx.x;
    const float* h2 = ws + WS_H2 + (size_t)b * 16384;
    for (int i = t * 4; i < 16384; i += 1024)
        *(float4*)(hl + i) = *(const float4*)(h2 + i);
    __syncthreads();

    const int pl = t & 63;
    const int q  = t >> 6;
    const int p  = pt * 64 + pl;
    const int pc = p < P ? p : P - 1;
    const float* wcpt = ws + WS_WCPT;

    float acc[16];
    #pragma unroll
    for (int g = 0; g < 16; g++) acc[g] = 0.f;

    for (int i = q * 256; i < q * 256 + 256; i++) {
        const float4* h4 = (const float4*)(hl + i * 16);
        float4 ha = h4[0], hb = h4[1], hc = h4[2], hd = h4[3];
        float hr[16] = {ha.x,ha.y,ha.z,ha.w, hb.x,hb.y,hb.z,hb.w,
                        hc.x,hc.y,hc.z,hc.w, hd.x,hd.y,hd.z,hd.w};
        float w0 = wcpt[(size_t)(i * 3 + 0) * 336 + pc];
        float w1 = wcpt[(size_t)(i * 3 + 1) * 336 + pc];
        float w2 = wcpt[(size_t)(i * 3 + 2) * 336 + pc];
        #pragma unroll
        for (int g = 0; g < 16; g++) acc[g] = fmaf(hr[g], w1, acc[g]);
        #pragma unroll
        for (int g = 1; g < 16; g++) acc[g] = fmaf(hr[g - 1], w0, acc[g]);
        #pragma unroll
        for (int g = 0; g < 15; g++) acc[g] = fmaf(hr[g + 1], w2, acc[g]);
    }
    __syncthreads();
    #pragma unroll
    for (int g = 0; g < 16; g++) hl[t * 16 + g] = acc[g];
    __syncthreads();

    float* Mo = ws + WS_M;
    for (int jj = t; jj < 1024; jj += 256) {
        int pl2 = jj >> 4, g = jj & 15;
        float s = hl[(0 * 64 + pl2) * 16 + g] + hl[(1 * 64 + pl2) * 16 + g]
                + hl[(2 * 64 + pl2) * 16 + g] + hl[(3 * 64 + pl2) * 16 + g];
        int pg = pt * 64 + pl2;
        if (pg < P)
            Mo[((size_t)b * P + pg) * 16 + g] = s + ws[WS_BCP + pg];
    }
}

// ---------------------------------------------------------------------------
// k_pred: MFMA bf16 GEMM  acc[p][c] = BETA * sum_u Whp2[p][u] x[b][u][c]
// + fused epilogue.  grid (ptile=2, b=128), 256 threads = 4 waves (2M x 2N),
// wave tile 96x64 = 6x4 fragments of 16x16x32.
// m92/m93-verified pattern: A-subtile [m][k], B^T-subtile [n][k], fragments
// read as plain short8 at row (lane&15), k-slice 8*(lane>>4); C/D per m89.
// LDS stored as [sub][kgroup][idx16][8] -> uniform bank load on every access.
__global__ __launch_bounds__(256, 2) void k_pred(
    const float* __restrict__ x,
    const float* __restrict__ W3, const float* __restrict__ b3,
    const float* __restrict__ ws, float* __restrict__ out)
{
    __shared__ __align__(16) unsigned short As[2][12][4][16][8];  // 49152 B
    __shared__ __align__(16) unsigned short Bs[2][8][4][16][8];   // 32768 B
    const int ptile = blockIdx.x;        // 0,1
    const int b     = blockIdx.y;
    const int t     = threadIdx.x;
    const int lane  = t & 63;
    const int wid   = t >> 6;
    const int wm    = wid >> 1;          // 0,1
    const int wn    = wid & 1;           // 0,1
    const int g     = lane >> 4;         // 0..3  (k-group)
    const int n16   = lane & 15;         // row/col within fragment

    const float* xb = x + (size_t)b * S * C;
    const uint4* aimg = (const uint4*)ws;     // A-image, uint4 granularity

    f32x4 acc[6][4];
    #pragma unroll
    for (int i = 0; i < 6; i++)
        #pragma unroll
        for (int j = 0; j < 4; j++) acc[i][j] = (f32x4){0.f, 0.f, 0.f, 0.f};

    uint4 pa[3];      // A prefetch: 3 x 16B per lane
    uint4 pbw[2];     // B prefetch: 2 x (8 bf16 packed) per lane
    int   pbc[2], pbk[2];

    // ---- helpers as lambdas ----
    auto load_tile = [&](int kt) {
        const uint4* asrc = aimg + (size_t)(kt * 2 + ptile) * 768;
        #pragma unroll
        for (int i = 0; i < 3; i++)
            pa[i] = asrc[i * 256 + t];
        #pragma unroll
        for (int i = 0; i < 2; i++) {
            int chunk = i * 256 + t;
            int c = chunk & 127, kg = chunk >> 7;
            const float* xs = xb + (size_t)(32 * kt + 8 * kg) * C + c;
            float f0 = xs[0*C], f1 = xs[1*C], f2 = xs[2*C], f3 = xs[3*C];
            float f4 = xs[4*C], f5 = xs[5*C], f6 = xs[6*C], f7 = xs[7*C];
            uint4 w;
            w.x = f2bf(f0) | (f2bf(f1) << 16);
            w.y = f2bf(f2) | (f2bf(f3) << 16);
            w.z = f2bf(f4) | (f2bf(f5) << 16);
            w.w = f2bf(f6) | (f2bf(f7) << 16);
            pbw[i] = w; pbc[i] = c; pbk[i] = kg;
        }
    };
    auto write_tile = [&](int buf) {
        #pragma unroll
        for (int i = 0; i < 3; i++)
            ((uint4*)As[buf])[i * 256 + t] = pa[i];
        #pragma unroll
        for (int i = 0; i < 2; i++)
            *(uint4*)&Bs[buf][pbc[i] >> 4][pbk[i]][pbc[i] & 15][0] = pbw[i];
    };

    // prologue: tile 0
    load_tile(0);
    write_tile(0);
    __syncthreads();

    for (int kt = 0; kt < 32; kt++) {
        if (kt < 31) load_tile(kt + 1);

        const int buf = kt & 1;
        s16x8 fa[6], fb[4];
        #pragma unroll
        for (int fi = 0; fi < 6; fi++)
            fa[fi] = *(const s16x8*)&As[buf][6 * wm + fi][g][n16][0];
        #pragma unroll
        for (int fj = 0; fj < 4; fj++)
            fb[fj] = *(const s16x8*)&Bs[buf][4 * wn + fj][g][n16][0];

        #pragma unroll
        for (int fi = 0; fi < 6; fi++)
            #pragma unroll
            for (int fj = 0; fj < 4; fj++)
                acc[fi][fj] = __builtin_amdgcn_mfma_f32_16x16x32_bf16(
                    fa[fi], fb[fj], acc[fi][fj], 0, 0, 0);

        __syncthreads();
        if (kt < 31) {
            write_tile(buf ^ 1);
            __syncthreads();
        }
    }

    // ---- epilogue ----
    // res = acc + sd_c*(OMB*sum_g M[p][g]W3[c][g] + A13 + A4*b3[c]) + A2*mn_c
    const int cb = wn * 64 + n16;
    float sdv[4], mnv[4], b3v[4];
    f32x4 w3r[4][4];
    #pragma unroll
    for (int fj = 0; fj < 4; fj++) {
        int c = cb + fj * 16;
        sdv[fj] = ws[WS_STD  + b * C + c];
        mnv[fj] = ws[WS_MEAN + b * C + c];
        b3v[fj] = b3[c];
        const f32x4* wr = (const f32x4*)(W3 + c * 16);
        #pragma unroll
        for (int q = 0; q < 4; q++) w3r[fj][q] = wr[q];
    }
    const int prow0 = ptile * 192 + wm * 96 + g * 4;
    #pragma unroll
    for (int fi = 0; fi < 6; fi++) {
        #pragma unroll
        for (int r = 0; r < 4; r++) {
            int p  = prow0 + fi * 16 + r;
            int pc = p < P ? p : P - 1;
            const f32x4* mrow = (const f32x4*)(ws + WS_M + ((size_t)b * P + pc) * 16);
            f32x4 m0 = mrow[0], m1 = mrow[1], m2 = mrow[2], m3 = mrow[3];
            const float* e = ws + WS_EPI + pc * 4;
            float A13 = e[0], A4 = e[1], A2 = e[2];
            #pragma unroll
            for (int fj = 0; fj < 4; fj++) {
                float s = 0.f;
                #pragma unroll
                for (int q = 0; q < 4; q++) {
                    const f32x4 mv = (q==0)?m0:(q==1)?m1:(q==2)?m2:m3;
                    s = fmaf(mv.x, w3r[fj][q].x, s);
                    s = fmaf(mv.y, w3r[fj][q].y, s);
                    s = fmaf(mv.z, w3r[fj][q].z, s);
                    s = fmaf(mv.w, w3r[fj][q].w, s);
                }
                float res = acc[fi][fj][r]
                          + sdv[fj] * (OMBf * s + A13 + A4 * b3v[fj])
                          + A2 * mnv[fj];
                if (p < P)
                    out[((size_t)b * P + p) * C + cb + fj * 16] = res;
            }
        }
    }
}

// ---------------------------------------------------------------------------
extern "C" void kernel_launch(void* const* d_in, const int* in_sizes, int n_in,
                              void* d_out, int out_size, void* d_ws, size_t ws_size,
                              hipStream_t stream)
{
    const float* x    = (const float*)d_in[0];
    const float* xme  = (const float*)d_in[1];
    const float* W1   = (const float*)d_in[4];
    const float* b1   = (const float*)d_in[5];
    const float* g1   = (const float*)d_in[6];
    const float* be1  = (const float*)d_in[7];
    const float* W2   = (const float*)d_in[8];
    const float* b2   = (const float*)d_in[9];
    const float* g2   = (const float*)d_in[10];
    const float* be2  = (const float*)d_in[11];
    const float* Wc   = (const float*)d_in[12];
    const float* bc   = (const float*)d_in[13];
    const float* W3   = (const float*)d_in[14];
    const float* b3   = (const float*)d_in[15];
    const float* Wtp  = (const float*)d_in[16];
    const float* btp  = (const float*)d_in[17];
    const float* Whp  = (const float*)d_in[18];
    const float* bhp  = (const float*)d_in[19];
    float* ws  = (float*)d_ws;
    float* out = (float*)d_out;

    k_prep  <<<dim3(P),      dim3(256), 0, stream>>>(Whp, Wtp, bc, bhp, btp, ws);
    k_stats1<<<dim3(B, 4),   dim3(256), 0, stream>>>(x, ws);
    k_stats2<<<dim3(64),     dim3(256), 0, stream>>>(ws);
    k_mlp   <<<dim3(512),    dim3(256), 0, stream>>>(xme, W1, b1, g1, be1,
                                                     W2, b2, g2, be2, ws);
    k_wcp   <<<dim3(12, 28), dim3(256), 0, stream>>>(Wc, Wtp, ws);
    k_mconv <<<dim3(B, 6),   dim3(256), 0, stream>>>(ws);
    k_pred  <<<dim3(2, B),   dim3(256), 0, stream>>>(x, W3, b3, ws, out);
}

// Round 5
// 228.276 us; speedup vs baseline: 3.4381x; 1.6466x over previous
//
#include <hip/hip_runtime.h>
#include <hip/hip_bf16.h>

#define INV_SQRT2f 0.70710678118654752440f
#define BETAf 0.3f
#define OMBf  0.7f
#define LN_EPSf 1e-5f

#define B 128
#define S 1024
#define P 336
#define C 128
#define H1 32
#define H2 16

// ---------------- workspace layout (float offsets) ----------------
// NOTE overlay: WS_M overlays old WCPT region (WCPT dead after k_repack);
// WS_AIMG takes the old WS_M slot. Zero net growth.
#define WS_WHP2G  0               // bf16 A-image for k_pred, 786432 B
#define WS_EPI    262144          // float4[384]: {A13, A4, A2, -}
#define WS_MEAN   263680          // 16384
#define WS_STD    280064          // 16384
#define WS_BCP    296448          // 384
#define WS_H2     296832          // 128*1024*16 = 2097152
#define WS_WCPT   2393984         // fp32 [m=3072][p=336] = 1032192 (dead after repack)
#define WS_M      2393984         // 128*336*16 = 688128  (overlays WCPT)
#define WS_AIMG   3426176         // bf16 conv A-image, 2359296 B = 589824 fl
#define WS_EVP    4114304         // 65536
#define WS_SQP    4179840         // 65536
// total 4245376 floats = 16.98 MB

typedef short  s16x8 __attribute__((ext_vector_type(8)));
typedef float  f32x4 __attribute__((ext_vector_type(4)));

// exact RNE float->bf16
__device__ __forceinline__ unsigned f2bf(float f) {
    unsigned u = __float_as_uint(f);
    return (u + 0x7fffu + ((u >> 16) & 1u)) >> 16;
}

// k_pred A-image u32 index for the pair (u=2sp, u=2sp+1) of projection row p.
__device__ __forceinline__ int whp2l_u32(int p, int sp) {
    int kt   = sp >> 4;
    int tile = kt * 2 + p / 192;
    int sub  = (p % 192) >> 4;
    int kg   = (sp & 15) >> 2;
    int m    = p & 15;
    int byte = tile * 12288 + sub * 1024 + kg * 256 + m * 16 + 4 * (sp & 3);
    return byte >> 2;
}

// ---------------------------------------------------------------------------
// k_prep: bf16 A-image (Haar-folded, BETA-scaled Whp2) + EPI + bcP
__global__ void k_prep(const float* __restrict__ Whp, const float* __restrict__ Wtp,
                       const float* __restrict__ bc,  const float* __restrict__ bhp,
                       const float* __restrict__ btp, float* __restrict__ ws)
{
    const int p = blockIdx.x;     // 0..335
    const int t = threadIdx.x;    // 256
    unsigned* img = (unsigned*)ws;
    __shared__ float red[768];
    float sw = 0.f, rw = 0.f, bp = 0.f;
    for (int sp = t; sp < 512; sp += 256) {
        float a = Whp[p * 1024 + sp];
        float d = Whp[p * 1024 + 512 + sp];
        float va = BETAf * (a + d) * INV_SQRT2f;   // u = 2sp
        float vb = BETAf * (a - d) * INV_SQRT2f;   // u = 2sp+1
        img[whp2l_u32(p, sp)] = f2bf(va) | (f2bf(vb) << 16);
        sw += a + d;
    }
    for (int s = t; s < S; s += 256) {
        float w = Wtp[p * 1024 + s];
        rw += w;
        bp += w * bc[s];
    }
    red[t] = sw; red[256 + t] = rw; red[512 + t] = bp;
    __syncthreads();
    for (int off = 128; off > 0; off >>= 1) {
        if (t < off) {
            red[t]       += red[t + off];
            red[256 + t] += red[256 + t + off];
            red[512 + t] += red[512 + t + off];
        }
        __syncthreads();
    }
    if (t == 0) {
        ws[WS_BCP + p] = red[512];
        float* e = ws + WS_EPI + p * 4;
        e[0] = BETAf * bhp[p] + OMBf * btp[p];   // A13
        e[1] = OMBf * red[256];                  // A4 = OMB*rowWtp
        e[2] = 1.f - BETAf * red[0];             // A2 = 1-BETA*sumWhp
        e[3] = 0.f;
    }
}

// ---------------------------------------------------------------------------
// stats pass 1
__global__ void k_stats1(const float* __restrict__ x, float* __restrict__ ws)
{
    const int b = blockIdx.x;
    const int j = blockIdx.y;       // 0..3
    const int t = threadIdx.x;      // 256
    const int c = t & 127;
    const int half = t >> 7;
    const float* xb = x + (size_t)b * S * C;
    const int ub = j * 256 + half * 128;
    float ev = 0.f, sq = 0.f;
    #pragma unroll 4
    for (int it = 0; it < 128; it += 2) {
        float v0 = xb[(size_t)(ub + it) * C + c];
        float v1 = xb[(size_t)(ub + it + 1) * C + c];
        ev += v0;
        sq += v0 * v0 + v1 * v1;
    }
    __shared__ float evb[256], sqb[256];
    evb[t] = ev; sqb[t] = sq;
    __syncthreads();
    if (t < 128) {
        ws[WS_EVP + ((size_t)b * 4 + j) * 128 + c] = evb[c] + evb[128 + c];
        ws[WS_SQP + ((size_t)b * 4 + j) * 128 + c] = sqb[c] + sqb[128 + c];
    }
}

__global__ void k_stats2(float* __restrict__ ws)
{
    const int idx = blockIdx.x * 256 + threadIdx.x;
    const int b = idx >> 7, c = idx & 127;
    float ev = 0.f, sq = 0.f;
    #pragma unroll
    for (int j = 0; j < 4; j++) {
        ev += ws[WS_EVP + ((size_t)b * 4 + j) * 128 + c];
        sq += ws[WS_SQP + ((size_t)b * 4 + j) * 128 + c];
    }
    float mean = ev * (INV_SQRT2f / 512.f);
    float var  = (sq - 1024.f * mean * mean) * (1.f / 1023.f);
    ws[WS_MEAN + idx] = mean;
    ws[WS_STD + idx]  = sqrtf(var + LN_EPSf);
}

// ---------------------------------------------------------------------------
// MLP
__global__ void k_mlp(const float* __restrict__ xme,
                      const float* __restrict__ W1, const float* __restrict__ b1,
                      const float* __restrict__ g1, const float* __restrict__ be1,
                      const float* __restrict__ W2, const float* __restrict__ b2,
                      const float* __restrict__ g2, const float* __restrict__ be2,
                      float* __restrict__ ws)
{
    __shared__ float w1s[128], b1s[32], g1s[32], be1s[32];
    __shared__ float w2s[512], b2s[16], g2s[16], be2s[16];
    const int t = threadIdx.x;
    if (t < 128) w1s[t] = W1[t];
    if (t < 32) { b1s[t] = b1[t]; g1s[t] = g1[t]; be1s[t] = be1[t]; }
    for (int i = t; i < 512; i += 256) w2s[i] = W2[i];
    if (t < 16) { b2s[t] = b2[t]; g2s[t] = g2[t]; be2s[t] = be2[t]; }
    __syncthreads();

    const int row = blockIdx.x * 256 + t;
    float4 v = *(const float4*)(xme + (size_t)row * 4);

    float h1v[32];
    float m = 0.f;
    #pragma unroll
    for (int i = 0; i < 32; i++) {
        float a = w1s[i*4+0]*v.x + w1s[i*4+1]*v.y + w1s[i*4+2]*v.z + w1s[i*4+3]*v.w + b1s[i];
        h1v[i] = a; m += a;
    }
    m *= (1.f / 32.f);
    float var = 0.f;
    #pragma unroll
    for (int i = 0; i < 32; i++) { float d = h1v[i] - m; var += d * d; }
    var *= (1.f / 32.f);
    float rs = rsqrtf(var + LN_EPSf);
    #pragma unroll
    for (int i = 0; i < 32; i++)
        h1v[i] = fmaxf((h1v[i] - m) * rs * g1s[i] + be1s[i], 0.f);

    float h2v[16];
    float m2 = 0.f;
    #pragma unroll
    for (int g = 0; g < 16; g++) {
        float a = b2s[g];
        #pragma unroll
        for (int i = 0; i < 32; i++) a = fmaf(w2s[g * 32 + i], h1v[i], a);
        h2v[g] = a; m2 += a;
    }
    m2 *= (1.f / 16.f);
    float v2 = 0.f;
    #pragma unroll
    for (int g = 0; g < 16; g++) { float d = h2v[g] - m2; v2 += d * d; }
    v2 *= (1.f / 16.f);
    float rs2 = rsqrtf(v2 + LN_EPSf);
    float* h2o = ws + WS_H2 + (size_t)row * 16;
    #pragma unroll
    for (int g = 0; g < 16; g++)
        h2o[g] = fmaxf((h2v[g] - m2) * rs2 * g2s[g] + be2s[g], 0.f);
}

// ---------------------------------------------------------------------------
// WcPT[m][p] = sum_o Wtp[p,o] * Wc[o, m]   (unchanged, known-good)
__global__ __launch_bounds__(256) void k_wcp(const float* __restrict__ Wc,
                                             const float* __restrict__ Wtp,
                                             float* __restrict__ ws)
{
    __shared__ float wtpT[1024 * 12];
    const int t = threadIdx.x;
    const int p0 = blockIdx.y * 12;
    for (int q = 0; q < 12; q++)
        for (int s = t; s < 1024; s += 256)
            wtpT[s * 12 + q] = Wtp[(size_t)(p0 + q) * 1024 + s];
    __syncthreads();

    const int m = blockIdx.x * 256 + t;
    float acc[12];
    #pragma unroll
    for (int q = 0; q < 12; q++) acc[q] = 0.f;

    for (int s = 0; s < 1024; s++) {
        float wv = Wc[(size_t)s * 3072 + m];
        const float4* w4 = (const float4*)(wtpT + s * 12);
        float4 a0 = w4[0], a1 = w4[1], a2 = w4[2];
        acc[0] = fmaf(a0.x, wv, acc[0]); acc[1]  = fmaf(a0.y, wv, acc[1]);
        acc[2] = fmaf(a0.z, wv, acc[2]); acc[3]  = fmaf(a0.w, wv, acc[3]);
        acc[4] = fmaf(a1.x, wv, acc[4]); acc[5]  = fmaf(a1.y, wv, acc[5]);
        acc[6] = fmaf(a1.z, wv, acc[6]); acc[7]  = fmaf(a1.w, wv, acc[7]);
        acc[8] = fmaf(a2.x, wv, acc[8]); acc[9]  = fmaf(a2.y, wv, acc[9]);
        acc[10] = fmaf(a2.z, wv, acc[10]); acc[11] = fmaf(a2.w, wv, acc[11]);
    }
    float* o = ws + WS_WCPT + (size_t)m * 336 + p0;
    *(float4*)(o)     = make_float4(acc[0], acc[1], acc[2],  acc[3]);
    *(float4*)(o + 4) = make_float4(acc[4], acc[5], acc[6],  acc[7]);
    *(float4*)(o + 8) = make_float4(acc[8], acc[9], acc[10], acc[11]);
}

// ---------------------------------------------------------------------------
// k_repack: fp32 WcPT[m][p]  ->  bf16 MFMA A-image.
// chunk ch = (k*32+kt)*24 + pfrag (1024 B): lane l holds A_k[pfrag*16+(l&15)]
// [i = kt*32 + (l>>4)*8 + e], e=0..7 -> one dwordx4 per lane.
__global__ void k_repack(float* __restrict__ ws)
{
    const int l  = threadIdx.x;          // 0..63
    const int ch = blockIdx.x;           // k*32+kt, 0..95
    const int pf = blockIdx.y;           // 0..23
    const int k  = ch >> 5;
    const int i0 = (ch & 31) * 32 + (l >> 4) * 8;
    const int p  = pf * 16 + (l & 15);
    uint4 w = make_uint4(0, 0, 0, 0);
    if (p < P) {
        const float* wc = ws + WS_WCPT;
        float v[8];
        #pragma unroll
        for (int e = 0; e < 8; e++)
            v[e] = wc[(size_t)((i0 + e) * 3 + k) * 336 + p];
        w.x = f2bf(v[0]) | (f2bf(v[1]) << 16);
        w.y = f2bf(v[2]) | (f2bf(v[3]) << 16);
        w.z = f2bf(v[4]) | (f2bf(v[5]) << 16);
        w.w = f2bf(v[6]) | (f2bf(v[7]) << 16);
    }
    ((uint4*)(ws + WS_AIMG))[(size_t)(ch * 24 + pf) * 64 + l] = w;
}

// ---------------------------------------------------------------------------
// k_mconv (MFMA): M[b,p,g] = bcP[p] + sum_k sum_i A_k[p][i] * h[b,i,g+k-1]
// grid (b=128, ptile=6), 256 thr = 4 waves, 1 p-fragment (16 rows) per wave.
// Ht LDS rows g' = -1..16 (18 rows), row stride 2112 B == 64 (mod 1024) so a
// wave b128 read (16 consecutive rows x 4 g-groups) tiles 1024 B: conflict-free.
#define HT_RS 1056            /* u16 elems per row (2112 B) */
__global__ __launch_bounds__(256) void k_mconv(float* __restrict__ ws)
{
    __shared__ unsigned short Ht[18 * HT_RS];   // 38016 B
    const int b  = blockIdx.x;
    const int pt = blockIdx.y;                  // 0..5
    const int t  = threadIdx.x;
    const int l  = t & 63;
    const int wid = t >> 6;
    const int pf = pt * 4 + wid;                // 0..23
    const int n16 = l & 15;
    const int g8  = l >> 4;

    // zero guard rows (g'=-1 and g'=16)
    for (int j = t; j < HT_RS; j += 256) {
        Ht[j] = 0;
        Ht[17 * HT_RS + j] = 0;
    }
    // transpose-stage h[b]: rows 1..16 hold h[s][g] at Ht[(g+1)*HT_RS + s]
    {
        const float* h2b = ws + WS_H2 + (size_t)b * 16384;
        const int s0 = t * 4;
        float v[4][16];
        #pragma unroll
        for (int rr = 0; rr < 4; rr++) {
            const float4* src = (const float4*)(h2b + (size_t)(s0 + rr) * 16);
            float4 a0 = src[0], a1 = src[1], a2 = src[2], a3 = src[3];
            v[rr][0]=a0.x; v[rr][1]=a0.y; v[rr][2]=a0.z; v[rr][3]=a0.w;
            v[rr][4]=a1.x; v[rr][5]=a1.y; v[rr][6]=a1.z; v[rr][7]=a1.w;
            v[rr][8]=a2.x; v[rr][9]=a2.y; v[rr][10]=a2.z; v[rr][11]=a2.w;
            v[rr][12]=a3.x; v[rr][13]=a3.y; v[rr][14]=a3.z; v[rr][15]=a3.w;
        }
        #pragma unroll
        for (int g = 0; g < 16; g++) {
            uint2 w;
            w.x = f2bf(v[0][g]) | (f2bf(v[1][g]) << 16);
            w.y = f2bf(v[2][g]) | (f2bf(v[3][g]) << 16);
            *(uint2*)&Ht[(g + 1) * HT_RS + s0] = w;
        }
    }
    __syncthreads();

    const uint4* ap = (const uint4*)(ws + WS_AIMG) + (size_t)pf * 64 + l;
    f32x4 acc = (f32x4){0.f, 0.f, 0.f, 0.f};
    uint4 fan = *ap;                    // prefetch it=0
    #pragma unroll 4
    for (int it = 0; it < 96; it++) {
        uint4 fac = fan;
        ap += 24 * 64;
        if (it < 95) fan = *ap;
        const int k  = it >> 5;
        const int kt = it & 31;
        s16x8 fb = *(const s16x8*)&Ht[(n16 + k) * HT_RS + kt * 32 + g8 * 8];
        s16x8 fa = *(s16x8*)&fac;
        acc = __builtin_amdgcn_mfma_f32_16x16x32_bf16(fa, fb, acc, 0, 0, 0);
    }

    // C/D per m89: col = lane&15 = g, row = (lane>>4)*4 + r = p-within-frag
    #pragma unroll
    for (int r = 0; r < 4; r++) {
        int p = pf * 16 + g8 * 4 + r;
        if (p < P)
            ws[WS_M + ((size_t)b * P + p) * 16 + n16] = acc[r] + ws[WS_BCP + p];
    }
}

// ---------------------------------------------------------------------------
// k_pred: MFMA bf16 GEMM + fused epilogue (unchanged from passing round 4).
__global__ __launch_bounds__(256, 2) void k_pred(
    const float* __restrict__ x,
    const float* __restrict__ W3, const float* __restrict__ b3,
    const float* __restrict__ ws, float* __restrict__ out)
{
    __shared__ __align__(16) unsigned short As[2][12][4][16][8];  // 49152 B
    __shared__ __align__(16) unsigned short Bs[2][8][4][16][8];   // 32768 B
    const int ptile = blockIdx.x;        // 0,1
    const int b     = blockIdx.y;
    const int t     = threadIdx.x;
    const int lane  = t & 63;
    const int wid   = t >> 6;
    const int wm    = wid >> 1;          // 0,1
    const int wn    = wid & 1;           // 0,1
    const int g     = lane >> 4;         // 0..3  (k-group)
    const int n16   = lane & 15;         // row/col within fragment

    const float* xb = x + (size_t)b * S * C;
    const uint4* aimg = (const uint4*)ws;

    f32x4 acc[6][4];
    #pragma unroll
    for (int i = 0; i < 6; i++)
        #pragma unroll
        for (int j = 0; j < 4; j++) acc[i][j] = (f32x4){0.f, 0.f, 0.f, 0.f};

    uint4 pa[3];
    uint4 pbw[2];
    int   pbc[2], pbk[2];

    auto load_tile = [&](int kt) {
        const uint4* asrc = aimg + (size_t)(kt * 2 + ptile) * 768;
        #pragma unroll
        for (int i = 0; i < 3; i++)
            pa[i] = asrc[i * 256 + t];
        #pragma unroll
        for (int i = 0; i < 2; i++) {
            int chunk = i * 256 + t;
            int c = chunk & 127, kg = chunk >> 7;
            const float* xs = xb + (size_t)(32 * kt + 8 * kg) * C + c;
            float f0 = xs[0*C], f1 = xs[1*C], f2 = xs[2*C], f3 = xs[3*C];
            float f4 = xs[4*C], f5 = xs[5*C], f6 = xs[6*C], f7 = xs[7*C];
            uint4 w;
            w.x = f2bf(f0) | (f2bf(f1) << 16);
            w.y = f2bf(f2) | (f2bf(f3) << 16);
            w.z = f2bf(f4) | (f2bf(f5) << 16);
            w.w = f2bf(f6) | (f2bf(f7) << 16);
            pbw[i] = w; pbc[i] = c; pbk[i] = kg;
        }
    };
    auto write_tile = [&](int buf) {
        #pragma unroll
        for (int i = 0; i < 3; i++)
            ((uint4*)As[buf])[i * 256 + t] = pa[i];
        #pragma unroll
        for (int i = 0; i < 2; i++)
            *(uint4*)&Bs[buf][pbc[i] >> 4][pbk[i]][pbc[i] & 15][0] = pbw[i];
    };

    load_tile(0);
    write_tile(0);
    __syncthreads();

    for (int kt = 0; kt < 32; kt++) {
        if (kt < 31) load_tile(kt + 1);

        const int buf = kt & 1;
        s16x8 fa[6], fb[4];
        #pragma unroll
        for (int fi = 0; fi < 6; fi++)
            fa[fi] = *(const s16x8*)&As[buf][6 * wm + fi][g][n16][0];
        #pragma unroll
        for (int fj = 0; fj < 4; fj++)
            fb[fj] = *(const s16x8*)&Bs[buf][4 * wn + fj][g][n16][0];

        #pragma unroll
        for (int fi = 0; fi < 6; fi++)
            #pragma unroll
            for (int fj = 0; fj < 4; fj++)
                acc[fi][fj] = __builtin_amdgcn_mfma_f32_16x16x32_bf16(
                    fa[fi], fb[fj], acc[fi][fj], 0, 0, 0);

        __syncthreads();
        if (kt < 31) {
            write_tile(buf ^ 1);
            __syncthreads();
        }
    }

    // ---- epilogue ----
    const int cb = wn * 64 + n16;
    float sdv[4], mnv[4], b3v[4];
    f32x4 w3r[4][4];
    #pragma unroll
    for (int fj = 0; fj < 4; fj++) {
        int c = cb + fj * 16;
        sdv[fj] = ws[WS_STD  + b * C + c];
        mnv[fj] = ws[WS_MEAN + b * C + c];
        b3v[fj] = b3[c];
        const f32x4* wr = (const f32x4*)(W3 + c * 16);
        #pragma unroll
        for (int q = 0; q < 4; q++) w3r[fj][q] = wr[q];
    }
    const int prow0 = ptile * 192 + wm * 96 + g * 4;
    #pragma unroll
    for (int fi = 0; fi < 6; fi++) {
        #pragma unroll
        for (int r = 0; r < 4; r++) {
            int p  = prow0 + fi * 16 + r;
            int pc = p < P ? p : P - 1;
            const f32x4* mrow = (const f32x4*)(ws + WS_M + ((size_t)b * P + pc) * 16);
            f32x4 m0 = mrow[0], m1 = mrow[1], m2 = mrow[2], m3 = mrow[3];
            const float* e = ws + WS_EPI + pc * 4;
            float A13 = e[0], A4 = e[1], A2 = e[2];
            #pragma unroll
            for (int fj = 0; fj < 4; fj++) {
                float s = 0.f;
                #pragma unroll
                for (int q = 0; q < 4; q++) {
                    const f32x4 mv = (q==0)?m0:(q==1)?m1:(q==2)?m2:m3;
                    s = fmaf(mv.x, w3r[fj][q].x, s);
                    s = fmaf(mv.y, w3r[fj][q].y, s);
                    s = fmaf(mv.z, w3r[fj][q].z, s);
                    s = fmaf(mv.w, w3r[fj][q].w, s);
                }
                float res = acc[fi][fj][r]
                          + sdv[fj] * (OMBf * s + A13 + A4 * b3v[fj])
                          + A2 * mnv[fj];
                if (p < P)
                    out[((size_t)b * P + p) * C + cb + fj * 16] = res;
            }
        }
    }
}

// ---------------------------------------------------------------------------
extern "C" void kernel_launch(void* const* d_in, const int* in_sizes, int n_in,
                              void* d_out, int out_size, void* d_ws, size_t ws_size,
                              hipStream_t stream)
{
    const float* x    = (const float*)d_in[0];
    const float* xme  = (const float*)d_in[1];
    const float* W1   = (const float*)d_in[4];
    const float* b1   = (const float*)d_in[5];
    const float* g1   = (const float*)d_in[6];
    const float* be1  = (const float*)d_in[7];
    const float* W2   = (const float*)d_in[8];
    const float* b2   = (const float*)d_in[9];
    const float* g2   = (const float*)d_in[10];
    const float* be2  = (const float*)d_in[11];
    const float* Wc   = (const float*)d_in[12];
    const float* bc   = (const float*)d_in[13];
    const float* W3   = (const float*)d_in[14];
    const float* b3   = (const float*)d_in[15];
    const float* Wtp  = (const float*)d_in[16];
    const float* btp  = (const float*)d_in[17];
    const float* Whp  = (const float*)d_in[18];
    const float* bhp  = (const float*)d_in[19];
    float* ws  = (float*)d_ws;
    float* out = (float*)d_out;

    k_prep  <<<dim3(P),      dim3(256), 0, stream>>>(Whp, Wtp, bc, bhp, btp, ws);
    k_stats1<<<dim3(B, 4),   dim3(256), 0, stream>>>(x, ws);
    k_stats2<<<dim3(64),     dim3(256), 0, stream>>>(ws);
    k_mlp   <<<dim3(512),    dim3(256), 0, stream>>>(xme, W1, b1, g1, be1,
                                                     W2, b2, g2, be2, ws);
    k_wcp   <<<dim3(12, 28), dim3(256), 0, stream>>>(Wc, Wtp, ws);
    k_repack<<<dim3(96, 24), dim3(64),  0, stream>>>(ws);
    k_mconv <<<dim3(B, 6),   dim3(256), 0, stream>>>(ws);
    k_pred  <<<dim3(2, B),   dim3(256), 0, stream>>>(x, W3, b3, ws, out);
}

// Round 6
// 191.069 us; speedup vs baseline: 4.1076x; 1.1947x over previous
//
#include <hip/hip_runtime.h>
#include <hip/hip_bf16.h>

#define INV_SQRT2f 0.70710678118654752440f
#define BETAf 0.3f
#define OMBf  0.7f
#define LN_EPSf 1e-5f

#define B 128
#define S 1024
#define P 336
#define C 128
#define H1 32
#define H2 16

// ---------------- workspace layout (float offsets) ----------------
// WS_WCPT now holds WcPT TRANSPOSED: [p=336][m3=3072] fp32 (dead after repack);
// WS_M overlays it (mconv runs after repack). WS_AIMG = conv bf16 A-image.
#define WS_WHP2G  0               // bf16 A-image for k_pred, 786432 B
#define WS_EPI    262144          // float4[384]: {A13, A4, A2, -}
#define WS_MEAN   263680          // 16384
#define WS_STD    280064          // 16384
#define WS_BCP    296448          // 384
#define WS_H2     296832          // 128*1024*16 = 2097152
#define WS_WCPT   2393984         // fp32 [p=336][m=3072] = 1032192 (dead after repack)
#define WS_M      2393984         // 128*336*16 = 688128  (overlays WCPT)
#define WS_AIMG   3426176         // bf16 conv A-image, 2359296 B = 589824 fl
#define WS_EVP    4114304         // 65536
#define WS_SQP    4179840         // 65536
// total 4245376 floats = 16.98 MB

typedef short  s16x8 __attribute__((ext_vector_type(8)));
typedef float  f32x4 __attribute__((ext_vector_type(4)));

// exact RNE float->bf16
__device__ __forceinline__ unsigned f2bf(float f) {
    unsigned u = __float_as_uint(f);
    return (u + 0x7fffu + ((u >> 16) & 1u)) >> 16;
}

// k_pred A-image u32 index for the pair (u=2sp, u=2sp+1) of projection row p.
__device__ __forceinline__ int whp2l_u32(int p, int sp) {
    int kt   = sp >> 4;
    int tile = kt * 2 + p / 192;
    int sub  = (p % 192) >> 4;
    int kg   = (sp & 15) >> 2;
    int m    = p & 15;
    int byte = tile * 12288 + sub * 1024 + kg * 256 + m * 16 + 4 * (sp & 3);
    return byte >> 2;
}

// ---------------------------------------------------------------------------
// k_prep: bf16 A-image (Haar-folded, BETA-scaled Whp2) + EPI + bcP
__global__ void k_prep(const float* __restrict__ Whp, const float* __restrict__ Wtp,
                       const float* __restrict__ bc,  const float* __restrict__ bhp,
                       const float* __restrict__ btp, float* __restrict__ ws)
{
    const int p = blockIdx.x;     // 0..335
    const int t = threadIdx.x;    // 256
    unsigned* img = (unsigned*)ws;
    __shared__ float red[768];
    float sw = 0.f, rw = 0.f, bp = 0.f;
    for (int sp = t; sp < 512; sp += 256) {
        float a = Whp[p * 1024 + sp];
        float d = Whp[p * 1024 + 512 + sp];
        float va = BETAf * (a + d) * INV_SQRT2f;   // u = 2sp
        float vb = BETAf * (a - d) * INV_SQRT2f;   // u = 2sp+1
        img[whp2l_u32(p, sp)] = f2bf(va) | (f2bf(vb) << 16);
        sw += a + d;
    }
    for (int s = t; s < S; s += 256) {
        float w = Wtp[p * 1024 + s];
        rw += w;
        bp += w * bc[s];
    }
    red[t] = sw; red[256 + t] = rw; red[512 + t] = bp;
    __syncthreads();
    for (int off = 128; off > 0; off >>= 1) {
        if (t < off) {
            red[t]       += red[t + off];
            red[256 + t] += red[256 + t + off];
            red[512 + t] += red[512 + t + off];
        }
        __syncthreads();
    }
    if (t == 0) {
        ws[WS_BCP + p] = red[512];
        float* e = ws + WS_EPI + p * 4;
        e[0] = BETAf * bhp[p] + OMBf * btp[p];   // A13
        e[1] = OMBf * red[256];                  // A4 = OMB*rowWtp
        e[2] = 1.f - BETAf * red[0];             // A2 = 1-BETA*sumWhp
        e[3] = 0.f;
    }
}

// ---------------------------------------------------------------------------
// stats pass 1
__global__ void k_stats1(const float* __restrict__ x, float* __restrict__ ws)
{
    const int b = blockIdx.x;
    const int j = blockIdx.y;       // 0..3
    const int t = threadIdx.x;      // 256
    const int c = t & 127;
    const int half = t >> 7;
    const float* xb = x + (size_t)b * S * C;
    const int ub = j * 256 + half * 128;
    float ev = 0.f, sq = 0.f;
    #pragma unroll 4
    for (int it = 0; it < 128; it += 2) {
        float v0 = xb[(size_t)(ub + it) * C + c];
        float v1 = xb[(size_t)(ub + it + 1) * C + c];
        ev += v0;
        sq += v0 * v0 + v1 * v1;
    }
    __shared__ float evb[256], sqb[256];
    evb[t] = ev; sqb[t] = sq;
    __syncthreads();
    if (t < 128) {
        ws[WS_EVP + ((size_t)b * 4 + j) * 128 + c] = evb[c] + evb[128 + c];
        ws[WS_SQP + ((size_t)b * 4 + j) * 128 + c] = sqb[c] + sqb[128 + c];
    }
}

__global__ void k_stats2(float* __restrict__ ws)
{
    const int idx = blockIdx.x * 256 + threadIdx.x;
    const int b = idx >> 7, c = idx & 127;
    float ev = 0.f, sq = 0.f;
    #pragma unroll
    for (int j = 0; j < 4; j++) {
        ev += ws[WS_EVP + ((size_t)b * 4 + j) * 128 + c];
        sq += ws[WS_SQP + ((size_t)b * 4 + j) * 128 + c];
    }
    float mean = ev * (INV_SQRT2f / 512.f);
    float var  = (sq - 1024.f * mean * mean) * (1.f / 1023.f);
    ws[WS_MEAN + idx] = mean;
    ws[WS_STD + idx]  = sqrtf(var + LN_EPSf);
}

// ---------------------------------------------------------------------------
// MLP
__global__ void k_mlp(const float* __restrict__ xme,
                      const float* __restrict__ W1, const float* __restrict__ b1,
                      const float* __restrict__ g1, const float* __restrict__ be1,
                      const float* __restrict__ W2, const float* __restrict__ b2,
                      const float* __restrict__ g2, const float* __restrict__ be2,
                      float* __restrict__ ws)
{
    __shared__ float w1s[128], b1s[32], g1s[32], be1s[32];
    __shared__ float w2s[512], b2s[16], g2s[16], be2s[16];
    const int t = threadIdx.x;
    if (t < 128) w1s[t] = W1[t];
    if (t < 32) { b1s[t] = b1[t]; g1s[t] = g1[t]; be1s[t] = be1[t]; }
    for (int i = t; i < 512; i += 256) w2s[i] = W2[i];
    if (t < 16) { b2s[t] = b2[t]; g2s[t] = g2[t]; be2s[t] = be2[t]; }
    __syncthreads();

    const int row = blockIdx.x * 256 + t;
    float4 v = *(const float4*)(xme + (size_t)row * 4);

    float h1v[32];
    float m = 0.f;
    #pragma unroll
    for (int i = 0; i < 32; i++) {
        float a = w1s[i*4+0]*v.x + w1s[i*4+1]*v.y + w1s[i*4+2]*v.z + w1s[i*4+3]*v.w + b1s[i];
        h1v[i] = a; m += a;
    }
    m *= (1.f / 32.f);
    float var = 0.f;
    #pragma unroll
    for (int i = 0; i < 32; i++) { float d = h1v[i] - m; var += d * d; }
    var *= (1.f / 32.f);
    float rs = rsqrtf(var + LN_EPSf);
    #pragma unroll
    for (int i = 0; i < 32; i++)
        h1v[i] = fmaxf((h1v[i] - m) * rs * g1s[i] + be1s[i], 0.f);

    float h2v[16];
    float m2 = 0.f;
    #pragma unroll
    for (int g = 0; g < 16; g++) {
        float a = b2s[g];
        #pragma unroll
        for (int i = 0; i < 32; i++) a = fmaf(w2s[g * 32 + i], h1v[i], a);
        h2v[g] = a; m2 += a;
    }
    m2 *= (1.f / 16.f);
    float v2 = 0.f;
    #pragma unroll
    for (int g = 0; g < 16; g++) { float d = h2v[g] - m2; v2 += d * d; }
    v2 *= (1.f / 16.f);
    float rs2 = rsqrtf(v2 + LN_EPSf);
    float* h2o = ws + WS_H2 + (size_t)row * 16;
    #pragma unroll
    for (int g = 0; g < 16; g++)
        h2o[g] = fmaxf((h2v[g] - m2) * rs2 * g2s[g] + be2s[g], 0.f);
}

// ---------------------------------------------------------------------------
// k_wcp (MFMA): WcPT_T[p][m3] = sum_o Wtp[p,o] * Wc[o, m3]
// Clone of the proven k_pred skeleton. M-dim = p (384 pad, A = Wtp, direct
// per-lane float4 loads: rows contiguous in o). N-dim = m3 (B = Wc staged
// via LDS subtiles exactly like k_pred's x staging). K = o = 1024, 32 steps.
// grid (ptile=2, mtile=24), 4 waves (2M x 2N), wave tile 96p x 64m3.
__global__ __launch_bounds__(256, 2) void k_wcp(const float* __restrict__ Wc,
                                                const float* __restrict__ Wtp,
                                                float* __restrict__ ws)
{
    __shared__ __align__(16) unsigned short Bs[2][8][4][16][8];   // 16384 B
    const int ptile = blockIdx.x;        // 0,1
    const int n0    = blockIdx.y * 128;  // m3 tile base
    const int t     = threadIdx.x;
    const int lane  = t & 63;
    const int wid   = t >> 6;
    const int wm    = wid >> 1;          // 0,1
    const int wn    = wid & 1;           // 0,1
    const int g8    = lane >> 4;         // 0..3  (k-group)
    const int n16   = lane & 15;

    // per-lane A rows (clamped; rows >= P produce discarded output)
    int prow[6];
    #pragma unroll
    for (int fi = 0; fi < 6; fi++) {
        int pr = ptile * 192 + wm * 96 + fi * 16 + n16;
        prow[fi] = pr < P ? pr : P - 1;
    }

    f32x4 acc[6][4];
    #pragma unroll
    for (int i = 0; i < 6; i++)
        #pragma unroll
        for (int j = 0; j < 4; j++) acc[i][j] = (f32x4){0.f, 0.f, 0.f, 0.f};

    uint4 pbw[2];            // B staging regs
    int   pbn[2], pbk[2];
    s16x8 fan[6];            // A fragments (next tile), packed at load

    auto load_tile = [&](int kt) {
        const int s0 = kt * 32;
        #pragma unroll
        for (int i = 0; i < 2; i++) {
            int chunk = i * 256 + t;
            int n = chunk & 127, kg = chunk >> 7;
            const float* xs = Wc + (size_t)(s0 + 8 * kg) * 3072 + n0 + n;
            float f0 = xs[0*3072], f1 = xs[1*3072], f2 = xs[2*3072], f3 = xs[3*3072];
            float f4 = xs[4*3072], f5 = xs[5*3072], f6 = xs[6*3072], f7 = xs[7*3072];
            uint4 w;
            w.x = f2bf(f0) | (f2bf(f1) << 16);
            w.y = f2bf(f2) | (f2bf(f3) << 16);
            w.z = f2bf(f4) | (f2bf(f5) << 16);
            w.w = f2bf(f6) | (f2bf(f7) << 16);
            pbw[i] = w; pbn[i] = n; pbk[i] = kg;
        }
        #pragma unroll
        for (int fi = 0; fi < 6; fi++) {
            const float* as = Wtp + (size_t)prow[fi] * 1024 + s0 + g8 * 8;
            float4 u = *(const float4*)(as);
            float4 v = *(const float4*)(as + 4);
            uint4 w;
            w.x = f2bf(u.x) | (f2bf(u.y) << 16);
            w.y = f2bf(u.z) | (f2bf(u.w) << 16);
            w.z = f2bf(v.x) | (f2bf(v.y) << 16);
            w.w = f2bf(v.z) | (f2bf(v.w) << 16);
            fan[fi] = *(s16x8*)&w;
        }
    };
    auto write_tile = [&](int buf) {
        #pragma unroll
        for (int i = 0; i < 2; i++)
            *(uint4*)&Bs[buf][pbn[i] >> 4][pbk[i]][pbn[i] & 15][0] = pbw[i];
    };

    load_tile(0);
    write_tile(0);
    s16x8 fa[6];
    #pragma unroll
    for (int fi = 0; fi < 6; fi++) fa[fi] = fan[fi];
    __syncthreads();

    for (int kt = 0; kt < 32; kt++) {
        if (kt < 31) load_tile(kt + 1);

        const int buf = kt & 1;
        s16x8 fb[4];
        #pragma unroll
        for (int fj = 0; fj < 4; fj++)
            fb[fj] = *(const s16x8*)&Bs[buf][4 * wn + fj][g8][n16][0];

        #pragma unroll
        for (int fi = 0; fi < 6; fi++)
            #pragma unroll
            for (int fj = 0; fj < 4; fj++)
                acc[fi][fj] = __builtin_amdgcn_mfma_f32_16x16x32_bf16(
                    fa[fi], fb[fj], acc[fi][fj], 0, 0, 0);

        __syncthreads();
        if (kt < 31) {
            write_tile(buf ^ 1);
            #pragma unroll
            for (int fi = 0; fi < 6; fi++) fa[fi] = fan[fi];
            __syncthreads();
        }
    }

    // C/D per m89: row (p within frag) = 4*g8 + r, col (m3 within frag) = n16
    float* wcT = ws + WS_WCPT;
    #pragma unroll
    for (int fi = 0; fi < 6; fi++) {
        #pragma unroll
        for (int r = 0; r < 4; r++) {
            int p = ptile * 192 + wm * 96 + fi * 16 + g8 * 4 + r;
            if (p < P) {
                #pragma unroll
                for (int fj = 0; fj < 4; fj++)
                    wcT[(size_t)p * 3072 + n0 + wn * 64 + fj * 16 + n16] =
                        acc[fi][fj][r];
            }
        }
    }
}

// ---------------------------------------------------------------------------
// k_repack: fp32 WcPT_T[p][m3]  ->  bf16 MFMA A-image.
// chunk ch = (k*32+kt)*24 + pfrag (1024 B): lane l holds A_k[pfrag*16+(l&15)]
// [i = kt*32 + (l>>4)*8 + e], e=0..7 -> one dwordx4 per lane.
__global__ void k_repack(float* __restrict__ ws)
{
    const int l  = threadIdx.x;          // 0..63
    const int ch = blockIdx.x;           // k*32+kt, 0..95
    const int pf = blockIdx.y;           // 0..23
    const int k  = ch >> 5;
    const int i0 = (ch & 31) * 32 + (l >> 4) * 8;
    const int p  = pf * 16 + (l & 15);
    uint4 w = make_uint4(0, 0, 0, 0);
    if (p < P) {
        const float* wcT = ws + WS_WCPT + (size_t)p * 3072;
        float v[8];
        #pragma unroll
        for (int e = 0; e < 8; e++)
            v[e] = wcT[(i0 + e) * 3 + k];
        w.x = f2bf(v[0]) | (f2bf(v[1]) << 16);
        w.y = f2bf(v[2]) | (f2bf(v[3]) << 16);
        w.z = f2bf(v[4]) | (f2bf(v[5]) << 16);
        w.w = f2bf(v[6]) | (f2bf(v[7]) << 16);
    }
    ((uint4*)(ws + WS_AIMG))[(size_t)(ch * 24 + pf) * 64 + l] = w;
}

// ---------------------------------------------------------------------------
// k_mconv (MFMA): M[b,p,g] = bcP[p] + sum_k sum_i A_k[p][i] * h[b,i,g+k-1]
#define HT_RS 1056            /* u16 elems per row (2112 B) */
__global__ __launch_bounds__(256) void k_mconv(float* __restrict__ ws)
{
    __shared__ unsigned short Ht[18 * HT_RS];   // 38016 B
    const int b  = blockIdx.x;
    const int pt = blockIdx.y;                  // 0..5
    const int t  = threadIdx.x;
    const int l  = t & 63;
    const int wid = t >> 6;
    const int pf = pt * 4 + wid;                // 0..23
    const int n16 = l & 15;
    const int g8  = l >> 4;

    for (int j = t; j < HT_RS; j += 256) {
        Ht[j] = 0;
        Ht[17 * HT_RS + j] = 0;
    }
    {
        const float* h2b = ws + WS_H2 + (size_t)b * 16384;
        const int s0 = t * 4;
        float v[4][16];
        #pragma unroll
        for (int rr = 0; rr < 4; rr++) {
            const float4* src = (const float4*)(h2b + (size_t)(s0 + rr) * 16);
            float4 a0 = src[0], a1 = src[1], a2 = src[2], a3 = src[3];
            v[rr][0]=a0.x; v[rr][1]=a0.y; v[rr][2]=a0.z; v[rr][3]=a0.w;
            v[rr][4]=a1.x; v[rr][5]=a1.y; v[rr][6]=a1.z; v[rr][7]=a1.w;
            v[rr][8]=a2.x; v[rr][9]=a2.y; v[rr][10]=a2.z; v[rr][11]=a2.w;
            v[rr][12]=a3.x; v[rr][13]=a3.y; v[rr][14]=a3.z; v[rr][15]=a3.w;
        }
        #pragma unroll
        for (int g = 0; g < 16; g++) {
            uint2 w;
            w.x = f2bf(v[0][g]) | (f2bf(v[1][g]) << 16);
            w.y = f2bf(v[2][g]) | (f2bf(v[3][g]) << 16);
            *(uint2*)&Ht[(g + 1) * HT_RS + s0] = w;
        }
    }
    __syncthreads();

    const uint4* ap = (const uint4*)(ws + WS_AIMG) + (size_t)pf * 64 + l;
    f32x4 acc = (f32x4){0.f, 0.f, 0.f, 0.f};
    uint4 fan = *ap;                    // prefetch it=0
    #pragma unroll 4
    for (int it = 0; it < 96; it++) {
        uint4 fac = fan;
        ap += 24 * 64;
        if (it < 95) fan = *ap;
        const int k  = it >> 5;
        const int kt = it & 31;
        s16x8 fb = *(const s16x8*)&Ht[(n16 + k) * HT_RS + kt * 32 + g8 * 8];
        s16x8 fa = *(s16x8*)&fac;
        acc = __builtin_amdgcn_mfma_f32_16x16x32_bf16(fa, fb, acc, 0, 0, 0);
    }

    #pragma unroll
    for (int r = 0; r < 4; r++) {
        int p = pf * 16 + g8 * 4 + r;
        if (p < P)
            ws[WS_M + ((size_t)b * P + p) * 16 + n16] = acc[r] + ws[WS_BCP + p];
    }
}

// ---------------------------------------------------------------------------
// k_pred: MFMA bf16 GEMM + fused epilogue (unchanged, passing).
__global__ __launch_bounds__(256, 2) void k_pred(
    const float* __restrict__ x,
    const float* __restrict__ W3, const float* __restrict__ b3,
    const float* __restrict__ ws, float* __restrict__ out)
{
    __shared__ __align__(16) unsigned short As[2][12][4][16][8];  // 49152 B
    __shared__ __align__(16) unsigned short Bs[2][8][4][16][8];   // 32768 B
    const int ptile = blockIdx.x;        // 0,1
    const int b     = blockIdx.y;
    const int t     = threadIdx.x;
    const int lane  = t & 63;
    const int wid   = t >> 6;
    const int wm    = wid >> 1;          // 0,1
    const int wn    = wid & 1;           // 0,1
    const int g     = lane >> 4;         // 0..3  (k-group)
    const int n16   = lane & 15;         // row/col within fragment

    const float* xb = x + (size_t)b * S * C;
    const uint4* aimg = (const uint4*)ws;

    f32x4 acc[6][4];
    #pragma unroll
    for (int i = 0; i < 6; i++)
        #pragma unroll
        for (int j = 0; j < 4; j++) acc[i][j] = (f32x4){0.f, 0.f, 0.f, 0.f};

    uint4 pa[3];
    uint4 pbw[2];
    int   pbc[2], pbk[2];

    auto load_tile = [&](int kt) {
        const uint4* asrc = aimg + (size_t)(kt * 2 + ptile) * 768;
        #pragma unroll
        for (int i = 0; i < 3; i++)
            pa[i] = asrc[i * 256 + t];
        #pragma unroll
        for (int i = 0; i < 2; i++) {
            int chunk = i * 256 + t;
            int c = chunk & 127, kg = chunk >> 7;
            const float* xs = xb + (size_t)(32 * kt + 8 * kg) * C + c;
            float f0 = xs[0*C], f1 = xs[1*C], f2 = xs[2*C], f3 = xs[3*C];
            float f4 = xs[4*C], f5 = xs[5*C], f6 = xs[6*C], f7 = xs[7*C];
            uint4 w;
            w.x = f2bf(f0) | (f2bf(f1) << 16);
            w.y = f2bf(f2) | (f2bf(f3) << 16);
            w.z = f2bf(f4) | (f2bf(f5) << 16);
            w.w = f2bf(f6) | (f2bf(f7) << 16);
            pbw[i] = w; pbc[i] = c; pbk[i] = kg;
        }
    };
    auto write_tile = [&](int buf) {
        #pragma unroll
        for (int i = 0; i < 3; i++)
            ((uint4*)As[buf])[i * 256 + t] = pa[i];
        #pragma unroll
        for (int i = 0; i < 2; i++)
            *(uint4*)&Bs[buf][pbc[i] >> 4][pbk[i]][pbc[i] & 15][0] = pbw[i];
    };

    load_tile(0);
    write_tile(0);
    __syncthreads();

    for (int kt = 0; kt < 32; kt++) {
        if (kt < 31) load_tile(kt + 1);

        const int buf = kt & 1;
        s16x8 fa[6], fb[4];
        #pragma unroll
        for (int fi = 0; fi < 6; fi++)
            fa[fi] = *(const s16x8*)&As[buf][6 * wm + fi][g][n16][0];
        #pragma unroll
        for (int fj = 0; fj < 4; fj++)
            fb[fj] = *(const s16x8*)&Bs[buf][4 * wn + fj][g][n16][0];

        #pragma unroll
        for (int fi = 0; fi < 6; fi++)
            #pragma unroll
            for (int fj = 0; fj < 4; fj++)
                acc[fi][fj] = __builtin_amdgcn_mfma_f32_16x16x32_bf16(
                    fa[fi], fb[fj], acc[fi][fj], 0, 0, 0);

        __syncthreads();
        if (kt < 31) {
            write_tile(buf ^ 1);
            __syncthreads();
        }
    }

    // ---- epilogue ----
    const int cb = wn * 64 + n16;
    float sdv[4], mnv[4], b3v[4];
    f32x4 w3r[4][4];
    #pragma unroll
    for (int fj = 0; fj < 4; fj++) {
        int c = cb + fj * 16;
        sdv[fj] = ws[WS_STD  + b * C + c];
        mnv[fj] = ws[WS_MEAN + b * C + c];
        b3v[fj] = b3[c];
        const f32x4* wr = (const f32x4*)(W3 + c * 16);
        #pragma unroll
        for (int q = 0; q < 4; q++) w3r[fj][q] = wr[q];
    }
    const int prow0 = ptile * 192 + wm * 96 + g * 4;
    #pragma unroll
    for (int fi = 0; fi < 6; fi++) {
        #pragma unroll
        for (int r = 0; r < 4; r++) {
            int p  = prow0 + fi * 16 + r;
            int pc = p < P ? p : P - 1;
            const f32x4* mrow = (const f32x4*)(ws + WS_M + ((size_t)b * P + pc) * 16);
            f32x4 m0 = mrow[0], m1 = mrow[1], m2 = mrow[2], m3 = mrow[3];
            const float* e = ws + WS_EPI + pc * 4;
            float A13 = e[0], A4 = e[1], A2 = e[2];
            #pragma unroll
            for (int fj = 0; fj < 4; fj++) {
                float s = 0.f;
                #pragma unroll
                for (int q = 0; q < 4; q++) {
                    const f32x4 mv = (q==0)?m0:(q==1)?m1:(q==2)?m2:m3;
                    s = fmaf(mv.x, w3r[fj][q].x, s);
                    s = fmaf(mv.y, w3r[fj][q].y, s);
                    s = fmaf(mv.z, w3r[fj][q].z, s);
                    s = fmaf(mv.w, w3r[fj][q].w, s);
                }
                float res = acc[fi][fj][r]
                          + sdv[fj] * (OMBf * s + A13 + A4 * b3v[fj])
                          + A2 * mnv[fj];
                if (p < P)
                    out[((size_t)b * P + p) * C + cb + fj * 16] = res;
            }
        }
    }
}

// ---------------------------------------------------------------------------
extern "C" void kernel_launch(void* const* d_in, const int* in_sizes, int n_in,
                              void* d_out, int out_size, void* d_ws, size_t ws_size,
                              hipStream_t stream)
{
    const float* x    = (const float*)d_in[0];
    const float* xme  = (const float*)d_in[1];
    const float* W1   = (const float*)d_in[4];
    const float* b1   = (const float*)d_in[5];
    const float* g1   = (const float*)d_in[6];
    const float* be1  = (const float*)d_in[7];
    const float* W2   = (const float*)d_in[8];
    const float* b2   = (const float*)d_in[9];
    const float* g2   = (const float*)d_in[10];
    const float* be2  = (const float*)d_in[11];
    const float* Wc   = (const float*)d_in[12];
    const float* bc   = (const float*)d_in[13];
    const float* W3   = (const float*)d_in[14];
    const float* b3   = (const float*)d_in[15];
    const float* Wtp  = (const float*)d_in[16];
    const float* btp  = (const float*)d_in[17];
    const float* Whp  = (const float*)d_in[18];
    const float* bhp  = (const float*)d_in[19];
    float* ws  = (float*)d_ws;
    float* out = (float*)d_out;

    k_prep  <<<dim3(P),      dim3(256), 0, stream>>>(Whp, Wtp, bc, bhp, btp, ws);
    k_stats1<<<dim3(B, 4),   dim3(256), 0, stream>>>(x, ws);
    k_stats2<<<dim3(64),     dim3(256), 0, stream>>>(ws);
    k_mlp   <<<dim3(512),    dim3(256), 0, stream>>>(xme, W1, b1, g1, be1,
                                                     W2, b2, g2, be2, ws);
    k_wcp   <<<dim3(2, 24),  dim3(256), 0, stream>>>(Wc, Wtp, ws);
    k_repack<<<dim3(96, 24), dim3(64),  0, stream>>>(ws);
    k_mconv <<<dim3(B, 6),   dim3(256), 0, stream>>>(ws);
    k_pred  <<<dim3(2, B),   dim3(256), 0, stream>>>(x, W3, b3, ws, out);
}

// Round 7
// 145.719 us; speedup vs baseline: 5.3859x; 1.3112x over previous
//
#include <hip/hip_runtime.h>
#include <hip/hip_bf16.h>

#define INV_SQRT2f 0.70710678118654752440f
#define BETAf 0.3f
#define OMBf  0.7f
#define LN_EPSf 1e-5f

#define B 128
#define S 1024
#define P 336
#define C 128
#define H1 32
#define H2 16

// ---------------- workspace layout (float offsets) ----------------
#define WS_WHP2G  0               // bf16 A-image for k_pred, 786432 B
#define WS_EPI    262144          // float4[384]: {A13, A4, A2, -}
#define WS_MEAN   263680          // 16384
#define WS_STD    280064          // 16384
#define WS_BCP    296448          // 384
#define WS_H2     296832          // 128*1024*16 = 2097152
#define WS_WCPT   2393984         // fp32 [p=336][m=3072] = 1032192 (dead after repack)
#define WS_M      2393984         // 128*336*16 = 688128  (overlays WCPT)
#define WS_AIMG   3426176         // bf16 conv A-image, 2359296 B = 589824 fl
#define WS_EVP    4114304         // 65536
#define WS_SQP    4179840         // 65536
// total 4245376 floats = 16.98 MB

typedef short  s16x8 __attribute__((ext_vector_type(8)));
typedef float  f32x4 __attribute__((ext_vector_type(4)));

// exact RNE float->bf16
__device__ __forceinline__ unsigned f2bf(float f) {
    unsigned u = __float_as_uint(f);
    return (u + 0x7fffu + ((u >> 16) & 1u)) >> 16;
}

// k_pred A-image u32 index for the pair (u=2sp, u=2sp+1) of projection row p.
__device__ __forceinline__ int whp2l_u32(int p, int sp) {
    int kt   = sp >> 4;
    int tile = kt * 2 + p / 192;
    int sub  = (p % 192) >> 4;
    int kg   = (sp & 15) >> 2;
    int m    = p & 15;
    int byte = tile * 12288 + sub * 1024 + kg * 256 + m * 16 + 4 * (sp & 3);
    return byte >> 2;
}

// ---------------------------------------------------------------------------
// k_prep: bf16 A-image (Haar-folded, BETA-scaled Whp2) + EPI + bcP
__global__ void k_prep(const float* __restrict__ Whp, const float* __restrict__ Wtp,
                       const float* __restrict__ bc,  const float* __restrict__ bhp,
                       const float* __restrict__ btp, float* __restrict__ ws)
{
    const int p = blockIdx.x;     // 0..335
    const int t = threadIdx.x;    // 256
    unsigned* img = (unsigned*)ws;
    __shared__ float red[768];
    float sw = 0.f, rw = 0.f, bp = 0.f;
    for (int sp = t; sp < 512; sp += 256) {
        float a = Whp[p * 1024 + sp];
        float d = Whp[p * 1024 + 512 + sp];
        float va = BETAf * (a + d) * INV_SQRT2f;   // u = 2sp
        float vb = BETAf * (a - d) * INV_SQRT2f;   // u = 2sp+1
        img[whp2l_u32(p, sp)] = f2bf(va) | (f2bf(vb) << 16);
        sw += a + d;
    }
    for (int s = t; s < S; s += 256) {
        float w = Wtp[p * 1024 + s];
        rw += w;
        bp += w * bc[s];
    }
    red[t] = sw; red[256 + t] = rw; red[512 + t] = bp;
    __syncthreads();
    for (int off = 128; off > 0; off >>= 1) {
        if (t < off) {
            red[t]       += red[t + off];
            red[256 + t] += red[256 + t + off];
            red[512 + t] += red[512 + t + off];
        }
        __syncthreads();
    }
    if (t == 0) {
        ws[WS_BCP + p] = red[512];
        float* e = ws + WS_EPI + p * 4;
        e[0] = BETAf * bhp[p] + OMBf * btp[p];   // A13
        e[1] = OMBf * red[256];                  // A4 = OMB*rowWtp
        e[2] = 1.f - BETAf * red[0];             // A2 = 1-BETA*sumWhp
        e[3] = 0.f;
    }
}

// ---------------------------------------------------------------------------
// stats pass 1
__global__ void k_stats1(const float* __restrict__ x, float* __restrict__ ws)
{
    const int b = blockIdx.x;
    const int j = blockIdx.y;       // 0..3
    const int t = threadIdx.x;      // 256
    const int c = t & 127;
    const int half = t >> 7;
    const float* xb = x + (size_t)b * S * C;
    const int ub = j * 256 + half * 128;
    float ev = 0.f, sq = 0.f;
    #pragma unroll 4
    for (int it = 0; it < 128; it += 2) {
        float v0 = xb[(size_t)(ub + it) * C + c];
        float v1 = xb[(size_t)(ub + it + 1) * C + c];
        ev += v0;
        sq += v0 * v0 + v1 * v1;
    }
    __shared__ float evb[256], sqb[256];
    evb[t] = ev; sqb[t] = sq;
    __syncthreads();
    if (t < 128) {
        ws[WS_EVP + ((size_t)b * 4 + j) * 128 + c] = evb[c] + evb[128 + c];
        ws[WS_SQP + ((size_t)b * 4 + j) * 128 + c] = sqb[c] + sqb[128 + c];
    }
}

__global__ void k_stats2(float* __restrict__ ws)
{
    const int idx = blockIdx.x * 256 + threadIdx.x;
    const int b = idx >> 7, c = idx & 127;
    float ev = 0.f, sq = 0.f;
    #pragma unroll
    for (int j = 0; j < 4; j++) {
        ev += ws[WS_EVP + ((size_t)b * 4 + j) * 128 + c];
        sq += ws[WS_SQP + ((size_t)b * 4 + j) * 128 + c];
    }
    float mean = ev * (INV_SQRT2f / 512.f);
    float var  = (sq - 1024.f * mean * mean) * (1.f / 1023.f);
    ws[WS_MEAN + idx] = mean;
    ws[WS_STD + idx]  = sqrtf(var + LN_EPSf);
}

// ---------------------------------------------------------------------------
// MLP
__global__ void k_mlp(const float* __restrict__ xme,
                      const float* __restrict__ W1, const float* __restrict__ b1,
                      const float* __restrict__ g1, const float* __restrict__ be1,
                      const float* __restrict__ W2, const float* __restrict__ b2,
                      const float* __restrict__ g2, const float* __restrict__ be2,
                      float* __restrict__ ws)
{
    __shared__ float w1s[128], b1s[32], g1s[32], be1s[32];
    __shared__ float w2s[512], b2s[16], g2s[16], be2s[16];
    const int t = threadIdx.x;
    if (t < 128) w1s[t] = W1[t];
    if (t < 32) { b1s[t] = b1[t]; g1s[t] = g1[t]; be1s[t] = be1[t]; }
    for (int i = t; i < 512; i += 256) w2s[i] = W2[i];
    if (t < 16) { b2s[t] = b2[t]; g2s[t] = g2[t]; be2s[t] = be2[t]; }
    __syncthreads();

    const int row = blockIdx.x * 256 + t;
    float4 v = *(const float4*)(xme + (size_t)row * 4);

    float h1v[32];
    float m = 0.f;
    #pragma unroll
    for (int i = 0; i < 32; i++) {
        float a = w1s[i*4+0]*v.x + w1s[i*4+1]*v.y + w1s[i*4+2]*v.z + w1s[i*4+3]*v.w + b1s[i];
        h1v[i] = a; m += a;
    }
    m *= (1.f / 32.f);
    float var = 0.f;
    #pragma unroll
    for (int i = 0; i < 32; i++) { float d = h1v[i] - m; var += d * d; }
    var *= (1.f / 32.f);
    float rs = rsqrtf(var + LN_EPSf);
    #pragma unroll
    for (int i = 0; i < 32; i++)
        h1v[i] = fmaxf((h1v[i] - m) * rs * g1s[i] + be1s[i], 0.f);

    float h2v[16];
    float m2 = 0.f;
    #pragma unroll
    for (int g = 0; g < 16; g++) {
        float a = b2s[g];
        #pragma unroll
        for (int i = 0; i < 32; i++) a = fmaf(w2s[g * 32 + i], h1v[i], a);
        h2v[g] = a; m2 += a;
    }
    m2 *= (1.f / 16.f);
    float v2 = 0.f;
    #pragma unroll
    for (int g = 0; g < 16; g++) { float d = h2v[g] - m2; v2 += d * d; }
    v2 *= (1.f / 16.f);
    float rs2 = rsqrtf(v2 + LN_EPSf);
    float* h2o = ws + WS_H2 + (size_t)row * 16;
    #pragma unroll
    for (int g = 0; g < 16; g++)
        h2o[g] = fmaxf((h2v[g] - m2) * rs2 * g2s[g] + be2s[g], 0.f);
}

// ---------------------------------------------------------------------------
// k_wcp (MFMA, 2-deep pipeline): WcPT_T[p][m3] = sum_o Wtp[p,o] * Wc[o, m3]
// grid (4 ptile x 48 ntile) = 192 blocks; block tile 96p x 64m3; 4 waves
// (2M x 2N), wave tile 48x32 = 3x2 frags. A (Wtp) = direct per-lane register
// fragments; B (Wc) staged via the proven [sub][kg][16][8] LDS subtiles.
// 2-deep: loads for kt+2 issued at kt; LDS-write waits on loads issued one
// full step earlier -> ~half the HBM latency exposed per k-step.
__global__ __launch_bounds__(256) void k_wcp(const float* __restrict__ Wc,
                                             const float* __restrict__ Wtp,
                                             float* __restrict__ ws)
{
    __shared__ __align__(16) unsigned short Bs[2][4][4][16][8];   // 8192 B
    const int pbase = blockIdx.x * 96;
    const int n0    = blockIdx.y * 64;
    const int t     = threadIdx.x;
    const int lane  = t & 63;
    const int wid   = t >> 6;
    const int wm    = wid >> 1;          // 0,1
    const int wn    = wid & 1;           // 0,1
    const int g8    = lane >> 4;         // 0..3  (k-group)
    const int n16   = lane & 15;

    const int bn  = t & 63;              // B staging: col within 64
    const int bkg = t >> 6;              // B staging: k-group

    int prow[3];
    #pragma unroll
    for (int fi = 0; fi < 3; fi++) {
        int pr = pbase + wm * 48 + fi * 16 + n16;
        prow[fi] = pr < P ? pr : P - 1;
    }

#define LOADB_(dst, kt) {                                                   \
    const float* xs_ = Wc + (size_t)((kt) * 32 + 8 * bkg) * 3072 + n0 + bn; \
    _Pragma("unroll")                                                       \
    for (int e_ = 0; e_ < 8; e_++) dst[e_] = xs_[(size_t)e_ * 3072]; }

#define WRITEB_(src, buf) {                                                 \
    uint4 w_;                                                               \
    w_.x = f2bf(src[0]) | (f2bf(src[1]) << 16);                             \
    w_.y = f2bf(src[2]) | (f2bf(src[3]) << 16);                             \
    w_.z = f2bf(src[4]) | (f2bf(src[5]) << 16);                             \
    w_.w = f2bf(src[6]) | (f2bf(src[7]) << 16);                             \
    *(uint4*)&Bs[buf][bn >> 4][bkg][bn & 15][0] = w_; }

#define LOADA_(dst, kt) {                                                   \
    _Pragma("unroll")                                                       \
    for (int fi_ = 0; fi_ < 3; fi_++) {                                     \
        const float* as_ = Wtp + (size_t)prow[fi_] * 1024 + (kt) * 32 + g8 * 8; \
        dst[fi_][0] = *(const float4*)(as_);                                \
        dst[fi_][1] = *(const float4*)(as_ + 4); } }

#define PACKA_(fa, src) {                                                   \
    _Pragma("unroll")                                                       \
    for (int fi_ = 0; fi_ < 3; fi_++) {                                     \
        uint4 w_;                                                           \
        w_.x = f2bf(src[fi_][0].x) | (f2bf(src[fi_][0].y) << 16);           \
        w_.y = f2bf(src[fi_][0].z) | (f2bf(src[fi_][0].w) << 16);           \
        w_.z = f2bf(src[fi_][1].x) | (f2bf(src[fi_][1].y) << 16);           \
        w_.w = f2bf(src[fi_][1].z) | (f2bf(src[fi_][1].w) << 16);           \
        fa[fi_] = *(s16x8*)&w_; } }

#define MFMA6_(buf, fa) {                                                   \
    s16x8 fb0 = *(const s16x8*)&Bs[buf][2 * wn + 0][g8][n16][0];            \
    s16x8 fb1 = *(const s16x8*)&Bs[buf][2 * wn + 1][g8][n16][0];            \
    _Pragma("unroll")                                                       \
    for (int fi_ = 0; fi_ < 3; fi_++) {                                     \
        acc[fi_][0] = __builtin_amdgcn_mfma_f32_16x16x32_bf16(fa[fi_], fb0, acc[fi_][0], 0, 0, 0); \
        acc[fi_][1] = __builtin_amdgcn_mfma_f32_16x16x32_bf16(fa[fi_], fb1, acc[fi_][1], 0, 0, 0); } }

    f32x4 acc[3][2];
    #pragma unroll
    for (int i = 0; i < 3; i++) {
        acc[i][0] = (f32x4){0.f, 0.f, 0.f, 0.f};
        acc[i][1] = (f32x4){0.f, 0.f, 0.f, 0.f};
    }

    float  b0r[8], b1r[8];
    float4 a0r[3][2], a1r[3][2];

    // prologue
    LOADA_(a0r, 0); LOADB_(b0r, 0);
    LOADA_(a1r, 1); LOADB_(b1r, 1);
    WRITEB_(b0r, 0);                 // waits b0r
    __syncthreads();

    for (int i = 0; i < 16; i++) {
        const int kt = 2 * i;
        // ---- even step: compute tile kt from Bs[0] ----
        {
            s16x8 fa[3];
            PACKA_(fa, a0r);                         // consume A(kt)
            if (kt + 2 < 32) { LOADA_(a0r, kt + 2); LOADB_(b0r, kt + 2); }
            MFMA6_(0, fa);
        }
        __syncthreads();
        WRITEB_(b1r, 1);                             // B(kt+1), issued 1 step ago
        __syncthreads();
        // ---- odd step: compute tile kt+1 from Bs[1] ----
        {
            s16x8 fa[3];
            PACKA_(fa, a1r);                         // consume A(kt+1)
            if (kt + 3 < 32) { LOADA_(a1r, kt + 3); LOADB_(b1r, kt + 3); }
            MFMA6_(1, fa);
        }
        __syncthreads();
        if (kt + 2 < 32) WRITEB_(b0r, 0);            // B(kt+2), issued 1 step ago
        __syncthreads();
    }

#undef LOADB_
#undef WRITEB_
#undef LOADA_
#undef PACKA_
#undef MFMA6_

    // C/D per m89: row (p within frag) = 4*g8 + r, col = n16
    float* wcT = ws + WS_WCPT;
    #pragma unroll
    for (int fi = 0; fi < 3; fi++) {
        #pragma unroll
        for (int r = 0; r < 4; r++) {
            int p = pbase + wm * 48 + fi * 16 + g8 * 4 + r;
            if (p < P) {
                wcT[(size_t)p * 3072 + n0 + wn * 32 + 0 * 16 + n16] = acc[fi][0][r];
                wcT[(size_t)p * 3072 + n0 + wn * 32 + 1 * 16 + n16] = acc[fi][1][r];
            }
        }
    }
}

// ---------------------------------------------------------------------------
// k_repack: fp32 WcPT_T[p][m3]  ->  bf16 MFMA A-image.
__global__ void k_repack(float* __restrict__ ws)
{
    const int l  = threadIdx.x;          // 0..63
    const int ch = blockIdx.x;           // k*32+kt, 0..95
    const int pf = blockIdx.y;           // 0..23
    const int k  = ch >> 5;
    const int i0 = (ch & 31) * 32 + (l >> 4) * 8;
    const int p  = pf * 16 + (l & 15);
    uint4 w = make_uint4(0, 0, 0, 0);
    if (p < P) {
        const float* wcT = ws + WS_WCPT + (size_t)p * 3072;
        float v[8];
        #pragma unroll
        for (int e = 0; e < 8; e++)
            v[e] = wcT[(i0 + e) * 3 + k];
        w.x = f2bf(v[0]) | (f2bf(v[1]) << 16);
        w.y = f2bf(v[2]) | (f2bf(v[3]) << 16);
        w.z = f2bf(v[4]) | (f2bf(v[5]) << 16);
        w.w = f2bf(v[6]) | (f2bf(v[7]) << 16);
    }
    ((uint4*)(ws + WS_AIMG))[(size_t)(ch * 24 + pf) * 64 + l] = w;
}

// ---------------------------------------------------------------------------
// k_mconv (MFMA): M[b,p,g] = bcP[p] + sum_k sum_i A_k[p][i] * h[b,i,g+k-1]
#define HT_RS 1056            /* u16 elems per row (2112 B) */
__global__ __launch_bounds__(256) void k_mconv(float* __restrict__ ws)
{
    __shared__ unsigned short Ht[18 * HT_RS];   // 38016 B
    const int b  = blockIdx.x;
    const int pt = blockIdx.y;                  // 0..5
    const int t  = threadIdx.x;
    const int l  = t & 63;
    const int wid = t >> 6;
    const int pf = pt * 4 + wid;                // 0..23
    const int n16 = l & 15;
    const int g8  = l >> 4;

    for (int j = t; j < HT_RS; j += 256) {
        Ht[j] = 0;
        Ht[17 * HT_RS + j] = 0;
    }
    {
        const float* h2b = ws + WS_H2 + (size_t)b * 16384;
        const int s0 = t * 4;
        float v[4][16];
        #pragma unroll
        for (int rr = 0; rr < 4; rr++) {
            const float4* src = (const float4*)(h2b + (size_t)(s0 + rr) * 16);
            float4 a0 = src[0], a1 = src[1], a2 = src[2], a3 = src[3];
            v[rr][0]=a0.x; v[rr][1]=a0.y; v[rr][2]=a0.z; v[rr][3]=a0.w;
            v[rr][4]=a1.x; v[rr][5]=a1.y; v[rr][6]=a1.z; v[rr][7]=a1.w;
            v[rr][8]=a2.x; v[rr][9]=a2.y; v[rr][10]=a2.z; v[rr][11]=a2.w;
            v[rr][12]=a3.x; v[rr][13]=a3.y; v[rr][14]=a3.z; v[rr][15]=a3.w;
        }
        #pragma unroll
        for (int g = 0; g < 16; g++) {
            uint2 w;
            w.x = f2bf(v[0][g]) | (f2bf(v[1][g]) << 16);
            w.y = f2bf(v[2][g]) | (f2bf(v[3][g]) << 16);
            *(uint2*)&Ht[(g + 1) * HT_RS + s0] = w;
        }
    }
    __syncthreads();

    const uint4* ap = (const uint4*)(ws + WS_AIMG) + (size_t)pf * 64 + l;
    f32x4 acc = (f32x4){0.f, 0.f, 0.f, 0.f};
    uint4 fan = *ap;                    // prefetch it=0
    #pragma unroll 4
    for (int it = 0; it < 96; it++) {
        uint4 fac = fan;
        ap += 24 * 64;
        if (it < 95) fan = *ap;
        const int k  = it >> 5;
        const int kt = it & 31;
        s16x8 fb = *(const s16x8*)&Ht[(n16 + k) * HT_RS + kt * 32 + g8 * 8];
        s16x8 fa = *(s16x8*)&fac;
        acc = __builtin_amdgcn_mfma_f32_16x16x32_bf16(fa, fb, acc, 0, 0, 0);
    }

    #pragma unroll
    for (int r = 0; r < 4; r++) {
        int p = pf * 16 + g8 * 4 + r;
        if (p < P)
            ws[WS_M + ((size_t)b * P + p) * 16 + n16] = acc[r] + ws[WS_BCP + p];
    }
}

// ---------------------------------------------------------------------------
// k_pred: MFMA bf16 GEMM + fused epilogue (unchanged, passing).
__global__ __launch_bounds__(256, 2) void k_pred(
    const float* __restrict__ x,
    const float* __restrict__ W3, const float* __restrict__ b3,
    const float* __restrict__ ws, float* __restrict__ out)
{
    __shared__ __align__(16) unsigned short As[2][12][4][16][8];  // 49152 B
    __shared__ __align__(16) unsigned short Bs[2][8][4][16][8];   // 32768 B
    const int ptile = blockIdx.x;        // 0,1
    const int b     = blockIdx.y;
    const int t     = threadIdx.x;
    const int lane  = t & 63;
    const int wid   = t >> 6;
    const int wm    = wid >> 1;          // 0,1
    const int wn    = wid & 1;           // 0,1
    const int g     = lane >> 4;         // 0..3  (k-group)
    const int n16   = lane & 15;         // row/col within fragment

    const float* xb = x + (size_t)b * S * C;
    const uint4* aimg = (const uint4*)ws;

    f32x4 acc[6][4];
    #pragma unroll
    for (int i = 0; i < 6; i++)
        #pragma unroll
        for (int j = 0; j < 4; j++) acc[i][j] = (f32x4){0.f, 0.f, 0.f, 0.f};

    uint4 pa[3];
    uint4 pbw[2];
    int   pbc[2], pbk[2];

    auto load_tile = [&](int kt) {
        const uint4* asrc = aimg + (size_t)(kt * 2 + ptile) * 768;
        #pragma unroll
        for (int i = 0; i < 3; i++)
            pa[i] = asrc[i * 256 + t];
        #pragma unroll
        for (int i = 0; i < 2; i++) {
            int chunk = i * 256 + t;
            int c = chunk & 127, kg = chunk >> 7;
            const float* xs = xb + (size_t)(32 * kt + 8 * kg) * C + c;
            float f0 = xs[0*C], f1 = xs[1*C], f2 = xs[2*C], f3 = xs[3*C];
            float f4 = xs[4*C], f5 = xs[5*C], f6 = xs[6*C], f7 = xs[7*C];
            uint4 w;
            w.x = f2bf(f0) | (f2bf(f1) << 16);
            w.y = f2bf(f2) | (f2bf(f3) << 16);
            w.z = f2bf(f4) | (f2bf(f5) << 16);
            w.w = f2bf(f6) | (f2bf(f7) << 16);
            pbw[i] = w; pbc[i] = c; pbk[i] = kg;
        }
    };
    auto write_tile = [&](int buf) {
        #pragma unroll
        for (int i = 0; i < 3; i++)
            ((uint4*)As[buf])[i * 256 + t] = pa[i];
        #pragma unroll
        for (int i = 0; i < 2; i++)
            *(uint4*)&Bs[buf][pbc[i] >> 4][pbk[i]][pbc[i] & 15][0] = pbw[i];
    };

    load_tile(0);
    write_tile(0);
    __syncthreads();

    for (int kt = 0; kt < 32; kt++) {
        if (kt < 31) load_tile(kt + 1);

        const int buf = kt & 1;
        s16x8 fa[6], fb[4];
        #pragma unroll
        for (int fi = 0; fi < 6; fi++)
            fa[fi] = *(const s16x8*)&As[buf][6 * wm + fi][g][n16][0];
        #pragma unroll
        for (int fj = 0; fj < 4; fj++)
            fb[fj] = *(const s16x8*)&Bs[buf][4 * wn + fj][g][n16][0];

        #pragma unroll
        for (int fi = 0; fi < 6; fi++)
            #pragma unroll
            for (int fj = 0; fj < 4; fj++)
                acc[fi][fj] = __builtin_amdgcn_mfma_f32_16x16x32_bf16(
                    fa[fi], fb[fj], acc[fi][fj], 0, 0, 0);

        __syncthreads();
        if (kt < 31) {
            write_tile(buf ^ 1);
            __syncthreads();
        }
    }

    // ---- epilogue ----
    const int cb = wn * 64 + n16;
    float sdv[4], mnv[4], b3v[4];
    f32x4 w3r[4][4];
    #pragma unroll
    for (int fj = 0; fj < 4; fj++) {
        int c = cb + fj * 16;
        sdv[fj] = ws[WS_STD  + b * C + c];
        mnv[fj] = ws[WS_MEAN + b * C + c];
        b3v[fj] = b3[c];
        const f32x4* wr = (const f32x4*)(W3 + c * 16);
        #pragma unroll
        for (int q = 0; q < 4; q++) w3r[fj][q] = wr[q];
    }
    const int prow0 = ptile * 192 + wm * 96 + g * 4;
    #pragma unroll
    for (int fi = 0; fi < 6; fi++) {
        #pragma unroll
        for (int r = 0; r < 4; r++) {
            int p  = prow0 + fi * 16 + r;
            int pc = p < P ? p : P - 1;
            const f32x4* mrow = (const f32x4*)(ws + WS_M + ((size_t)b * P + pc) * 16);
            f32x4 m0 = mrow[0], m1 = mrow[1], m2 = mrow[2], m3 = mrow[3];
            const float* e = ws + WS_EPI + pc * 4;
            float A13 = e[0], A4 = e[1], A2 = e[2];
            #pragma unroll
            for (int fj = 0; fj < 4; fj++) {
                float s = 0.f;
                #pragma unroll
                for (int q = 0; q < 4; q++) {
                    const f32x4 mv = (q==0)?m0:(q==1)?m1:(q==2)?m2:m3;
                    s = fmaf(mv.x, w3r[fj][q].x, s);
                    s = fmaf(mv.y, w3r[fj][q].y, s);
                    s = fmaf(mv.z, w3r[fj][q].z, s);
                    s = fmaf(mv.w, w3r[fj][q].w, s);
                }
                float res = acc[fi][fj][r]
                          + sdv[fj] * (OMBf * s + A13 + A4 * b3v[fj])
                          + A2 * mnv[fj];
                if (p < P)
                    out[((size_t)b * P + p) * C + cb + fj * 16] = res;
            }
        }
    }
}

// ---------------------------------------------------------------------------
extern "C" void kernel_launch(void* const* d_in, const int* in_sizes, int n_in,
                              void* d_out, int out_size, void* d_ws, size_t ws_size,
                              hipStream_t stream)
{
    const float* x    = (const float*)d_in[0];
    const float* xme  = (const float*)d_in[1];
    const float* W1   = (const float*)d_in[4];
    const float* b1   = (const float*)d_in[5];
    const float* g1   = (const float*)d_in[6];
    const float* be1  = (const float*)d_in[7];
    const float* W2   = (const float*)d_in[8];
    const float* b2   = (const float*)d_in[9];
    const float* g2   = (const float*)d_in[10];
    const float* be2  = (const float*)d_in[11];
    const float* Wc   = (const float*)d_in[12];
    const float* bc   = (const float*)d_in[13];
    const float* W3   = (const float*)d_in[14];
    const float* b3   = (const float*)d_in[15];
    const float* Wtp  = (const float*)d_in[16];
    const float* btp  = (const float*)d_in[17];
    const float* Whp  = (const float*)d_in[18];
    const float* bhp  = (const float*)d_in[19];
    float* ws  = (float*)d_ws;
    float* out = (float*)d_out;

    k_prep  <<<dim3(P),      dim3(256), 0, stream>>>(Whp, Wtp, bc, bhp, btp, ws);
    k_stats1<<<dim3(B, 4),   dim3(256), 0, stream>>>(x, ws);
    k_stats2<<<dim3(64),     dim3(256), 0, stream>>>(ws);
    k_mlp   <<<dim3(512),    dim3(256), 0, stream>>>(xme, W1, b1, g1, be1,
                                                     W2, b2, g2, be2, ws);
    k_wcp   <<<dim3(4, 48),  dim3(256), 0, stream>>>(Wc, Wtp, ws);
    k_repack<<<dim3(96, 24), dim3(64),  0, stream>>>(ws);
    k_mconv <<<dim3(B, 6),   dim3(256), 0, stream>>>(ws);
    k_pred  <<<dim3(2, B),   dim3(256), 0, stream>>>(x, W3, b3, ws, out);
}

// Round 8
// 138.255 us; speedup vs baseline: 5.6767x; 1.0540x over previous
//
#include <hip/hip_runtime.h>
#include <hip/hip_bf16.h>

#define INV_SQRT2f 0.70710678118654752440f
#define BETAf 0.3f
#define OMBf  0.7f
#define LN_EPSf 1e-5f

#define B 128
#define S 1024
#define P 336
#define C 128
#define H1 32
#define H2 16

// ---------------- workspace layout (float offsets) ----------------
#define WS_WHP2G  0               // bf16 A-image for k_pred, 786432 B
#define WS_EPI    262144          // float4[384]: {A13, A4, A2, -}
#define WS_MEAN   263680          // 16384
#define WS_STD    280064          // 16384
#define WS_BCP    296448          // 384
#define WS_H2     296832          // 128*1024*16 = 2097152
#define WS_WCPT   2393984         // fp32 [p=336][m=3072] = 1032192 (dead after repack)
#define WS_M      2393984         // 128*336*16 = 688128  (overlays WCPT)
#define WS_AIMG   3426176         // bf16 conv A-image, 2359296 B = 589824 fl
#define WS_EVP    4114304         // 65536
#define WS_SQP    4179840         // 65536
// total 4245376 floats = 16.98 MB

typedef short  s16x8 __attribute__((ext_vector_type(8)));
typedef float  f32x4 __attribute__((ext_vector_type(4)));

// exact RNE float->bf16
__device__ __forceinline__ unsigned f2bf(float f) {
    unsigned u = __float_as_uint(f);
    return (u + 0x7fffu + ((u >> 16) & 1u)) >> 16;
}

// k_pred A-image u32 index for the pair (u=2sp, u=2sp+1) of projection row p.
__device__ __forceinline__ int whp2l_u32(int p, int sp) {
    int kt   = sp >> 4;
    int tile = kt * 2 + p / 192;
    int sub  = (p % 192) >> 4;
    int kg   = (sp & 15) >> 2;
    int m    = p & 15;
    int byte = tile * 12288 + sub * 1024 + kg * 256 + m * 16 + 4 * (sp & 3);
    return byte >> 2;
}

// ---------------------------------------------------------------------------
// k_prep: bf16 A-image (Haar-folded, BETA-scaled Whp2) + EPI + bcP
__global__ void k_prep(const float* __restrict__ Whp, const float* __restrict__ Wtp,
                       const float* __restrict__ bc,  const float* __restrict__ bhp,
                       const float* __restrict__ btp, float* __restrict__ ws)
{
    const int p = blockIdx.x;     // 0..335
    const int t = threadIdx.x;    // 256
    unsigned* img = (unsigned*)ws;
    __shared__ float red[768];
    float sw = 0.f, rw = 0.f, bp = 0.f;
    for (int sp = t; sp < 512; sp += 256) {
        float a = Whp[p * 1024 + sp];
        float d = Whp[p * 1024 + 512 + sp];
        float va = BETAf * (a + d) * INV_SQRT2f;   // u = 2sp
        float vb = BETAf * (a - d) * INV_SQRT2f;   // u = 2sp+1
        img[whp2l_u32(p, sp)] = f2bf(va) | (f2bf(vb) << 16);
        sw += a + d;
    }
    for (int s = t; s < S; s += 256) {
        float w = Wtp[p * 1024 + s];
        rw += w;
        bp += w * bc[s];
    }
    red[t] = sw; red[256 + t] = rw; red[512 + t] = bp;
    __syncthreads();
    for (int off = 128; off > 0; off >>= 1) {
        if (t < off) {
            red[t]       += red[t + off];
            red[256 + t] += red[256 + t + off];
            red[512 + t] += red[512 + t + off];
        }
        __syncthreads();
    }
    if (t == 0) {
        ws[WS_BCP + p] = red[512];
        float* e = ws + WS_EPI + p * 4;
        e[0] = BETAf * bhp[p] + OMBf * btp[p];   // A13
        e[1] = OMBf * red[256];                  // A4 = OMB*rowWtp
        e[2] = 1.f - BETAf * red[0];             // A2 = 1-BETA*sumWhp
        e[3] = 0.f;
    }
}

// ---------------------------------------------------------------------------
// stats pass 1
__global__ void k_stats1(const float* __restrict__ x, float* __restrict__ ws)
{
    const int b = blockIdx.x;
    const int j = blockIdx.y;       // 0..3
    const int t = threadIdx.x;      // 256
    const int c = t & 127;
    const int half = t >> 7;
    const float* xb = x + (size_t)b * S * C;
    const int ub = j * 256 + half * 128;
    float ev = 0.f, sq = 0.f;
    #pragma unroll 4
    for (int it = 0; it < 128; it += 2) {
        float v0 = xb[(size_t)(ub + it) * C + c];
        float v1 = xb[(size_t)(ub + it + 1) * C + c];
        ev += v0;
        sq += v0 * v0 + v1 * v1;
    }
    __shared__ float evb[256], sqb[256];
    evb[t] = ev; sqb[t] = sq;
    __syncthreads();
    if (t < 128) {
        ws[WS_EVP + ((size_t)b * 4 + j) * 128 + c] = evb[c] + evb[128 + c];
        ws[WS_SQP + ((size_t)b * 4 + j) * 128 + c] = sqb[c] + sqb[128 + c];
    }
}

__global__ void k_stats2(float* __restrict__ ws)
{
    const int idx = blockIdx.x * 256 + threadIdx.x;
    const int b = idx >> 7, c = idx & 127;
    float ev = 0.f, sq = 0.f;
    #pragma unroll
    for (int j = 0; j < 4; j++) {
        ev += ws[WS_EVP + ((size_t)b * 4 + j) * 128 + c];
        sq += ws[WS_SQP + ((size_t)b * 4 + j) * 128 + c];
    }
    float mean = ev * (INV_SQRT2f / 512.f);
    float var  = (sq - 1024.f * mean * mean) * (1.f / 1023.f);
    ws[WS_MEAN + idx] = mean;
    ws[WS_STD + idx]  = sqrtf(var + LN_EPSf);
}

// ---------------------------------------------------------------------------
// MLP
__global__ void k_mlp(const float* __restrict__ xme,
                      const float* __restrict__ W1, const float* __restrict__ b1,
                      const float* __restrict__ g1, const float* __restrict__ be1,
                      const float* __restrict__ W2, const float* __restrict__ b2,
                      const float* __restrict__ g2, const float* __restrict__ be2,
                      float* __restrict__ ws)
{
    __shared__ float w1s[128], b1s[32], g1s[32], be1s[32];
    __shared__ float w2s[512], b2s[16], g2s[16], be2s[16];
    const int t = threadIdx.x;
    if (t < 128) w1s[t] = W1[t];
    if (t < 32) { b1s[t] = b1[t]; g1s[t] = g1[t]; be1s[t] = be1[t]; }
    for (int i = t; i < 512; i += 256) w2s[i] = W2[i];
    if (t < 16) { b2s[t] = b2[t]; g2s[t] = g2[t]; be2s[t] = be2[t]; }
    __syncthreads();

    const int row = blockIdx.x * 256 + t;
    float4 v = *(const float4*)(xme + (size_t)row * 4);

    float h1v[32];
    float m = 0.f;
    #pragma unroll
    for (int i = 0; i < 32; i++) {
        float a = w1s[i*4+0]*v.x + w1s[i*4+1]*v.y + w1s[i*4+2]*v.z + w1s[i*4+3]*v.w + b1s[i];
        h1v[i] = a; m += a;
    }
    m *= (1.f / 32.f);
    float var = 0.f;
    #pragma unroll
    for (int i = 0; i < 32; i++) { float d = h1v[i] - m; var += d * d; }
    var *= (1.f / 32.f);
    float rs = rsqrtf(var + LN_EPSf);
    #pragma unroll
    for (int i = 0; i < 32; i++)
        h1v[i] = fmaxf((h1v[i] - m) * rs * g1s[i] + be1s[i], 0.f);

    float h2v[16];
    float m2 = 0.f;
    #pragma unroll
    for (int g = 0; g < 16; g++) {
        float a = b2s[g];
        #pragma unroll
        for (int i = 0; i < 32; i++) a = fmaf(w2s[g * 32 + i], h1v[i], a);
        h2v[g] = a; m2 += a;
    }
    m2 *= (1.f / 16.f);
    float v2 = 0.f;
    #pragma unroll
    for (int g = 0; g < 16; g++) { float d = h2v[g] - m2; v2 += d * d; }
    v2 *= (1.f / 16.f);
    float rs2 = rsqrtf(v2 + LN_EPSf);
    float* h2o = ws + WS_H2 + (size_t)row * 16;
    #pragma unroll
    for (int g = 0; g < 16; g++)
        h2o[g] = fmaxf((h2v[g] - m2) * rs2 * g2s[g] + be2s[g], 0.f);
}

// ---------------------------------------------------------------------------
// k_wcp (MFMA, 2-deep pipeline) — unchanged, passing.
__global__ __launch_bounds__(256) void k_wcp(const float* __restrict__ Wc,
                                             const float* __restrict__ Wtp,
                                             float* __restrict__ ws)
{
    __shared__ __align__(16) unsigned short Bs[2][4][4][16][8];   // 8192 B
    const int pbase = blockIdx.x * 96;
    const int n0    = blockIdx.y * 64;
    const int t     = threadIdx.x;
    const int lane  = t & 63;
    const int wid   = t >> 6;
    const int wm    = wid >> 1;          // 0,1
    const int wn    = wid & 1;           // 0,1
    const int g8    = lane >> 4;         // 0..3  (k-group)
    const int n16   = lane & 15;

    const int bn  = t & 63;
    const int bkg = t >> 6;

    int prow[3];
    #pragma unroll
    for (int fi = 0; fi < 3; fi++) {
        int pr = pbase + wm * 48 + fi * 16 + n16;
        prow[fi] = pr < P ? pr : P - 1;
    }

#define LOADB_(dst, kt) {                                                   \
    const float* xs_ = Wc + (size_t)((kt) * 32 + 8 * bkg) * 3072 + n0 + bn; \
    _Pragma("unroll")                                                       \
    for (int e_ = 0; e_ < 8; e_++) dst[e_] = xs_[(size_t)e_ * 3072]; }

#define WRITEB_(src, buf) {                                                 \
    uint4 w_;                                                               \
    w_.x = f2bf(src[0]) | (f2bf(src[1]) << 16);                             \
    w_.y = f2bf(src[2]) | (f2bf(src[3]) << 16);                             \
    w_.z = f2bf(src[4]) | (f2bf(src[5]) << 16);                             \
    w_.w = f2bf(src[6]) | (f2bf(src[7]) << 16);                             \
    *(uint4*)&Bs[buf][bn >> 4][bkg][bn & 15][0] = w_; }

#define LOADA_(dst, kt) {                                                   \
    _Pragma("unroll")                                                       \
    for (int fi_ = 0; fi_ < 3; fi_++) {                                     \
        const float* as_ = Wtp + (size_t)prow[fi_] * 1024 + (kt) * 32 + g8 * 8; \
        dst[fi_][0] = *(const float4*)(as_);                                \
        dst[fi_][1] = *(const float4*)(as_ + 4); } }

#define PACKA_(fa, src) {                                                   \
    _Pragma("unroll")                                                       \
    for (int fi_ = 0; fi_ < 3; fi_++) {                                     \
        uint4 w_;                                                           \
        w_.x = f2bf(src[fi_][0].x) | (f2bf(src[fi_][0].y) << 16);           \
        w_.y = f2bf(src[fi_][0].z) | (f2bf(src[fi_][0].w) << 16);           \
        w_.z = f2bf(src[fi_][1].x) | (f2bf(src[fi_][1].y) << 16);           \
        w_.w = f2bf(src[fi_][1].z) | (f2bf(src[fi_][1].w) << 16);           \
        fa[fi_] = *(s16x8*)&w_; } }

#define MFMA6_(buf, fa) {                                                   \
    s16x8 fb0 = *(const s16x8*)&Bs[buf][2 * wn + 0][g8][n16][0];            \
    s16x8 fb1 = *(const s16x8*)&Bs[buf][2 * wn + 1][g8][n16][0];            \
    _Pragma("unroll")                                                       \
    for (int fi_ = 0; fi_ < 3; fi_++) {                                     \
        acc[fi_][0] = __builtin_amdgcn_mfma_f32_16x16x32_bf16(fa[fi_], fb0, acc[fi_][0], 0, 0, 0); \
        acc[fi_][1] = __builtin_amdgcn_mfma_f32_16x16x32_bf16(fa[fi_], fb1, acc[fi_][1], 0, 0, 0); } }

    f32x4 acc[3][2];
    #pragma unroll
    for (int i = 0; i < 3; i++) {
        acc[i][0] = (f32x4){0.f, 0.f, 0.f, 0.f};
        acc[i][1] = (f32x4){0.f, 0.f, 0.f, 0.f};
    }

    float  b0r[8], b1r[8];
    float4 a0r[3][2], a1r[3][2];

    LOADA_(a0r, 0); LOADB_(b0r, 0);
    LOADA_(a1r, 1); LOADB_(b1r, 1);
    WRITEB_(b0r, 0);
    __syncthreads();

    for (int i = 0; i < 16; i++) {
        const int kt = 2 * i;
        {
            s16x8 fa[3];
            PACKA_(fa, a0r);
            if (kt + 2 < 32) { LOADA_(a0r, kt + 2); LOADB_(b0r, kt + 2); }
            MFMA6_(0, fa);
        }
        __syncthreads();
        WRITEB_(b1r, 1);
        __syncthreads();
        {
            s16x8 fa[3];
            PACKA_(fa, a1r);
            if (kt + 3 < 32) { LOADA_(a1r, kt + 3); LOADB_(b1r, kt + 3); }
            MFMA6_(1, fa);
        }
        __syncthreads();
        if (kt + 2 < 32) WRITEB_(b0r, 0);
        __syncthreads();
    }

#undef LOADB_
#undef WRITEB_
#undef LOADA_
#undef PACKA_
#undef MFMA6_

    float* wcT = ws + WS_WCPT;
    #pragma unroll
    for (int fi = 0; fi < 3; fi++) {
        #pragma unroll
        for (int r = 0; r < 4; r++) {
            int p = pbase + wm * 48 + fi * 16 + g8 * 4 + r;
            if (p < P) {
                wcT[(size_t)p * 3072 + n0 + wn * 32 + 0 * 16 + n16] = acc[fi][0][r];
                wcT[(size_t)p * 3072 + n0 + wn * 32 + 1 * 16 + n16] = acc[fi][1][r];
            }
        }
    }
}

// ---------------------------------------------------------------------------
// k_repack: fp32 WcPT_T[p][m3]  ->  bf16 MFMA A-image.
__global__ void k_repack(float* __restrict__ ws)
{
    const int l  = threadIdx.x;          // 0..63
    const int ch = blockIdx.x;           // k*32+kt, 0..95
    const int pf = blockIdx.y;           // 0..23
    const int k  = ch >> 5;
    const int i0 = (ch & 31) * 32 + (l >> 4) * 8;
    const int p  = pf * 16 + (l & 15);
    uint4 w = make_uint4(0, 0, 0, 0);
    if (p < P) {
        const float* wcT = ws + WS_WCPT + (size_t)p * 3072;
        float v[8];
        #pragma unroll
        for (int e = 0; e < 8; e++)
            v[e] = wcT[(i0 + e) * 3 + k];
        w.x = f2bf(v[0]) | (f2bf(v[1]) << 16);
        w.y = f2bf(v[2]) | (f2bf(v[3]) << 16);
        w.z = f2bf(v[4]) | (f2bf(v[5]) << 16);
        w.w = f2bf(v[6]) | (f2bf(v[7]) << 16);
    }
    ((uint4*)(ws + WS_AIMG))[(size_t)(ch * 24 + pf) * 64 + l] = w;
}

// ---------------------------------------------------------------------------
// k_mconv (MFMA): M[b,p,g] = bcP[p] + sum_k sum_i A_k[p][i] * h[b,i,g+k-1]
#define HT_RS 1056            /* u16 elems per row (2112 B) */
__global__ __launch_bounds__(256) void k_mconv(float* __restrict__ ws)
{
    __shared__ unsigned short Ht[18 * HT_RS];   // 38016 B
    const int b  = blockIdx.x;
    const int pt = blockIdx.y;                  // 0..5
    const int t  = threadIdx.x;
    const int l  = t & 63;
    const int wid = t >> 6;
    const int pf = pt * 4 + wid;                // 0..23
    const int n16 = l & 15;
    const int g8  = l >> 4;

    for (int j = t; j < HT_RS; j += 256) {
        Ht[j] = 0;
        Ht[17 * HT_RS + j] = 0;
    }
    {
        const float* h2b = ws + WS_H2 + (size_t)b * 16384;
        const int s0 = t * 4;
        float v[4][16];
        #pragma unroll
        for (int rr = 0; rr < 4; rr++) {
            const float4* src = (const float4*)(h2b + (size_t)(s0 + rr) * 16);
            float4 a0 = src[0], a1 = src[1], a2 = src[2], a3 = src[3];
            v[rr][0]=a0.x; v[rr][1]=a0.y; v[rr][2]=a0.z; v[rr][3]=a0.w;
            v[rr][4]=a1.x; v[rr][5]=a1.y; v[rr][6]=a1.z; v[rr][7]=a1.w;
            v[rr][8]=a2.x; v[rr][9]=a2.y; v[rr][10]=a2.z; v[rr][11]=a2.w;
            v[rr][12]=a3.x; v[rr][13]=a3.y; v[rr][14]=a3.z; v[rr][15]=a3.w;
        }
        #pragma unroll
        for (int g = 0; g < 16; g++) {
            uint2 w;
            w.x = f2bf(v[0][g]) | (f2bf(v[1][g]) << 16);
            w.y = f2bf(v[2][g]) | (f2bf(v[3][g]) << 16);
            *(uint2*)&Ht[(g + 1) * HT_RS + s0] = w;
        }
    }
    __syncthreads();

    const uint4* ap = (const uint4*)(ws + WS_AIMG) + (size_t)pf * 64 + l;
    f32x4 acc = (f32x4){0.f, 0.f, 0.f, 0.f};
    uint4 fan = *ap;                    // prefetch it=0
    #pragma unroll 4
    for (int it = 0; it < 96; it++) {
        uint4 fac = fan;
        ap += 24 * 64;
        if (it < 95) fan = *ap;
        const int k  = it >> 5;
        const int kt = it & 31;
        s16x8 fb = *(const s16x8*)&Ht[(n16 + k) * HT_RS + kt * 32 + g8 * 8];
        s16x8 fa = *(s16x8*)&fac;
        acc = __builtin_amdgcn_mfma_f32_16x16x32_bf16(fa, fb, acc, 0, 0, 0);
    }

    #pragma unroll
    for (int r = 0; r < 4; r++) {
        int p = pf * 16 + g8 * 4 + r;
        if (p < P)
            ws[WS_M + ((size_t)b * P + p) * 16 + n16] = acc[r] + ws[WS_BCP + p];
    }
}

// ---------------------------------------------------------------------------
// k_pred v2: MFMA bf16 GEMM + fused epilogue.
// grid (4 ptile x 128 b) = 512 blocks (2/CU), 4 waves (2M x 2N),
// block tile 96p x 128c; wave tile 48p x 64c = 3x4 frags.
// A: DIRECT per-lane uint4 global loads from the fragment-ordered image
// (no LDS). B: x staged via proven [sub][kg][16][8] LDS subtiles with the
// k_wcp 2-deep even/odd register-stage pipeline.
__global__ __launch_bounds__(256, 2) void k_pred(
    const float* __restrict__ x,
    const float* __restrict__ W3, const float* __restrict__ b3,
    const float* __restrict__ ws, float* __restrict__ out)
{
    __shared__ __align__(16) unsigned short Bs[2][8][4][16][8];   // 32768 B
    const int ptile = blockIdx.x;        // 0..3 (96 p-rows each)
    const int b     = blockIdx.y;
    const int t     = threadIdx.x;
    const int lane  = t & 63;
    const int wid   = t >> 6;
    const int wm    = wid >> 1;          // 0,1
    const int wn    = wid & 1;           // 0,1
    const int g8    = lane >> 4;         // 0..3  (k-group)
    const int n16   = lane & 15;

    const float* xb = x + (size_t)b * S * C;
    // A image: tile (kt*2 + (ptile>>1)) * 12288 B; subs (ptile&1)*6 + wm*3 + fi
    const char* aimgc = (const char*)ws
        + ((ptile >> 1) * 12288)
        + (((ptile & 1) * 6 + wm * 3) * 1024)
        + (g8 * 256 + n16 * 16);

    f32x4 acc[3][4];
    #pragma unroll
    for (int i = 0; i < 3; i++)
        #pragma unroll
        for (int j = 0; j < 4; j++) acc[i][j] = (f32x4){0.f, 0.f, 0.f, 0.f};

#define P_LOADB_(dst, kt) {                                                 \
    _Pragma("unroll")                                                       \
    for (int i_ = 0; i_ < 2; i_++) {                                        \
        int chunk_ = i_ * 256 + t;                                          \
        int c_ = chunk_ & 127, kg_ = chunk_ >> 7;                           \
        const float* xs_ = xb + (size_t)(32 * (kt) + 8 * kg_) * C + c_;     \
        _Pragma("unroll")                                                   \
        for (int e_ = 0; e_ < 8; e_++) dst[i_][e_] = xs_[(size_t)e_ * C]; } }

#define P_WRITEB_(src, buf) {                                               \
    _Pragma("unroll")                                                       \
    for (int i_ = 0; i_ < 2; i_++) {                                        \
        int chunk_ = i_ * 256 + t;                                          \
        int c_ = chunk_ & 127, kg_ = chunk_ >> 7;                           \
        uint4 w_;                                                           \
        w_.x = f2bf(src[i_][0]) | (f2bf(src[i_][1]) << 16);                 \
        w_.y = f2bf(src[i_][2]) | (f2bf(src[i_][3]) << 16);                 \
        w_.z = f2bf(src[i_][4]) | (f2bf(src[i_][5]) << 16);                 \
        w_.w = f2bf(src[i_][6]) | (f2bf(src[i_][7]) << 16);                 \
        *(uint4*)&Bs[buf][c_ >> 4][kg_][c_ & 15][0] = w_; } }

#define P_LOADA_(dst, kt) {                                                 \
    const char* ap_ = aimgc + (size_t)(kt) * 24576;                         \
    _Pragma("unroll")                                                       \
    for (int fi_ = 0; fi_ < 3; fi_++)                                       \
        dst[fi_] = *(const uint4*)(ap_ + fi_ * 1024); }

#define P_MFMA_(buf, au) {                                                  \
    s16x8 fb0 = *(const s16x8*)&Bs[buf][4 * wn + 0][g8][n16][0];            \
    s16x8 fb1 = *(const s16x8*)&Bs[buf][4 * wn + 1][g8][n16][0];            \
    s16x8 fb2 = *(const s16x8*)&Bs[buf][4 * wn + 2][g8][n16][0];            \
    s16x8 fb3 = *(const s16x8*)&Bs[buf][4 * wn + 3][g8][n16][0];            \
    _Pragma("unroll")                                                       \
    for (int fi_ = 0; fi_ < 3; fi_++) {                                     \
        s16x8 fa_ = *(s16x8*)&au[fi_];                                      \
        acc[fi_][0] = __builtin_amdgcn_mfma_f32_16x16x32_bf16(fa_, fb0, acc[fi_][0], 0, 0, 0); \
        acc[fi_][1] = __builtin_amdgcn_mfma_f32_16x16x32_bf16(fa_, fb1, acc[fi_][1], 0, 0, 0); \
        acc[fi_][2] = __builtin_amdgcn_mfma_f32_16x16x32_bf16(fa_, fb2, acc[fi_][2], 0, 0, 0); \
        acc[fi_][3] = __builtin_amdgcn_mfma_f32_16x16x32_bf16(fa_, fb3, acc[fi_][3], 0, 0, 0); } }

    float b0r[2][8], b1r[2][8];
    uint4 a0u[3], a1u[3];

    // prologue
    P_LOADA_(a0u, 0); P_LOADB_(b0r, 0);
    P_LOADA_(a1u, 1); P_LOADB_(b1r, 1);
    P_WRITEB_(b0r, 0);
    __syncthreads();

    for (int i = 0; i < 16; i++) {
        const int kt = 2 * i;
        // even step: compute kt from Bs[0]
        {
            uint4 au[3];
            #pragma unroll
            for (int fi = 0; fi < 3; fi++) au[fi] = a0u[fi];   // wait A(kt)
            if (kt + 2 < 32) { P_LOADA_(a0u, kt + 2); P_LOADB_(b0r, kt + 2); }
            P_MFMA_(0, au);
        }
        __syncthreads();
        P_WRITEB_(b1r, 1);                 // B(kt+1), loaded one step earlier
        __syncthreads();
        // odd step: compute kt+1 from Bs[1]
        {
            uint4 au[3];
            #pragma unroll
            for (int fi = 0; fi < 3; fi++) au[fi] = a1u[fi];
            if (kt + 3 < 32) { P_LOADA_(a1u, kt + 3); P_LOADB_(b1r, kt + 3); }
            P_MFMA_(1, au);
        }
        __syncthreads();
        if (kt + 2 < 32) P_WRITEB_(b0r, 0);
        __syncthreads();
    }

#undef P_LOADB_
#undef P_WRITEB_
#undef P_LOADA_
#undef P_MFMA_

    // ---- epilogue ----
    const int cb = wn * 64 + n16;
    float sdv[4], mnv[4], b3v[4];
    f32x4 w3r[4][4];
    #pragma unroll
    for (int fj = 0; fj < 4; fj++) {
        int c = cb + fj * 16;
        sdv[fj] = ws[WS_STD  + b * C + c];
        mnv[fj] = ws[WS_MEAN + b * C + c];
        b3v[fj] = b3[c];
        const f32x4* wr = (const f32x4*)(W3 + c * 16);
        #pragma unroll
        for (int q = 0; q < 4; q++) w3r[fj][q] = wr[q];
    }
    const int prow0 = ptile * 96 + wm * 48 + g8 * 4;
    #pragma unroll
    for (int fi = 0; fi < 3; fi++) {
        #pragma unroll
        for (int r = 0; r < 4; r++) {
            int p  = prow0 + fi * 16 + r;
            int pc = p < P ? p : P - 1;
            const f32x4* mrow = (const f32x4*)(ws + WS_M + ((size_t)b * P + pc) * 16);
            f32x4 m0 = mrow[0], m1 = mrow[1], m2 = mrow[2], m3 = mrow[3];
            const float* e = ws + WS_EPI + pc * 4;
            float A13 = e[0], A4 = e[1], A2 = e[2];
            #pragma unroll
            for (int fj = 0; fj < 4; fj++) {
                float s = 0.f;
                #pragma unroll
                for (int q = 0; q < 4; q++) {
                    const f32x4 mv = (q==0)?m0:(q==1)?m1:(q==2)?m2:m3;
                    s = fmaf(mv.x, w3r[fj][q].x, s);
                    s = fmaf(mv.y, w3r[fj][q].y, s);
                    s = fmaf(mv.z, w3r[fj][q].z, s);
                    s = fmaf(mv.w, w3r[fj][q].w, s);
                }
                float res = acc[fi][fj][r]
                          + sdv[fj] * (OMBf * s + A13 + A4 * b3v[fj])
                          + A2 * mnv[fj];
                if (p < P)
                    out[((size_t)b * P + p) * C + cb + fj * 16] = res;
            }
        }
    }
}

// ---------------------------------------------------------------------------
extern "C" void kernel_launch(void* const* d_in, const int* in_sizes, int n_in,
                              void* d_out, int out_size, void* d_ws, size_t ws_size,
                              hipStream_t stream)
{
    const float* x    = (const float*)d_in[0];
    const float* xme  = (const float*)d_in[1];
    const float* W1   = (const float*)d_in[4];
    const float* b1   = (const float*)d_in[5];
    const float* g1   = (const float*)d_in[6];
    const float* be1  = (const float*)d_in[7];
    const float* W2   = (const float*)d_in[8];
    const float* b2   = (const float*)d_in[9];
    const float* g2   = (const float*)d_in[10];
    const float* be2  = (const float*)d_in[11];
    const float* Wc   = (const float*)d_in[12];
    const float* bc   = (const float*)d_in[13];
    const float* W3   = (const float*)d_in[14];
    const float* b3   = (const float*)d_in[15];
    const float* Wtp  = (const float*)d_in[16];
    const float* btp  = (const float*)d_in[17];
    const float* Whp  = (const float*)d_in[18];
    const float* bhp  = (const float*)d_in[19];
    float* ws  = (float*)d_ws;
    float* out = (float*)d_out;

    k_prep  <<<dim3(P),      dim3(256), 0, stream>>>(Whp, Wtp, bc, bhp, btp, ws);
    k_stats1<<<dim3(B, 4),   dim3(256), 0, stream>>>(x, ws);
    k_stats2<<<dim3(64),     dim3(256), 0, stream>>>(ws);
    k_mlp   <<<dim3(512),    dim3(256), 0, stream>>>(xme, W1, b1, g1, be1,
                                                     W2, b2, g2, be2, ws);
    k_wcp   <<<dim3(4, 48),  dim3(256), 0, stream>>>(Wc, Wtp, ws);
    k_repack<<<dim3(96, 24), dim3(64),  0, stream>>>(ws);
    k_mconv <<<dim3(B, 6),   dim3(256), 0, stream>>>(ws);
    k_pred  <<<dim3(4, B),   dim3(256), 0, stream>>>(x, W3, b3, ws, out);
}

// Round 9
// 109.551 us; speedup vs baseline: 7.1641x; 1.2620x over previous
//
#include <hip/hip_runtime.h>
#include <hip/hip_bf16.h>

#define INV_SQRT2f 0.70710678118654752440f
#define BETAf 0.3f
#define OMBf  0.7f
#define LN_EPSf 1e-5f

#define B 128
#define S 1024
#define P 336
#define C 128
#define H1 32
#define H2 16

// ---------------- workspace layout (float offsets) ----------------
#define WS_WHP2G  0               // bf16 A-image for k_pred, 786432 B
#define WS_EPI    262144          // float4[384]: {A13, A4, A2, -}
#define WS_BCP    296448          // 384
#define WS_H2     296832          // 128*1024*16 = 2097152
#define WS_WCPT   2393984         // fp32 [p=336][m=3072] = 1032192 (dead after repack)
#define WS_M      2393984         // 128*336*16 = 688128  (overlays WCPT)
#define WS_AIMG   3426176         // bf16 conv A-image, 2359296 B = 589824 fl
// total < 4245376 floats = 16.98 MB

typedef short  s16x8 __attribute__((ext_vector_type(8)));
typedef float  f32x4 __attribute__((ext_vector_type(4)));

// exact RNE float->bf16
__device__ __forceinline__ unsigned f2bf(float f) {
    unsigned u = __float_as_uint(f);
    return (u + 0x7fffu + ((u >> 16) & 1u)) >> 16;
}

// k_pred A-image u32 index for the pair (u=2sp, u=2sp+1) of projection row p.
__device__ __forceinline__ int whp2l_u32(int p, int sp) {
    int kt   = sp >> 4;
    int tile = kt * 2 + p / 192;
    int sub  = (p % 192) >> 4;
    int kg   = (sp & 15) >> 2;
    int m    = p & 15;
    int byte = tile * 12288 + sub * 1024 + kg * 256 + m * 16 + 4 * (sp & 3);
    return byte >> 2;
}

// ---------------------------------------------------------------------------
// k_prep: bf16 A-image (Haar-folded, BETA-scaled Whp2) + EPI + bcP
__global__ void k_prep(const float* __restrict__ Whp, const float* __restrict__ Wtp,
                       const float* __restrict__ bc,  const float* __restrict__ bhp,
                       const float* __restrict__ btp, float* __restrict__ ws)
{
    const int p = blockIdx.x;     // 0..335
    const int t = threadIdx.x;    // 256
    unsigned* img = (unsigned*)ws;
    __shared__ float red[768];
    float sw = 0.f, rw = 0.f, bp = 0.f;
    for (int sp = t; sp < 512; sp += 256) {
        float a = Whp[p * 1024 + sp];
        float d = Whp[p * 1024 + 512 + sp];
        float va = BETAf * (a + d) * INV_SQRT2f;   // u = 2sp
        float vb = BETAf * (a - d) * INV_SQRT2f;   // u = 2sp+1
        img[whp2l_u32(p, sp)] = f2bf(va) | (f2bf(vb) << 16);
        sw += a + d;
    }
    for (int s = t; s < S; s += 256) {
        float w = Wtp[p * 1024 + s];
        rw += w;
        bp += w * bc[s];
    }
    red[t] = sw; red[256 + t] = rw; red[512 + t] = bp;
    __syncthreads();
    for (int off = 128; off > 0; off >>= 1) {
        if (t < off) {
            red[t]       += red[t + off];
            red[256 + t] += red[256 + t + off];
            red[512 + t] += red[512 + t + off];
        }
        __syncthreads();
    }
    if (t == 0) {
        ws[WS_BCP + p] = red[512];
        float* e = ws + WS_EPI + p * 4;
        e[0] = BETAf * bhp[p] + OMBf * btp[p];   // A13
        e[1] = OMBf * red[256];                  // A4 = OMB*rowWtp
        e[2] = 1.f - BETAf * red[0];             // A2 = 1-BETA*sumWhp
        e[3] = 0.f;
    }
}

// ---------------------------------------------------------------------------
// MLP
__global__ void k_mlp(const float* __restrict__ xme,
                      const float* __restrict__ W1, const float* __restrict__ b1,
                      const float* __restrict__ g1, const float* __restrict__ be1,
                      const float* __restrict__ W2, const float* __restrict__ b2,
                      const float* __restrict__ g2, const float* __restrict__ be2,
                      float* __restrict__ ws)
{
    __shared__ float w1s[128], b1s[32], g1s[32], be1s[32];
    __shared__ float w2s[512], b2s[16], g2s[16], be2s[16];
    const int t = threadIdx.x;
    if (t < 128) w1s[t] = W1[t];
    if (t < 32) { b1s[t] = b1[t]; g1s[t] = g1[t]; be1s[t] = be1[t]; }
    for (int i = t; i < 512; i += 256) w2s[i] = W2[i];
    if (t < 16) { b2s[t] = b2[t]; g2s[t] = g2[t]; be2s[t] = be2[t]; }
    __syncthreads();

    const int row = blockIdx.x * 256 + t;
    float4 v = *(const float4*)(xme + (size_t)row * 4);

    float h1v[32];
    float m = 0.f;
    #pragma unroll
    for (int i = 0; i < 32; i++) {
        float a = w1s[i*4+0]*v.x + w1s[i*4+1]*v.y + w1s[i*4+2]*v.z + w1s[i*4+3]*v.w + b1s[i];
        h1v[i] = a; m += a;
    }
    m *= (1.f / 32.f);
    float var = 0.f;
    #pragma unroll
    for (int i = 0; i < 32; i++) { float d = h1v[i] - m; var += d * d; }
    var *= (1.f / 32.f);
    float rs = rsqrtf(var + LN_EPSf);
    #pragma unroll
    for (int i = 0; i < 32; i++)
        h1v[i] = fmaxf((h1v[i] - m) * rs * g1s[i] + be1s[i], 0.f);

    float h2v[16];
    float m2 = 0.f;
    #pragma unroll
    for (int g = 0; g < 16; g++) {
        float a = b2s[g];
        #pragma unroll
        for (int i = 0; i < 32; i++) a = fmaf(w2s[g * 32 + i], h1v[i], a);
        h2v[g] = a; m2 += a;
    }
    m2 *= (1.f / 16.f);
    float v2 = 0.f;
    #pragma unroll
    for (int g = 0; g < 16; g++) { float d = h2v[g] - m2; v2 += d * d; }
    v2 *= (1.f / 16.f);
    float rs2 = rsqrtf(v2 + LN_EPSf);
    float* h2o = ws + WS_H2 + (size_t)row * 16;
    #pragma unroll
    for (int g = 0; g < 16; g++)
        h2o[g] = fmaxf((h2v[g] - m2) * rs2 * g2s[g] + be2s[g], 0.f);
}

// ---------------------------------------------------------------------------
// k_wcp (MFMA, 2-deep pipeline) — unchanged, passing.
__global__ __launch_bounds__(256) void k_wcp(const float* __restrict__ Wc,
                                             const float* __restrict__ Wtp,
                                             float* __restrict__ ws)
{
    __shared__ __align__(16) unsigned short Bs[2][4][4][16][8];   // 8192 B
    const int pbase = blockIdx.x * 96;
    const int n0    = blockIdx.y * 64;
    const int t     = threadIdx.x;
    const int lane  = t & 63;
    const int wid   = t >> 6;
    const int wm    = wid >> 1;          // 0,1
    const int wn    = wid & 1;           // 0,1
    const int g8    = lane >> 4;         // 0..3  (k-group)
    const int n16   = lane & 15;

    const int bn  = t & 63;
    const int bkg = t >> 6;

    int prow[3];
    #pragma unroll
    for (int fi = 0; fi < 3; fi++) {
        int pr = pbase + wm * 48 + fi * 16 + n16;
        prow[fi] = pr < P ? pr : P - 1;
    }

#define LOADB_(dst, kt) {                                                   \
    const float* xs_ = Wc + (size_t)((kt) * 32 + 8 * bkg) * 3072 + n0 + bn; \
    _Pragma("unroll")                                                       \
    for (int e_ = 0; e_ < 8; e_++) dst[e_] = xs_[(size_t)e_ * 3072]; }

#define WRITEB_(src, buf) {                                                 \
    uint4 w_;                                                               \
    w_.x = f2bf(src[0]) | (f2bf(src[1]) << 16);                             \
    w_.y = f2bf(src[2]) | (f2bf(src[3]) << 16);                             \
    w_.z = f2bf(src[4]) | (f2bf(src[5]) << 16);                             \
    w_.w = f2bf(src[6]) | (f2bf(src[7]) << 16);                             \
    *(uint4*)&Bs[buf][bn >> 4][bkg][bn & 15][0] = w_; }

#define LOADA_(dst, kt) {                                                   \
    _Pragma("unroll")                                                       \
    for (int fi_ = 0; fi_ < 3; fi_++) {                                     \
        const float* as_ = Wtp + (size_t)prow[fi_] * 1024 + (kt) * 32 + g8 * 8; \
        dst[fi_][0] = *(const float4*)(as_);                                \
        dst[fi_][1] = *(const float4*)(as_ + 4); } }

#define PACKA_(fa, src) {                                                   \
    _Pragma("unroll")                                                       \
    for (int fi_ = 0; fi_ < 3; fi_++) {                                     \
        uint4 w_;                                                           \
        w_.x = f2bf(src[fi_][0].x) | (f2bf(src[fi_][0].y) << 16);           \
        w_.y = f2bf(src[fi_][0].z) | (f2bf(src[fi_][0].w) << 16);           \
        w_.z = f2bf(src[fi_][1].x) | (f2bf(src[fi_][1].y) << 16);           \
        w_.w = f2bf(src[fi_][1].z) | (f2bf(src[fi_][1].w) << 16);           \
        fa[fi_] = *(s16x8*)&w_; } }

#define MFMA6_(buf, fa) {                                                   \
    s16x8 fb0 = *(const s16x8*)&Bs[buf][2 * wn + 0][g8][n16][0];            \
    s16x8 fb1 = *(const s16x8*)&Bs[buf][2 * wn + 1][g8][n16][0];            \
    _Pragma("unroll")                                                       \
    for (int fi_ = 0; fi_ < 3; fi_++) {                                     \
        acc[fi_][0] = __builtin_amdgcn_mfma_f32_16x16x32_bf16(fa[fi_], fb0, acc[fi_][0], 0, 0, 0); \
        acc[fi_][1] = __builtin_amdgcn_mfma_f32_16x16x32_bf16(fa[fi_], fb1, acc[fi_][1], 0, 0, 0); } }

    f32x4 acc[3][2];
    #pragma unroll
    for (int i = 0; i < 3; i++) {
        acc[i][0] = (f32x4){0.f, 0.f, 0.f, 0.f};
        acc[i][1] = (f32x4){0.f, 0.f, 0.f, 0.f};
    }

    float  b0r[8], b1r[8];
    float4 a0r[3][2], a1r[3][2];

    LOADA_(a0r, 0); LOADB_(b0r, 0);
    LOADA_(a1r, 1); LOADB_(b1r, 1);
    WRITEB_(b0r, 0);
    __syncthreads();

    for (int i = 0; i < 16; i++) {
        const int kt = 2 * i;
        {
            s16x8 fa[3];
            PACKA_(fa, a0r);
            if (kt + 2 < 32) { LOADA_(a0r, kt + 2); LOADB_(b0r, kt + 2); }
            MFMA6_(0, fa);
        }
        __syncthreads();
        WRITEB_(b1r, 1);
        __syncthreads();
        {
            s16x8 fa[3];
            PACKA_(fa, a1r);
            if (kt + 3 < 32) { LOADA_(a1r, kt + 3); LOADB_(b1r, kt + 3); }
            MFMA6_(1, fa);
        }
        __syncthreads();
        if (kt + 2 < 32) WRITEB_(b0r, 0);
        __syncthreads();
    }

#undef LOADB_
#undef WRITEB_
#undef LOADA_
#undef PACKA_
#undef MFMA6_

    float* wcT = ws + WS_WCPT;
    #pragma unroll
    for (int fi = 0; fi < 3; fi++) {
        #pragma unroll
        for (int r = 0; r < 4; r++) {
            int p = pbase + wm * 48 + fi * 16 + g8 * 4 + r;
            if (p < P) {
                wcT[(size_t)p * 3072 + n0 + wn * 32 + 0 * 16 + n16] = acc[fi][0][r];
                wcT[(size_t)p * 3072 + n0 + wn * 32 + 1 * 16 + n16] = acc[fi][1][r];
            }
        }
    }
}

// ---------------------------------------------------------------------------
// k_repack: fp32 WcPT_T[p][m3]  ->  bf16 MFMA A-image.
__global__ void k_repack(float* __restrict__ ws)
{
    const int l  = threadIdx.x;          // 0..63
    const int ch = blockIdx.x;           // k*32+kt, 0..95
    const int pf = blockIdx.y;           // 0..23
    const int k  = ch >> 5;
    const int i0 = (ch & 31) * 32 + (l >> 4) * 8;
    const int p  = pf * 16 + (l & 15);
    uint4 w = make_uint4(0, 0, 0, 0);
    if (p < P) {
        const float* wcT = ws + WS_WCPT + (size_t)p * 3072;
        float v[8];
        #pragma unroll
        for (int e = 0; e < 8; e++)
            v[e] = wcT[(i0 + e) * 3 + k];
        w.x = f2bf(v[0]) | (f2bf(v[1]) << 16);
        w.y = f2bf(v[2]) | (f2bf(v[3]) << 16);
        w.z = f2bf(v[4]) | (f2bf(v[5]) << 16);
        w.w = f2bf(v[6]) | (f2bf(v[7]) << 16);
    }
    ((uint4*)(ws + WS_AIMG))[(size_t)(ch * 24 + pf) * 64 + l] = w;
}

// ---------------------------------------------------------------------------
// k_mconv (MFMA): M[b,p,g] = bcP[p] + sum_k sum_i A_k[p][i] * h[b,i,g+k-1]
#define HT_RS 1056            /* u16 elems per row (2112 B) */
__global__ __launch_bounds__(256) void k_mconv(float* __restrict__ ws)
{
    __shared__ unsigned short Ht[18 * HT_RS];   // 38016 B
    const int b  = blockIdx.x;
    const int pt = blockIdx.y;                  // 0..5
    const int t  = threadIdx.x;
    const int l  = t & 63;
    const int wid = t >> 6;
    const int pf = pt * 4 + wid;                // 0..23
    const int n16 = l & 15;
    const int g8  = l >> 4;

    for (int j = t; j < HT_RS; j += 256) {
        Ht[j] = 0;
        Ht[17 * HT_RS + j] = 0;
    }
    {
        const float* h2b = ws + WS_H2 + (size_t)b * 16384;
        const int s0 = t * 4;
        float v[4][16];
        #pragma unroll
        for (int rr = 0; rr < 4; rr++) {
            const float4* src = (const float4*)(h2b + (size_t)(s0 + rr) * 16);
            float4 a0 = src[0], a1 = src[1], a2 = src[2], a3 = src[3];
            v[rr][0]=a0.x; v[rr][1]=a0.y; v[rr][2]=a0.z; v[rr][3]=a0.w;
            v[rr][4]=a1.x; v[rr][5]=a1.y; v[rr][6]=a1.z; v[rr][7]=a1.w;
            v[rr][8]=a2.x; v[rr][9]=a2.y; v[rr][10]=a2.z; v[rr][11]=a2.w;
            v[rr][12]=a3.x; v[rr][13]=a3.y; v[rr][14]=a3.z; v[rr][15]=a3.w;
        }
        #pragma unroll
        for (int g = 0; g < 16; g++) {
            uint2 w;
            w.x = f2bf(v[0][g]) | (f2bf(v[1][g]) << 16);
            w.y = f2bf(v[2][g]) | (f2bf(v[3][g]) << 16);
            *(uint2*)&Ht[(g + 1) * HT_RS + s0] = w;
        }
    }
    __syncthreads();

    const uint4* ap = (const uint4*)(ws + WS_AIMG) + (size_t)pf * 64 + l;
    f32x4 acc = (f32x4){0.f, 0.f, 0.f, 0.f};
    uint4 fan = *ap;                    // prefetch it=0
    #pragma unroll 4
    for (int it = 0; it < 96; it++) {
        uint4 fac = fan;
        ap += 24 * 64;
        if (it < 95) fan = *ap;
        const int k  = it >> 5;
        const int kt = it & 31;
        s16x8 fb = *(const s16x8*)&Ht[(n16 + k) * HT_RS + kt * 32 + g8 * 8];
        s16x8 fa = *(s16x8*)&fac;
        acc = __builtin_amdgcn_mfma_f32_16x16x32_bf16(fa, fb, acc, 0, 0, 0);
    }

    #pragma unroll
    for (int r = 0; r < 4; r++) {
        int p = pf * 16 + g8 * 4 + r;
        if (p < P)
            ws[WS_M + ((size_t)b * P + p) * 16 + n16] = acc[r] + ws[WS_BCP + p];
    }
}

// ---------------------------------------------------------------------------
// k_pred v3: MFMA bf16 GEMM + fused stats + fused epilogue.
// grid (b=128, ptile=4): same-b blocks are 128 apart in dispatch id ==
// same id mod 8 -> SAME XCD -> the 4 sharers of x[b] hit one L2 (T1).
// Stats fused: each block stages all of x[b]; accumulate ev/sq during
// staging (each element exactly once), LDS-reduce, mean/std in-kernel.
__global__ __launch_bounds__(256, 2) void k_pred(
    const float* __restrict__ x,
    const float* __restrict__ W3, const float* __restrict__ b3,
    const float* __restrict__ ws, float* __restrict__ out)
{
    __shared__ __align__(16) unsigned short Bs[2][8][4][16][8];   // 32768 B
    __shared__ float sev[256], ssq[256], smean[128], sstd[128];
    const int b     = blockIdx.x;
    const int ptile = blockIdx.y;        // 0..3 (96 p-rows each)
    const int t     = threadIdx.x;
    const int lane  = t & 63;
    const int wid   = t >> 6;
    const int wm    = wid >> 1;          // 0,1
    const int wn    = wid & 1;           // 0,1
    const int g8    = lane >> 4;         // 0..3  (k-group)
    const int n16   = lane & 15;

    const float* xb = x + (size_t)b * S * C;
    // A image: tile (kt*2 + (ptile>>1)) * 12288 B; subs (ptile&1)*6 + wm*3 + fi
    const char* aimgc = (const char*)ws
        + ((ptile >> 1) * 12288)
        + (((ptile & 1) * 6 + wm * 3) * 1024)
        + (g8 * 256 + n16 * 16);

    f32x4 acc[3][4];
    #pragma unroll
    for (int i = 0; i < 3; i++)
        #pragma unroll
        for (int j = 0; j < 4; j++) acc[i][j] = (f32x4){0.f, 0.f, 0.f, 0.f};

    float ev_acc = 0.f, sq_acc = 0.f;    // per-thread stats partials (col t&127)

#define P_LOADB_(dst, kt) {                                                 \
    _Pragma("unroll")                                                       \
    for (int i_ = 0; i_ < 2; i_++) {                                        \
        int chunk_ = i_ * 256 + t;                                          \
        int c_ = chunk_ & 127, kg_ = chunk_ >> 7;                           \
        const float* xs_ = xb + (size_t)(32 * (kt) + 8 * kg_) * C + c_;     \
        _Pragma("unroll")                                                   \
        for (int e_ = 0; e_ < 8; e_++) dst[i_][e_] = xs_[(size_t)e_ * C]; } }

#define P_WRITEB_(src, buf) {                                               \
    _Pragma("unroll")                                                       \
    for (int i_ = 0; i_ < 2; i_++) {                                        \
        int chunk_ = i_ * 256 + t;                                          \
        int c_ = chunk_ & 127, kg_ = chunk_ >> 7;                           \
        uint4 w_;                                                           \
        w_.x = f2bf(src[i_][0]) | (f2bf(src[i_][1]) << 16);                 \
        w_.y = f2bf(src[i_][2]) | (f2bf(src[i_][3]) << 16);                 \
        w_.z = f2bf(src[i_][4]) | (f2bf(src[i_][5]) << 16);                 \
        w_.w = f2bf(src[i_][6]) | (f2bf(src[i_][7]) << 16);                 \
        *(uint4*)&Bs[buf][c_ >> 4][kg_][c_ & 15][0] = w_;                   \
        _Pragma("unroll")                                                   \
        for (int e_ = 0; e_ < 8; e_++) {                                    \
            float v_ = src[i_][e_];                                         \
            sq_acc = fmaf(v_, v_, sq_acc);                                  \
            if ((e_ & 1) == 0) ev_acc += v_;   /* s=32kt+8kg+e: even<=>e even */ \
        } } }

#define P_LOADA_(dst, kt) {                                                 \
    const char* ap_ = aimgc + (size_t)(kt) * 24576;                         \
    _Pragma("unroll")                                                       \
    for (int fi_ = 0; fi_ < 3; fi_++)                                       \
        dst[fi_] = *(const uint4*)(ap_ + fi_ * 1024); }

#define P_MFMA_(buf, au) {                                                  \
    s16x8 fb0 = *(const s16x8*)&Bs[buf][4 * wn + 0][g8][n16][0];            \
    s16x8 fb1 = *(const s16x8*)&Bs[buf][4 * wn + 1][g8][n16][0];            \
    s16x8 fb2 = *(const s16x8*)&Bs[buf][4 * wn + 2][g8][n16][0];            \
    s16x8 fb3 = *(const s16x8*)&Bs[buf][4 * wn + 3][g8][n16][0];            \
    _Pragma("unroll")                                                       \
    for (int fi_ = 0; fi_ < 3; fi_++) {                                     \
        s16x8 fa_ = *(s16x8*)&au[fi_];                                      \
        acc[fi_][0] = __builtin_amdgcn_mfma_f32_16x16x32_bf16(fa_, fb0, acc[fi_][0], 0, 0, 0); \
        acc[fi_][1] = __builtin_amdgcn_mfma_f32_16x16x32_bf16(fa_, fb1, acc[fi_][1], 0, 0, 0); \
        acc[fi_][2] = __builtin_amdgcn_mfma_f32_16x16x32_bf16(fa_, fb2, acc[fi_][2], 0, 0, 0); \
        acc[fi_][3] = __builtin_amdgcn_mfma_f32_16x16x32_bf16(fa_, fb3, acc[fi_][3], 0, 0, 0); } }

    float b0r[2][8], b1r[2][8];
    uint4 a0u[3], a1u[3];

    // prologue
    P_LOADA_(a0u, 0); P_LOADB_(b0r, 0);
    P_LOADA_(a1u, 1); P_LOADB_(b1r, 1);
    P_WRITEB_(b0r, 0);
    __syncthreads();

    for (int i = 0; i < 16; i++) {
        const int kt = 2 * i;
        // even step: compute kt from Bs[0]
        {
            uint4 au[3];
            #pragma unroll
            for (int fi = 0; fi < 3; fi++) au[fi] = a0u[fi];   // wait A(kt)
            if (kt + 2 < 32) { P_LOADA_(a0u, kt + 2); P_LOADB_(b0r, kt + 2); }
            P_MFMA_(0, au);
        }
        __syncthreads();
        P_WRITEB_(b1r, 1);                 // B(kt+1), loaded one step earlier
        __syncthreads();
        // odd step: compute kt+1 from Bs[1]
        {
            uint4 au[3];
            #pragma unroll
            for (int fi = 0; fi < 3; fi++) au[fi] = a1u[fi];
            if (kt + 3 < 32) { P_LOADA_(a1u, kt + 3); P_LOADB_(b1r, kt + 3); }
            P_MFMA_(1, au);
        }
        __syncthreads();
        if (kt + 2 < 32) P_WRITEB_(b0r, 0);
        __syncthreads();
    }

#undef P_LOADB_
#undef P_WRITEB_
#undef P_LOADA_
#undef P_MFMA_

    // ---- in-block stats reduction (threads t and t+128 share column t&127) ----
    sev[t] = ev_acc; ssq[t] = sq_acc;
    __syncthreads();
    if (t < 128) {
        float ev = sev[t] + sev[t + 128];
        float sq = ssq[t] + ssq[t + 128];
        float mean = ev * (INV_SQRT2f / 512.f);
        float var  = (sq - 1024.f * mean * mean) * (1.f / 1023.f);  // ddof=1
        smean[t] = mean;
        sstd[t]  = sqrtf(var + LN_EPSf);
    }
    __syncthreads();

    // ---- epilogue ----
    const int cb = wn * 64 + n16;
    float sdv[4], mnv[4], b3v[4];
    f32x4 w3r[4][4];
    #pragma unroll
    for (int fj = 0; fj < 4; fj++) {
        int c = cb + fj * 16;
        sdv[fj] = sstd[c];
        mnv[fj] = smean[c];
        b3v[fj] = b3[c];
        const f32x4* wr = (const f32x4*)(W3 + c * 16);
        #pragma unroll
        for (int q = 0; q < 4; q++) w3r[fj][q] = wr[q];
    }
    const int prow0 = ptile * 96 + wm * 48 + g8 * 4;
    #pragma unroll
    for (int fi = 0; fi < 3; fi++) {
        #pragma unroll
        for (int r = 0; r < 4; r++) {
            int p  = prow0 + fi * 16 + r;
            int pc = p < P ? p : P - 1;
            const f32x4* mrow = (const f32x4*)(ws + WS_M + ((size_t)b * P + pc) * 16);
            f32x4 m0 = mrow[0], m1 = mrow[1], m2 = mrow[2], m3 = mrow[3];
            const float* e = ws + WS_EPI + pc * 4;
            float A13 = e[0], A4 = e[1], A2 = e[2];
            #pragma unroll
            for (int fj = 0; fj < 4; fj++) {
                float s = 0.f;
                #pragma unroll
                for (int q = 0; q < 4; q++) {
                    const f32x4 mv = (q==0)?m0:(q==1)?m1:(q==2)?m2:m3;
                    s = fmaf(mv.x, w3r[fj][q].x, s);
                    s = fmaf(mv.y, w3r[fj][q].y, s);
                    s = fmaf(mv.z, w3r[fj][q].z, s);
                    s = fmaf(mv.w, w3r[fj][q].w, s);
                }
                float res = acc[fi][fj][r]
                          + sdv[fj] * (OMBf * s + A13 + A4 * b3v[fj])
                          + A2 * mnv[fj];
                if (p < P)
                    out[((size_t)b * P + p) * C + cb + fj * 16] = res;
            }
        }
    }
}

// ---------------------------------------------------------------------------
extern "C" void kernel_launch(void* const* d_in, const int* in_sizes, int n_in,
                              void* d_out, int out_size, void* d_ws, size_t ws_size,
                              hipStream_t stream)
{
    const float* x    = (const float*)d_in[0];
    const float* xme  = (const float*)d_in[1];
    const float* W1   = (const float*)d_in[4];
    const float* b1   = (const float*)d_in[5];
    const float* g1   = (const float*)d_in[6];
    const float* be1  = (const float*)d_in[7];
    const float* W2   = (const float*)d_in[8];
    const float* b2   = (const float*)d_in[9];
    const float* g2   = (const float*)d_in[10];
    const float* be2  = (const float*)d_in[11];
    const float* Wc   = (const float*)d_in[12];
    const float* bc   = (const float*)d_in[13];
    const float* W3   = (const float*)d_in[14];
    const float* b3   = (const float*)d_in[15];
    const float* Wtp  = (const float*)d_in[16];
    const float* btp  = (const float*)d_in[17];
    const float* Whp  = (const float*)d_in[18];
    const float* bhp  = (const float*)d_in[19];
    float* ws  = (float*)d_ws;
    float* out = (float*)d_out;

    k_prep  <<<dim3(P),      dim3(256), 0, stream>>>(Whp, Wtp, bc, bhp, btp, ws);
    k_mlp   <<<dim3(512),    dim3(256), 0, stream>>>(xme, W1, b1, g1, be1,
                                                     W2, b2, g2, be2, ws);
    k_wcp   <<<dim3(4, 48),  dim3(256), 0, stream>>>(Wc, Wtp, ws);
    k_repack<<<dim3(96, 24), dim3(64),  0, stream>>>(ws);
    k_mconv <<<dim3(B, 6),   dim3(256), 0, stream>>>(ws);
    k_pred  <<<dim3(B, 4),   dim3(256), 0, stream>>>(x, W3, b3, ws, out);
}

// Round 10
// 104.686 us; speedup vs baseline: 7.4970x; 1.0465x over previous
//
#include <hip/hip_runtime.h>
#include <hip/hip_bf16.h>

#define INV_SQRT2f 0.70710678118654752440f
#define BETAf 0.3f
#define OMBf  0.7f
#define LN_EPSf 1e-5f

#define B 128
#define S 1024
#define P 336
#define C 128
#define H1 32
#define H2 16

// ---------------- workspace layout (float offsets) ----------------
#define WS_WHP2G  0               // bf16 A-image for k_pred, 786432 B
#define WS_EPI    262144          // float4[384]: {A13, A4, A2, -}
#define WS_BCP    296448          // 384
#define WS_H2     296832          // 128*1024*16 = 2097152
#define WS_WCPT   2393984         // fp32 [p=336][m=3072] = 1032192 (dead after repack)
#define WS_M      2393984         // 128*336*16 = 688128  (overlays WCPT)
#define WS_AIMG   3426176         // bf16 conv A-image, 2359296 B = 589824 fl
// total < 4245376 floats = 16.98 MB

typedef short  s16x8 __attribute__((ext_vector_type(8)));
typedef float  f32x4 __attribute__((ext_vector_type(4)));

// exact RNE float->bf16
__device__ __forceinline__ unsigned f2bf(float f) {
    unsigned u = __float_as_uint(f);
    return (u + 0x7fffu + ((u >> 16) & 1u)) >> 16;
}

// k_pred A-image u32 index for the pair (u=2sp, u=2sp+1) of projection row p.
__device__ __forceinline__ int whp2l_u32(int p, int sp) {
    int kt   = sp >> 4;
    int tile = kt * 2 + p / 192;
    int sub  = (p % 192) >> 4;
    int kg   = (sp & 15) >> 2;
    int m    = p & 15;
    int byte = tile * 12288 + sub * 1024 + kg * 256 + m * 16 + 4 * (sp & 3);
    return byte >> 2;
}

// ---------------------------------------------------------------------------
// k_prep: bf16 A-image (Haar-folded, BETA-scaled Whp2) + EPI + bcP
__global__ void k_prep(const float* __restrict__ Whp, const float* __restrict__ Wtp,
                       const float* __restrict__ bc,  const float* __restrict__ bhp,
                       const float* __restrict__ btp, float* __restrict__ ws)
{
    const int p = blockIdx.x;     // 0..335
    const int t = threadIdx.x;    // 256
    unsigned* img = (unsigned*)ws;
    __shared__ float red[768];
    float sw = 0.f, rw = 0.f, bp = 0.f;
    for (int sp = t; sp < 512; sp += 256) {
        float a = Whp[p * 1024 + sp];
        float d = Whp[p * 1024 + 512 + sp];
        float va = BETAf * (a + d) * INV_SQRT2f;   // u = 2sp
        float vb = BETAf * (a - d) * INV_SQRT2f;   // u = 2sp+1
        img[whp2l_u32(p, sp)] = f2bf(va) | (f2bf(vb) << 16);
        sw += a + d;
    }
    for (int s = t; s < S; s += 256) {
        float w = Wtp[p * 1024 + s];
        rw += w;
        bp += w * bc[s];
    }
    red[t] = sw; red[256 + t] = rw; red[512 + t] = bp;
    __syncthreads();
    for (int off = 128; off > 0; off >>= 1) {
        if (t < off) {
            red[t]       += red[t + off];
            red[256 + t] += red[256 + t + off];
            red[512 + t] += red[512 + t + off];
        }
        __syncthreads();
    }
    if (t == 0) {
        ws[WS_BCP + p] = red[512];
        float* e = ws + WS_EPI + p * 4;
        e[0] = BETAf * bhp[p] + OMBf * btp[p];   // A13
        e[1] = OMBf * red[256];                  // A4 = OMB*rowWtp
        e[2] = 1.f - BETAf * red[0];             // A2 = 1-BETA*sumWhp
        e[3] = 0.f;
    }
}

// ---------------------------------------------------------------------------
// MLP
__global__ void k_mlp(const float* __restrict__ xme,
                      const float* __restrict__ W1, const float* __restrict__ b1,
                      const float* __restrict__ g1, const float* __restrict__ be1,
                      const float* __restrict__ W2, const float* __restrict__ b2,
                      const float* __restrict__ g2, const float* __restrict__ be2,
                      float* __restrict__ ws)
{
    __shared__ float w1s[128], b1s[32], g1s[32], be1s[32];
    __shared__ float w2s[512], b2s[16], g2s[16], be2s[16];
    const int t = threadIdx.x;
    if (t < 128) w1s[t] = W1[t];
    if (t < 32) { b1s[t] = b1[t]; g1s[t] = g1[t]; be1s[t] = be1[t]; }
    for (int i = t; i < 512; i += 256) w2s[i] = W2[i];
    if (t < 16) { b2s[t] = b2[t]; g2s[t] = g2[t]; be2s[t] = be2[t]; }
    __syncthreads();

    const int row = blockIdx.x * 256 + t;
    float4 v = *(const float4*)(xme + (size_t)row * 4);

    float h1v[32];
    float m = 0.f;
    #pragma unroll
    for (int i = 0; i < 32; i++) {
        float a = w1s[i*4+0]*v.x + w1s[i*4+1]*v.y + w1s[i*4+2]*v.z + w1s[i*4+3]*v.w + b1s[i];
        h1v[i] = a; m += a;
    }
    m *= (1.f / 32.f);
    float var = 0.f;
    #pragma unroll
    for (int i = 0; i < 32; i++) { float d = h1v[i] - m; var += d * d; }
    var *= (1.f / 32.f);
    float rs = rsqrtf(var + LN_EPSf);
    #pragma unroll
    for (int i = 0; i < 32; i++)
        h1v[i] = fmaxf((h1v[i] - m) * rs * g1s[i] + be1s[i], 0.f);

    float h2v[16];
    float m2 = 0.f;
    #pragma unroll
    for (int g = 0; g < 16; g++) {
        float a = b2s[g];
        #pragma unroll
        for (int i = 0; i < 32; i++) a = fmaf(w2s[g * 32 + i], h1v[i], a);
        h2v[g] = a; m2 += a;
    }
    m2 *= (1.f / 16.f);
    float v2 = 0.f;
    #pragma unroll
    for (int g = 0; g < 16; g++) { float d = h2v[g] - m2; v2 += d * d; }
    v2 *= (1.f / 16.f);
    float rs2 = rsqrtf(v2 + LN_EPSf);
    float* h2o = ws + WS_H2 + (size_t)row * 16;
    #pragma unroll
    for (int g = 0; g < 16; g++)
        h2o[g] = fmaxf((h2v[g] - m2) * rs2 * g2s[g] + be2s[g], 0.f);
}

// ---------------------------------------------------------------------------
// k_wcp (MFMA, 2-deep pipeline) — unchanged, passing.
__global__ __launch_bounds__(256) void k_wcp(const float* __restrict__ Wc,
                                             const float* __restrict__ Wtp,
                                             float* __restrict__ ws)
{
    __shared__ __align__(16) unsigned short Bs[2][4][4][16][8];   // 8192 B
    const int pbase = blockIdx.x * 96;
    const int n0    = blockIdx.y * 64;
    const int t     = threadIdx.x;
    const int lane  = t & 63;
    const int wid   = t >> 6;
    const int wm    = wid >> 1;          // 0,1
    const int wn    = wid & 1;           // 0,1
    const int g8    = lane >> 4;         // 0..3  (k-group)
    const int n16   = lane & 15;

    const int bn  = t & 63;
    const int bkg = t >> 6;

    int prow[3];
    #pragma unroll
    for (int fi = 0; fi < 3; fi++) {
        int pr = pbase + wm * 48 + fi * 16 + n16;
        prow[fi] = pr < P ? pr : P - 1;
    }

#define LOADB_(dst, kt) {                                                   \
    const float* xs_ = Wc + (size_t)((kt) * 32 + 8 * bkg) * 3072 + n0 + bn; \
    _Pragma("unroll")                                                       \
    for (int e_ = 0; e_ < 8; e_++) dst[e_] = xs_[(size_t)e_ * 3072]; }

#define WRITEB_(src, buf) {                                                 \
    uint4 w_;                                                               \
    w_.x = f2bf(src[0]) | (f2bf(src[1]) << 16);                             \
    w_.y = f2bf(src[2]) | (f2bf(src[3]) << 16);                             \
    w_.z = f2bf(src[4]) | (f2bf(src[5]) << 16);                             \
    w_.w = f2bf(src[6]) | (f2bf(src[7]) << 16);                             \
    *(uint4*)&Bs[buf][bn >> 4][bkg][bn & 15][0] = w_; }

#define LOADA_(dst, kt) {                                                   \
    _Pragma("unroll")                                                       \
    for (int fi_ = 0; fi_ < 3; fi_++) {                                     \
        const float* as_ = Wtp + (size_t)prow[fi_] * 1024 + (kt) * 32 + g8 * 8; \
        dst[fi_][0] = *(const float4*)(as_);                                \
        dst[fi_][1] = *(const float4*)(as_ + 4); } }

#define PACKA_(fa, src) {                                                   \
    _Pragma("unroll")                                                       \
    for (int fi_ = 0; fi_ < 3; fi_++) {                                     \
        uint4 w_;                                                           \
        w_.x = f2bf(src[fi_][0].x) | (f2bf(src[fi_][0].y) << 16);           \
        w_.y = f2bf(src[fi_][0].z) | (f2bf(src[fi_][0].w) << 16);           \
        w_.z = f2bf(src[fi_][1].x) | (f2bf(src[fi_][1].y) << 16);           \
        w_.w = f2bf(src[fi_][1].z) | (f2bf(src[fi_][1].w) << 16);           \
        fa[fi_] = *(s16x8*)&w_; } }

#define MFMA6_(buf, fa) {                                                   \
    s16x8 fb0 = *(const s16x8*)&Bs[buf][2 * wn + 0][g8][n16][0];            \
    s16x8 fb1 = *(const s16x8*)&Bs[buf][2 * wn + 1][g8][n16][0];            \
    _Pragma("unroll")                                                       \
    for (int fi_ = 0; fi_ < 3; fi_++) {                                     \
        acc[fi_][0] = __builtin_amdgcn_mfma_f32_16x16x32_bf16(fa[fi_], fb0, acc[fi_][0], 0, 0, 0); \
        acc[fi_][1] = __builtin_amdgcn_mfma_f32_16x16x32_bf16(fa[fi_], fb1, acc[fi_][1], 0, 0, 0); } }

    f32x4 acc[3][2];
    #pragma unroll
    for (int i = 0; i < 3; i++) {
        acc[i][0] = (f32x4){0.f, 0.f, 0.f, 0.f};
        acc[i][1] = (f32x4){0.f, 0.f, 0.f, 0.f};
    }

    float  b0r[8], b1r[8];
    float4 a0r[3][2], a1r[3][2];

    LOADA_(a0r, 0); LOADB_(b0r, 0);
    LOADA_(a1r, 1); LOADB_(b1r, 1);
    WRITEB_(b0r, 0);
    __syncthreads();

    for (int i = 0; i < 16; i++) {
        const int kt = 2 * i;
        {
            s16x8 fa[3];
            PACKA_(fa, a0r);
            if (kt + 2 < 32) { LOADA_(a0r, kt + 2); LOADB_(b0r, kt + 2); }
            MFMA6_(0, fa);
        }
        __syncthreads();
        WRITEB_(b1r, 1);
        __syncthreads();
        {
            s16x8 fa[3];
            PACKA_(fa, a1r);
            if (kt + 3 < 32) { LOADA_(a1r, kt + 3); LOADB_(b1r, kt + 3); }
            MFMA6_(1, fa);
        }
        __syncthreads();
        if (kt + 2 < 32) WRITEB_(b0r, 0);
        __syncthreads();
    }

#undef LOADB_
#undef WRITEB_
#undef LOADA_
#undef PACKA_
#undef MFMA6_

    float* wcT = ws + WS_WCPT;
    #pragma unroll
    for (int fi = 0; fi < 3; fi++) {
        #pragma unroll
        for (int r = 0; r < 4; r++) {
            int p = pbase + wm * 48 + fi * 16 + g8 * 4 + r;
            if (p < P) {
                wcT[(size_t)p * 3072 + n0 + wn * 32 + 0 * 16 + n16] = acc[fi][0][r];
                wcT[(size_t)p * 3072 + n0 + wn * 32 + 1 * 16 + n16] = acc[fi][1][r];
            }
        }
    }
}

// ---------------------------------------------------------------------------
// k_repack: fp32 WcPT_T[p][m3]  ->  bf16 MFMA A-image.
__global__ void k_repack(float* __restrict__ ws)
{
    const int l  = threadIdx.x;          // 0..63
    const int ch = blockIdx.x;           // k*32+kt, 0..95
    const int pf = blockIdx.y;           // 0..23
    const int k  = ch >> 5;
    const int i0 = (ch & 31) * 32 + (l >> 4) * 8;
    const int p  = pf * 16 + (l & 15);
    uint4 w = make_uint4(0, 0, 0, 0);
    if (p < P) {
        const float* wcT = ws + WS_WCPT + (size_t)p * 3072;
        float v[8];
        #pragma unroll
        for (int e = 0; e < 8; e++)
            v[e] = wcT[(i0 + e) * 3 + k];
        w.x = f2bf(v[0]) | (f2bf(v[1]) << 16);
        w.y = f2bf(v[2]) | (f2bf(v[3]) << 16);
        w.z = f2bf(v[4]) | (f2bf(v[5]) << 16);
        w.w = f2bf(v[6]) | (f2bf(v[7]) << 16);
    }
    ((uint4*)(ws + WS_AIMG))[(size_t)(ch * 24 + pf) * 64 + l] = w;
}

// ---------------------------------------------------------------------------
// k_mconv (MFMA): M[b,p,g] = bcP[p] + sum_k sum_i A_k[p][i] * h[b,i,g+k-1]
#define HT_RS 1056            /* u16 elems per row (2112 B) */
__global__ __launch_bounds__(256) void k_mconv(float* __restrict__ ws)
{
    __shared__ unsigned short Ht[18 * HT_RS];   // 38016 B
    const int b  = blockIdx.x;
    const int pt = blockIdx.y;                  // 0..5
    const int t  = threadIdx.x;
    const int l  = t & 63;
    const int wid = t >> 6;
    const int pf = pt * 4 + wid;                // 0..23
    const int n16 = l & 15;
    const int g8  = l >> 4;

    for (int j = t; j < HT_RS; j += 256) {
        Ht[j] = 0;
        Ht[17 * HT_RS + j] = 0;
    }
    {
        const float* h2b = ws + WS_H2 + (size_t)b * 16384;
        const int s0 = t * 4;
        float v[4][16];
        #pragma unroll
        for (int rr = 0; rr < 4; rr++) {
            const float4* src = (const float4*)(h2b + (size_t)(s0 + rr) * 16);
            float4 a0 = src[0], a1 = src[1], a2 = src[2], a3 = src[3];
            v[rr][0]=a0.x; v[rr][1]=a0.y; v[rr][2]=a0.z; v[rr][3]=a0.w;
            v[rr][4]=a1.x; v[rr][5]=a1.y; v[rr][6]=a1.z; v[rr][7]=a1.w;
            v[rr][8]=a2.x; v[rr][9]=a2.y; v[rr][10]=a2.z; v[rr][11]=a2.w;
            v[rr][12]=a3.x; v[rr][13]=a3.y; v[rr][14]=a3.z; v[rr][15]=a3.w;
        }
        #pragma unroll
        for (int g = 0; g < 16; g++) {
            uint2 w;
            w.x = f2bf(v[0][g]) | (f2bf(v[1][g]) << 16);
            w.y = f2bf(v[2][g]) | (f2bf(v[3][g]) << 16);
            *(uint2*)&Ht[(g + 1) * HT_RS + s0] = w;
        }
    }
    __syncthreads();

    const uint4* ap = (const uint4*)(ws + WS_AIMG) + (size_t)pf * 64 + l;
    f32x4 acc = (f32x4){0.f, 0.f, 0.f, 0.f};
    uint4 fan = *ap;                    // prefetch it=0
    #pragma unroll 4
    for (int it = 0; it < 96; it++) {
        uint4 fac = fan;
        ap += 24 * 64;
        if (it < 95) fan = *ap;
        const int k  = it >> 5;
        const int kt = it & 31;
        s16x8 fb = *(const s16x8*)&Ht[(n16 + k) * HT_RS + kt * 32 + g8 * 8];
        s16x8 fa = *(s16x8*)&fac;
        acc = __builtin_amdgcn_mfma_f32_16x16x32_bf16(fa, fb, acc, 0, 0, 0);
    }

    #pragma unroll
    for (int r = 0; r < 4; r++) {
        int p = pf * 16 + g8 * 4 + r;
        if (p < P)
            ws[WS_M + ((size_t)b * P + p) * 16 + n16] = acc[r] + ws[WS_BCP + p];
    }
}

// ---------------------------------------------------------------------------
// k_pred v4: MFMA bf16 GEMM + fused stats + fused epilogue.
// 512 threads (8 waves, 4M x 2N), block tile 192p x 128c, grid (b, 2):
// staging redundancy 2x (was 4x), same-b blocks on same XCD (T1).
// Single barrier per k-step: MFMA(buf[kt&1]) || WRITEB(buf[(kt+1)&1] from
// regs loaded one iter earlier); loads for kt+2 issued before both.
__global__ __launch_bounds__(512, 1) void k_pred(
    const float* __restrict__ x,
    const float* __restrict__ W3, const float* __restrict__ b3,
    const float* __restrict__ ws, float* __restrict__ out)
{
    __shared__ __align__(16) unsigned short Bs[2][8][4][16][8];   // 16384 B
    __shared__ float sev[512], ssq[512], smean[128], sstd[128];
    const int b     = blockIdx.x;
    const int ptile = blockIdx.y;        // 0,1 (192 p-rows each)
    const int t     = threadIdx.x;       // 0..511
    const int lane  = t & 63;
    const int wid   = t >> 6;            // 0..7
    const int wm    = wid >> 1;          // 0..3
    const int wn    = wid & 1;           // 0,1
    const int g8    = lane >> 4;         // 0..3  (k-group)
    const int n16   = lane & 15;

    const int sc  = t & 127;             // staging column
    const int skg = t >> 7;              // staging k-group 0..3

    const float* xb = x + (size_t)b * S * C;
    // A image: tile (kt*2 + ptile)*12288 B; sub = wm*3 + fi
    const char* aimgc = (const char*)ws + ptile * 12288
        + (wm * 3) * 1024 + g8 * 256 + n16 * 16;

    f32x4 acc[3][4];
    #pragma unroll
    for (int i = 0; i < 3; i++)
        #pragma unroll
        for (int j = 0; j < 4; j++) acc[i][j] = (f32x4){0.f, 0.f, 0.f, 0.f};

    float ev_acc = 0.f, sq_acc = 0.f;    // per-thread stats partials (col sc)

#define P_LOADB_(dst, kt) {                                                 \
    const float* xs_ = xb + (size_t)(32 * (kt) + 8 * skg) * C + sc;         \
    _Pragma("unroll")                                                       \
    for (int e_ = 0; e_ < 8; e_++) dst[e_] = xs_[(size_t)e_ * C]; }

#define P_WRITEB_(src, buf) {                                               \
    uint4 w_;                                                               \
    w_.x = f2bf(src[0]) | (f2bf(src[1]) << 16);                             \
    w_.y = f2bf(src[2]) | (f2bf(src[3]) << 16);                             \
    w_.z = f2bf(src[4]) | (f2bf(src[5]) << 16);                             \
    w_.w = f2bf(src[6]) | (f2bf(src[7]) << 16);                             \
    *(uint4*)&Bs[buf][sc >> 4][skg][sc & 15][0] = w_;                       \
    _Pragma("unroll")                                                       \
    for (int e_ = 0; e_ < 8; e_++) {                                        \
        float v_ = src[e_];                                                 \
        sq_acc = fmaf(v_, v_, sq_acc);                                      \
        if ((e_ & 1) == 0) ev_acc += v_;   /* s=32kt+8skg+e: even<=>e even */ \
    } }

#define P_LOADA_(dst, kt) {                                                 \
    const char* ap_ = aimgc + (size_t)(kt) * 24576;                         \
    _Pragma("unroll")                                                       \
    for (int fi_ = 0; fi_ < 3; fi_++)                                       \
        dst[fi_] = *(const uint4*)(ap_ + fi_ * 1024); }

#define P_MFMA_(buf, au) {                                                  \
    s16x8 fb0 = *(const s16x8*)&Bs[buf][4 * wn + 0][g8][n16][0];            \
    s16x8 fb1 = *(const s16x8*)&Bs[buf][4 * wn + 1][g8][n16][0];            \
    s16x8 fb2 = *(const s16x8*)&Bs[buf][4 * wn + 2][g8][n16][0];            \
    s16x8 fb3 = *(const s16x8*)&Bs[buf][4 * wn + 3][g8][n16][0];            \
    _Pragma("unroll")                                                       \
    for (int fi_ = 0; fi_ < 3; fi_++) {                                     \
        s16x8 fa_ = *(s16x8*)&au[fi_];                                      \
        acc[fi_][0] = __builtin_amdgcn_mfma_f32_16x16x32_bf16(fa_, fb0, acc[fi_][0], 0, 0, 0); \
        acc[fi_][1] = __builtin_amdgcn_mfma_f32_16x16x32_bf16(fa_, fb1, acc[fi_][1], 0, 0, 0); \
        acc[fi_][2] = __builtin_amdgcn_mfma_f32_16x16x32_bf16(fa_, fb2, acc[fi_][2], 0, 0, 0); \
        acc[fi_][3] = __builtin_amdgcn_mfma_f32_16x16x32_bf16(fa_, fb3, acc[fi_][3], 0, 0, 0); } }

    float b0r[8], b1r[8];     // R0 = even tiles, R1 = odd tiles
    uint4 a0u[3], a1u[3];

    // prologue: issue tiles 0,1; write tile 0 -> buf0
    P_LOADB_(b0r, 0); P_LOADB_(b1r, 1);
    P_LOADA_(a0u, 0); P_LOADA_(a1u, 1);
    P_WRITEB_(b0r, 0);
    __syncthreads();

    for (int i = 0; i < 16; i++) {
        const int kt = 2 * i;
        // even step kt: MFMA(buf0) || write tile kt+1 -> buf1
        {
            uint4 au[3];
            #pragma unroll
            for (int fi = 0; fi < 3; fi++) au[fi] = a0u[fi];   // A(kt), issued kt-2
            if (kt + 2 < 32) { P_LOADA_(a0u, kt + 2); P_LOADB_(b0r, kt + 2); }
            P_MFMA_(0, au);
            P_WRITEB_(b1r, 1);            // tile kt+1 (loads issued >=1 iter ago)
            __syncthreads();
        }
        // odd step kt+1: MFMA(buf1) || write tile kt+2 -> buf0
        {
            const int kt1 = kt + 1;
            uint4 au[3];
            #pragma unroll
            for (int fi = 0; fi < 3; fi++) au[fi] = a1u[fi];   // A(kt1)
            if (kt1 + 2 < 32) { P_LOADA_(a1u, kt1 + 2); P_LOADB_(b1r, kt1 + 2); }
            P_MFMA_(1, au);
            if (kt1 < 31) P_WRITEB_(b0r, 0);   // tile kt1+1
            __syncthreads();
        }
    }

#undef P_LOADB_
#undef P_WRITEB_
#undef P_LOADA_
#undef P_MFMA_

    // ---- in-block stats reduction (4 kg-groups share column sc) ----
    sev[t] = ev_acc; ssq[t] = sq_acc;
    __syncthreads();
    if (t < 128) {
        float ev = sev[t] + sev[t + 128] + sev[t + 256] + sev[t + 384];
        float sq = ssq[t] + ssq[t + 128] + ssq[t + 256] + ssq[t + 384];
        float mean = ev * (INV_SQRT2f / 512.f);
        float var  = (sq - 1024.f * mean * mean) * (1.f / 1023.f);  // ddof=1
        smean[t] = mean;
        sstd[t]  = sqrtf(var + LN_EPSf);
    }
    __syncthreads();

    // ---- epilogue ----
    const int cb = wn * 64 + n16;
    float sdv[4], mnv[4], b3v[4];
    f32x4 w3r[4][4];
    #pragma unroll
    for (int fj = 0; fj < 4; fj++) {
        int c = cb + fj * 16;
        sdv[fj] = sstd[c];
        mnv[fj] = smean[c];
        b3v[fj] = b3[c];
        const f32x4* wr = (const f32x4*)(W3 + c * 16);
        #pragma unroll
        for (int q = 0; q < 4; q++) w3r[fj][q] = wr[q];
    }
    const int prow0 = ptile * 192 + wm * 48 + g8 * 4;
    #pragma unroll
    for (int fi = 0; fi < 3; fi++) {
        #pragma unroll
        for (int r = 0; r < 4; r++) {
            int p  = prow0 + fi * 16 + r;
            int pc = p < P ? p : P - 1;
            const f32x4* mrow = (const f32x4*)(ws + WS_M + ((size_t)b * P + pc) * 16);
            f32x4 m0 = mrow[0], m1 = mrow[1], m2 = mrow[2], m3 = mrow[3];
            const float* e = ws + WS_EPI + pc * 4;
            float A13 = e[0], A4 = e[1], A2 = e[2];
            #pragma unroll
            for (int fj = 0; fj < 4; fj++) {
                float s = 0.f;
                #pragma unroll
                for (int q = 0; q < 4; q++) {
                    const f32x4 mv = (q==0)?m0:(q==1)?m1:(q==2)?m2:m3;
                    s = fmaf(mv.x, w3r[fj][q].x, s);
                    s = fmaf(mv.y, w3r[fj][q].y, s);
                    s = fmaf(mv.z, w3r[fj][q].z, s);
                    s = fmaf(mv.w, w3r[fj][q].w, s);
                }
                float res = acc[fi][fj][r]
                          + sdv[fj] * (OMBf * s + A13 + A4 * b3v[fj])
                          + A2 * mnv[fj];
                if (p < P)
                    out[((size_t)b * P + p) * C + cb + fj * 16] = res;
            }
        }
    }
}

// ---------------------------------------------------------------------------
extern "C" void kernel_launch(void* const* d_in, const int* in_sizes, int n_in,
                              void* d_out, int out_size, void* d_ws, size_t ws_size,
                              hipStream_t stream)
{
    const float* x    = (const float*)d_in[0];
    const float* xme  = (const float*)d_in[1];
    const float* W1   = (const float*)d_in[4];
    const float* b1   = (const float*)d_in[5];
    const float* g1   = (const float*)d_in[6];
    const float* be1  = (const float*)d_in[7];
    const float* W2   = (const float*)d_in[8];
    const float* b2   = (const float*)d_in[9];
    const float* g2   = (const float*)d_in[10];
    const float* be2  = (const float*)d_in[11];
    const float* Wc   = (const float*)d_in[12];
    const float* bc   = (const float*)d_in[13];
    const float* W3   = (const float*)d_in[14];
    const float* b3   = (const float*)d_in[15];
    const float* Wtp  = (const float*)d_in[16];
    const float* btp  = (const float*)d_in[17];
    const float* Whp  = (const float*)d_in[18];
    const float* bhp  = (const float*)d_in[19];
    float* ws  = (float*)d_ws;
    float* out = (float*)d_out;

    k_prep  <<<dim3(P),      dim3(256), 0, stream>>>(Whp, Wtp, bc, bhp, btp, ws);
    k_mlp   <<<dim3(512),    dim3(256), 0, stream>>>(xme, W1, b1, g1, be1,
                                                     W2, b2, g2, be2, ws);
    k_wcp   <<<dim3(4, 48),  dim3(256), 0, stream>>>(Wc, Wtp, ws);
    k_repack<<<dim3(96, 24), dim3(64),  0, stream>>>(ws);
    k_mconv <<<dim3(B, 6),   dim3(256), 0, stream>>>(ws);
    k_pred  <<<dim3(B, 2),   dim3(512), 0, stream>>>(x, W3, b3, ws, out);
}